// Round 1
// baseline (1032.469 us; speedup 1.0000x reference)
//
#include <hip/hip_runtime.h>
#include <hip/hip_bf16.h>

#define NN 100000
#define NE 1600000
#define NG 256
#define FIN 16
#define HID 64

__device__ __forceinline__ int lower_bound_i(const int* __restrict__ b, int n, int v) {
    int lo = 0, hi = n;
    while (lo < hi) { int m = (lo + hi) >> 1; if (b[m] < v) lo = m + 1; else hi = m; }
    return lo;
}

// ---- degree / CSR build ------------------------------------------------
__global__ void k_init(float* __restrict__ deg, int* __restrict__ cursor) {
    int i = blockIdx.x * blockDim.x + threadIdx.x;
    if (i < NN) deg[i] = 1.0f;          // self-loop
    if (i == 0) *cursor = 0;
}

__global__ void k_count(const int* __restrict__ row, float* __restrict__ deg) {
    int e = blockIdx.x * blockDim.x + threadIdx.x;
    if (e < NE) atomicAdd(&deg[row[e]], 1.0f);
}

__global__ void k_alloc(const float* __restrict__ deg, float* __restrict__ dinv,
                        int* __restrict__ cursor, int* __restrict__ startv,
                        int* __restrict__ fillcur) {
    int i = blockIdx.x * blockDim.x + threadIdx.x;
    if (i >= NN) return;
    float d = deg[i];
    dinv[i] = rsqrtf(d);
    int cnt = (int)(d + 0.5f) - 1;
    int s = atomicAdd(cursor, cnt);
    startv[i] = s;
    fillcur[i] = s;
}

__global__ void k_fill(const int* __restrict__ row, const int* __restrict__ col,
                       int* __restrict__ fillcur, const float* __restrict__ dinv,
                       int* __restrict__ csr_col, float* __restrict__ csr_norm) {
    int e = blockIdx.x * blockDim.x + threadIdx.x;
    if (e >= NE) return;
    int r = row[e], c = col[e];
    int pos = atomicAdd(&fillcur[r], 1);
    csr_col[pos] = c;
    csr_norm[pos] = dinv[r] * dinv[c];
}

// ---- GraphNorm: one block per graph, batch is sorted --------------------
template <int C>
__global__ void k_graphnorm(const float* __restrict__ x, const int* __restrict__ batch,
                            const float* __restrict__ w, const float* __restrict__ b,
                            const float* __restrict__ ms, float* __restrict__ out) {
    constexpr int NPB = 256 / C;
    __shared__ float red[NPB][C];
    __shared__ float mm_s[C];
    __shared__ float rstd_s[C];
    int g = blockIdx.x;
    int s = lower_bound_i(batch, NN, g);
    int e = lower_bound_i(batch, NN, g + 1);
    float fc = (float)max(e - s, 1);
    int c = threadIdx.x % C, slot = threadIdx.x / C;

    float acc = 0.f;
    for (int i = s + slot; i < e; i += NPB) acc += x[i * C + c];
    red[slot][c] = acc;
    __syncthreads();
    if (threadIdx.x < C) {
        float t = 0.f;
        for (int k = 0; k < NPB; k++) t += red[k][threadIdx.x];
        mm_s[threadIdx.x] = ms[threadIdx.x] * (t / fc);
    }
    __syncthreads();
    float mm = mm_s[c];
    float acc2 = 0.f;
    for (int i = s + slot; i < e; i += NPB) { float v = x[i * C + c] - mm; acc2 += v * v; }
    red[slot][c] = acc2;
    __syncthreads();
    if (threadIdx.x < C) {
        float t = 0.f;
        for (int k = 0; k < NPB; k++) t += red[k][threadIdx.x];
        rstd_s[threadIdx.x] = rsqrtf(t / fc + 1e-5f);
    }
    __syncthreads();
    float ww = w[c] * rstd_s[c], bb = b[c];
    for (int i = s + slot; i < e; i += NPB) out[i * C + c] = ww * (x[i * C + c] - mm) + bb;
}

// ---- x @ W (K x 64), no bias -------------------------------------------
template <int K>
__global__ void k_gemm(const float* __restrict__ x, const float* __restrict__ W,
                       float* __restrict__ out) {
    constexpr int NPB = 32;  // nodes per block; 100000/32 = 3125 exact
    __shared__ float Ws[K * 64];
    __shared__ float xs[NPB * K];
    int base = blockIdx.x * NPB;
    for (int i = threadIdx.x; i < K * 64; i += 256) Ws[i] = W[i];
    for (int i = threadIdx.x; i < NPB * K; i += 256) xs[i] = x[(long)(base + i / K) * K + (i % K)];
    __syncthreads();
    int j = threadIdx.x & 63, s0 = threadIdx.x >> 6;
    for (int r = 0; r < NPB / 4; r++) {
        int slot = s0 + r * 4;
        float acc = 0.f;
#pragma unroll
        for (int k = 0; k < K; k++) acc += xs[slot * K + k] * Ws[k * 64 + j];
        out[(long)(base + slot) * 64 + j] = acc;
    }
}

// ---- GCN aggregate: one wave per destination row, lane = channel --------
__global__ void k_gather(const float* __restrict__ h, const int* __restrict__ startv,
                         const float* __restrict__ deg, const float* __restrict__ dinv,
                         const int* __restrict__ csr_col, const float* __restrict__ csr_norm,
                         const float* __restrict__ bias, float* __restrict__ out) {
    int wave = (blockIdx.x * blockDim.x + threadIdx.x) >> 6;
    int lane = threadIdx.x & 63;
    if (wave >= NN) return;
    int i = wave;
    float di = dinv[i];
    float acc = di * di * h[(long)i * 64 + lane];
    int s = startv[i];
    int cnt = (int)(deg[i] + 0.5f) - 1;
    for (int k = 0; k < cnt; k++) {
        int c = csr_col[s + k];
        float nrm = csr_norm[s + k];
        acc += nrm * h[(long)c * 64 + lane];
    }
    out[(long)i * 64 + lane] = fmaxf(acc + bias[lane], 0.f);
}

// ---- global mean pool ---------------------------------------------------
__global__ void k_pool(const float* __restrict__ x, const int* __restrict__ batch,
                       float* __restrict__ gpool) {
    __shared__ float red[4][64];
    int g = blockIdx.x;
    int s = lower_bound_i(batch, NN, g);
    int e = lower_bound_i(batch, NN, g + 1);
    int c = threadIdx.x & 63, slot = threadIdx.x >> 6;
    float acc = 0.f;
    for (int i = s + slot; i < e; i += 4) acc += x[i * 64 + c];
    red[slot][c] = acc;
    __syncthreads();
    if (threadIdx.x < 64) {
        float t = 0.f;
        for (int k = 0; k < 4; k++) t += red[k][threadIdx.x];
        gpool[g * 64 + threadIdx.x] = t / (float)max(e - s, 1);
    }
}

// ---- dense head + softmax ----------------------------------------------
__global__ void k_head(const float* __restrict__ gpool, const float* __restrict__ Wd,
                       const float* __restrict__ bd, const float* __restrict__ Wo,
                       const float* __restrict__ bo, float* __restrict__ out) {
    int g = blockIdx.x, j = threadIdx.x;  // 64 threads
    __shared__ float gs[64];
    gs[j] = gpool[g * 64 + j];
    __syncthreads();
    float acc = bd[j];
    for (int k = 0; k < 64; k++) acc += gs[k] * Wd[k * 64 + j];
    float hv = fmaxf(acc, 0.f);
    float p0 = hv * Wo[j * 2 + 0], p1 = hv * Wo[j * 2 + 1];
    for (int off = 32; off; off >>= 1) { p0 += __shfl_down(p0, off); p1 += __shfl_down(p1, off); }
    if (j == 0) {
        float l0 = p0 + bo[0], l1 = p1 + bo[1];
        float m = fmaxf(l0, l1);
        float e0 = expf(l0 - m), e1 = expf(l1 - m);
        float inv = 1.f / (e0 + e1);
        out[g * 2 + 0] = e0 * inv;
        out[g * 2 + 1] = e1 * inv;
    }
}

extern "C" void kernel_launch(void* const* d_in, const int* in_sizes, int n_in,
                              void* d_out, int out_size, void* d_ws, size_t ws_size,
                              hipStream_t stream) {
    const float* x = (const float*)d_in[0];
    const int* ei = (const int*)d_in[1];
    const int* row = ei;
    const int* col = ei + NE;
    const int* batch = (const int*)d_in[2];
    const float* gn0w = (const float*)d_in[3];
    const float* gn0b = (const float*)d_in[4];
    const float* gn0ms = (const float*)d_in[5];
    const float* W1 = (const float*)d_in[6];
    const float* b1 = (const float*)d_in[7];
    const float* gn1w = (const float*)d_in[8];
    const float* gn1b = (const float*)d_in[9];
    const float* gn1ms = (const float*)d_in[10];
    const float* W2 = (const float*)d_in[11];
    const float* b2 = (const float*)d_in[12];
    const float* gn2w = (const float*)d_in[13];
    const float* gn2b = (const float*)d_in[14];
    const float* gn2ms = (const float*)d_in[15];
    const float* W3 = (const float*)d_in[16];
    const float* b3 = (const float*)d_in[17];
    const float* Wd = (const float*)d_in[18];
    const float* bd = (const float*)d_in[19];
    const float* Wo = (const float*)d_in[20];
    const float* bo = (const float*)d_in[21];
    float* outp = (float*)d_out;

    float* deg = (float*)d_ws;           // NN
    float* dinv = deg + NN;              // NN
    int* startv = (int*)(dinv + NN);     // NN
    int* fillcur = startv + NN;          // NN
    int* cursor = fillcur + NN;          // 1 (padded to 64)
    int* csr_col = cursor + 64;          // NE
    float* csr_norm = (float*)(csr_col + NE);  // NE
    float* X16 = csr_norm + NE;          // NN*16
    float* A = X16 + (long)NN * FIN;     // NN*64
    float* B = A + (long)NN * HID;       // NN*64
    float* gpool = B + (long)NN * HID;   // NG*64

    k_init<<<(NN + 255) / 256, 256, 0, stream>>>(deg, cursor);
    k_count<<<(NE + 255) / 256, 256, 0, stream>>>(row, deg);
    k_alloc<<<(NN + 255) / 256, 256, 0, stream>>>(deg, dinv, cursor, startv, fillcur);
    k_fill<<<(NE + 255) / 256, 256, 0, stream>>>(row, col, fillcur, dinv, csr_col, csr_norm);

    k_graphnorm<FIN><<<NG, 256, 0, stream>>>(x, batch, gn0w, gn0b, gn0ms, X16);
    k_gemm<FIN><<<NN / 32, 256, 0, stream>>>(X16, W1, A);
    k_gather<<<NN / 4, 256, 0, stream>>>(A, startv, deg, dinv, csr_col, csr_norm, b1, B);

    k_graphnorm<HID><<<NG, 256, 0, stream>>>(B, batch, gn1w, gn1b, gn1ms, A);
    k_gemm<HID><<<NN / 32, 256, 0, stream>>>(A, W2, B);
    k_gather<<<NN / 4, 256, 0, stream>>>(B, startv, deg, dinv, csr_col, csr_norm, b2, A);

    k_graphnorm<HID><<<NG, 256, 0, stream>>>(A, batch, gn2w, gn2b, gn2ms, B);
    k_gemm<HID><<<NN / 32, 256, 0, stream>>>(B, W3, A);
    k_gather<<<NN / 4, 256, 0, stream>>>(A, startv, deg, dinv, csr_col, csr_norm, b3, B);

    k_pool<<<NG, 256, 0, stream>>>(B, batch, gpool);
    k_head<<<NG, 64, 0, stream>>>(gpool, Wd, bd, Wo, bo, outp);
}

// Round 2
// 680.889 us; speedup vs baseline: 1.5164x; 1.5164x over previous
//
#include <hip/hip_runtime.h>
#include <hip/hip_bf16.h>

#define NN 100000
#define NE 1600000
#define NG 256
#define FIN 16
#define HID 64

__device__ __forceinline__ int lower_bound_i(const int* __restrict__ b, int n, int v) {
    int lo = 0, hi = n;
    while (lo < hi) { int m = (lo + hi) >> 1; if (b[m] < v) lo = m + 1; else hi = m; }
    return lo;
}

// ---- degree / CSR build ------------------------------------------------
__global__ void k_init(int* __restrict__ degc, int* __restrict__ cursor) {
    int i = blockIdx.x * blockDim.x + threadIdx.x;
    if (i < NN) degc[i] = 0;
    if (i == 0) *cursor = 0;
}

__global__ void k_count(const int* __restrict__ row, int* __restrict__ degc) {
    int t = blockIdx.x * blockDim.x + threadIdx.x;
    if (t * 4 >= NE) return;
    int4 r = ((const int4*)row)[t];
    atomicAdd(&degc[r.x], 1);
    atomicAdd(&degc[r.y], 1);
    atomicAdd(&degc[r.z], 1);
    atomicAdd(&degc[r.w], 1);
}

__global__ void k_alloc(const int* __restrict__ degc, float* __restrict__ dinv,
                        int* __restrict__ cursor, int* __restrict__ startv,
                        int* __restrict__ fillcur) {
    int i = blockIdx.x * blockDim.x + threadIdx.x;
    if (i >= NN) return;
    int cnt = degc[i];
    dinv[i] = rsqrtf((float)(cnt + 1));
    int s = atomicAdd(cursor, cnt);
    startv[i] = s;
    fillcur[i] = s;
}

__global__ void k_fill(const int* __restrict__ row, const int* __restrict__ col,
                       int* __restrict__ fillcur, const float* __restrict__ dinv,
                       int2* __restrict__ csr) {
    int e = blockIdx.x * blockDim.x + threadIdx.x;
    if (e >= NE) return;
    int r = row[e], c = col[e];
    int pos = atomicAdd(&fillcur[r], 1);
    int2 ent;
    ent.x = c;
    ent.y = __float_as_int(dinv[r] * dinv[c]);
    csr[pos] = ent;
}

// ---- GraphNorm (materializing, used for layer 0 / C=16) -----------------
template <int C>
__global__ void k_graphnorm(const float* __restrict__ x, const int* __restrict__ batch,
                            const float* __restrict__ w, const float* __restrict__ b,
                            const float* __restrict__ ms, float* __restrict__ out) {
    constexpr int NPB = 256 / C;
    __shared__ float red[NPB][C];
    __shared__ float mm_s[C];
    __shared__ float rstd_s[C];
    int g = blockIdx.x;
    int s = lower_bound_i(batch, NN, g);
    int e = lower_bound_i(batch, NN, g + 1);
    float fc = (float)max(e - s, 1);
    int c = threadIdx.x % C, slot = threadIdx.x / C;

    float acc = 0.f;
    for (int i = s + slot; i < e; i += NPB) acc += x[i * C + c];
    red[slot][c] = acc;
    __syncthreads();
    if (threadIdx.x < C) {
        float t = 0.f;
        for (int k = 0; k < NPB; k++) t += red[k][threadIdx.x];
        mm_s[threadIdx.x] = ms[threadIdx.x] * (t / fc);
    }
    __syncthreads();
    float mm = mm_s[c];
    float acc2 = 0.f;
    for (int i = s + slot; i < e; i += NPB) { float v = x[i * C + c] - mm; acc2 += v * v; }
    red[slot][c] = acc2;
    __syncthreads();
    if (threadIdx.x < C) {
        float t = 0.f;
        for (int k = 0; k < NPB; k++) t += red[k][threadIdx.x];
        rstd_s[threadIdx.x] = rsqrtf(t / fc + 1e-5f);
    }
    __syncthreads();
    float ww = w[c] * rstd_s[c], bb = b[c];
    for (int i = s + slot; i < e; i += NPB) out[i * C + c] = ww * (x[i * C + c] - mm) + bb;
}

// ---- GraphNorm stats only: writes affine tables A=w*rstd, B=b-A*ms*mean --
__global__ void k_gnstats(const float* __restrict__ x, const int* __restrict__ batch,
                          const float* __restrict__ w, const float* __restrict__ b,
                          const float* __restrict__ ms,
                          float* __restrict__ tabA, float* __restrict__ tabB) {
    constexpr int C = 64, NPB = 4;
    __shared__ float red[NPB][C];
    __shared__ float mm_s[C];
    int g = blockIdx.x;
    int s = lower_bound_i(batch, NN, g);
    int e = lower_bound_i(batch, NN, g + 1);
    float fc = (float)max(e - s, 1);
    int c = threadIdx.x & 63, slot = threadIdx.x >> 6;

    float acc = 0.f;
    for (int i = s + slot; i < e; i += NPB) acc += x[i * C + c];
    red[slot][c] = acc;
    __syncthreads();
    if (threadIdx.x < C) {
        float t = 0.f;
        for (int k = 0; k < NPB; k++) t += red[k][threadIdx.x];
        mm_s[threadIdx.x] = ms[threadIdx.x] * (t / fc);
    }
    __syncthreads();
    float mm = mm_s[c];
    float acc2 = 0.f;
    for (int i = s + slot; i < e; i += NPB) { float v = x[i * C + c] - mm; acc2 += v * v; }
    red[slot][c] = acc2;
    __syncthreads();
    if (threadIdx.x < C) {
        float t = 0.f;
        for (int k = 0; k < NPB; k++) t += red[k][threadIdx.x];
        float rstd = rsqrtf(t / fc + 1e-5f);
        float A = w[threadIdx.x] * rstd;
        tabA[g * C + threadIdx.x] = A;
        tabB[g * C + threadIdx.x] = b[threadIdx.x] - A * mm_s[threadIdx.x];
    }
}

// ---- 16-dim gather (layer 1, pre-GEMM): 4 edges per wave-iteration ------
__global__ void k_gather16(const float* __restrict__ x, const int* __restrict__ startv,
                           const int* __restrict__ degc, const float* __restrict__ dinv,
                           const int2* __restrict__ csr, float* __restrict__ agg) {
    int wave = (blockIdx.x * blockDim.x + threadIdx.x) >> 6;
    if (wave >= NN) return;
    int lane = threadIdx.x & 63;
    int ch = lane & 15, grp = lane >> 4;
    int i = wave;
    int s = startv[i], cnt = degc[i];
    float acc = 0.f;
    for (int k = grp; k < cnt; k += 4) {
        int2 e = csr[s + k];
        acc += __int_as_float(e.y) * x[(long)e.x * FIN + ch];
    }
    acc += __shfl_xor(acc, 16);
    acc += __shfl_xor(acc, 32);
    float di = dinv[i];
    float r = acc + di * di * x[(long)i * FIN + ch];
    if (lane < 16) agg[(long)i * FIN + ch] = r;
}

// ---- 64-dim gather, 8-deep pipelined; fused bias+relu -------------------
__global__ void k_gather64(const float* __restrict__ h, const int* __restrict__ startv,
                           const int* __restrict__ degc, const float* __restrict__ dinv,
                           const int2* __restrict__ csr, const float* __restrict__ bias,
                           float* __restrict__ out) {
    int wave = (blockIdx.x * blockDim.x + threadIdx.x) >> 6;
    if (wave >= NN) return;
    int lane = threadIdx.x & 63;
    int i = wave;
    int s = startv[i], cnt = degc[i];
    float di = dinv[i];
    float acc = di * di * h[(long)i * HID + lane];
    int k = 0;
    for (; k + 8 <= cnt; k += 8) {
        int2 e0 = csr[s + k + 0], e1 = csr[s + k + 1], e2 = csr[s + k + 2], e3 = csr[s + k + 3];
        int2 e4 = csr[s + k + 4], e5 = csr[s + k + 5], e6 = csr[s + k + 6], e7 = csr[s + k + 7];
        float v0 = h[(long)e0.x * HID + lane];
        float v1 = h[(long)e1.x * HID + lane];
        float v2 = h[(long)e2.x * HID + lane];
        float v3 = h[(long)e3.x * HID + lane];
        float v4 = h[(long)e4.x * HID + lane];
        float v5 = h[(long)e5.x * HID + lane];
        float v6 = h[(long)e6.x * HID + lane];
        float v7 = h[(long)e7.x * HID + lane];
        acc += __int_as_float(e0.y) * v0 + __int_as_float(e1.y) * v1 +
               __int_as_float(e2.y) * v2 + __int_as_float(e3.y) * v3 +
               __int_as_float(e4.y) * v4 + __int_as_float(e5.y) * v5 +
               __int_as_float(e6.y) * v6 + __int_as_float(e7.y) * v7;
    }
    for (; k < cnt; k++) {
        int2 e = csr[s + k];
        acc += __int_as_float(e.y) * h[(long)e.x * HID + lane];
    }
    out[(long)i * HID + lane] = fmaxf(acc + bias[lane], 0.f);
}

// ---- GEMM 16->64 with fused bias+relu (layer 1 after aggregation) -------
__global__ void k_gemm16(const float* __restrict__ x, const float* __restrict__ W,
                         const float* __restrict__ bias, float* __restrict__ out) {
    constexpr int NPB = 32;
    __shared__ float Ws[FIN * 64];
    __shared__ float xs[NPB * FIN];
    int base = blockIdx.x * NPB;
    for (int i = threadIdx.x; i < FIN * 64; i += 256) Ws[i] = W[i];
    for (int i = threadIdx.x; i < NPB * FIN; i += 256)
        xs[i] = x[(long)(base + i / FIN) * FIN + (i % FIN)];
    __syncthreads();
    int j = threadIdx.x & 63, s0 = threadIdx.x >> 6;
    float bb = bias[j];
    for (int r = 0; r < NPB / 4; r++) {
        int slot = s0 + r * 4;
        float acc = bb;
#pragma unroll
        for (int k = 0; k < FIN; k++) acc += xs[slot * FIN + k] * Ws[k * 64 + j];
        out[(long)(base + slot) * 64 + j] = fmaxf(acc, 0.f);
    }
}

// ---- GEMM 64->64 with GraphNorm affine fused into staging ---------------
__global__ void k_gemm64n(const float* __restrict__ x, const int* __restrict__ batch,
                          const float* __restrict__ tabA, const float* __restrict__ tabB,
                          const float* __restrict__ W, float* __restrict__ out) {
    constexpr int NPB = 100;  // 100000/100 = 1000 blocks
    __shared__ float Ws[64 * 64];
    __shared__ float xs[NPB * 64];
    __shared__ int gb[NPB];
    int base = blockIdx.x * NPB;
    for (int i = threadIdx.x; i < 64 * 64; i += 256) Ws[i] = W[i];
    for (int i = threadIdx.x; i < NPB; i += 256) gb[i] = batch[base + i];
    __syncthreads();
    for (int i = threadIdx.x; i < NPB * 64; i += 256) {
        int node = i >> 6, c = i & 63;
        int g = gb[node];
        xs[i] = tabA[g * 64 + c] * x[(long)(base + node) * 64 + c] + tabB[g * 64 + c];
    }
    __syncthreads();
    int j = threadIdx.x & 63, s0 = threadIdx.x >> 6;
    // 25 outputs per thread, unrolled 4-at-a-time sharing the W read
    for (int r0 = 0; r0 < NPB / 4; r0 += 4) {
        float a0 = 0.f, a1 = 0.f, a2 = 0.f, a3 = 0.f;
        int sl0 = s0 + (r0 + 0) * 4, sl1 = s0 + (r0 + 1) * 4;
        int sl2 = s0 + (r0 + 2) * 4, sl3 = s0 + (r0 + 3) * 4;
#pragma unroll
        for (int k = 0; k < 64; k++) {
            float w = Ws[k * 64 + j];
            a0 += xs[sl0 * 64 + k] * w;
            a1 += xs[sl1 * 64 + k] * w;
            a2 += xs[sl2 * 64 + k] * w;
            a3 += xs[sl3 * 64 + k] * w;
        }
        out[(long)(base + sl0) * 64 + j] = a0;
        out[(long)(base + sl1) * 64 + j] = a1;
        out[(long)(base + sl2) * 64 + j] = a2;
        out[(long)(base + sl3) * 64 + j] = a3;
    }
    // tail output (25th): r = 24
    {
        int sl = s0 + 24 * 4;
        float a = 0.f;
#pragma unroll
        for (int k = 0; k < 64; k++) a += xs[sl * 64 + k] * Ws[k * 64 + j];
        out[(long)(base + sl) * 64 + j] = a;
    }
}

// ---- global mean pool ---------------------------------------------------
__global__ void k_pool(const float* __restrict__ x, const int* __restrict__ batch,
                       float* __restrict__ gpool) {
    __shared__ float red[16][64];
    int g = blockIdx.x;
    int s = lower_bound_i(batch, NN, g);
    int e = lower_bound_i(batch, NN, g + 1);
    int c = threadIdx.x & 63, slot = threadIdx.x >> 6;
    float acc = 0.f;
    for (int i = s + slot; i < e; i += 16) acc += x[i * 64 + c];
    red[slot][c] = acc;
    __syncthreads();
    if (threadIdx.x < 64) {
        float t = 0.f;
        for (int k = 0; k < 16; k++) t += red[k][threadIdx.x];
        gpool[g * 64 + threadIdx.x] = t / (float)max(e - s, 1);
    }
}

// ---- dense head + softmax ----------------------------------------------
__global__ void k_head(const float* __restrict__ gpool, const float* __restrict__ Wd,
                       const float* __restrict__ bd, const float* __restrict__ Wo,
                       const float* __restrict__ bo, float* __restrict__ out) {
    int g = blockIdx.x, j = threadIdx.x;  // 64 threads
    __shared__ float gs[64];
    gs[j] = gpool[g * 64 + j];
    __syncthreads();
    float acc = bd[j];
    for (int k = 0; k < 64; k++) acc += gs[k] * Wd[k * 64 + j];
    float hv = fmaxf(acc, 0.f);
    float p0 = hv * Wo[j * 2 + 0], p1 = hv * Wo[j * 2 + 1];
    for (int off = 32; off; off >>= 1) { p0 += __shfl_down(p0, off); p1 += __shfl_down(p1, off); }
    if (j == 0) {
        float l0 = p0 + bo[0], l1 = p1 + bo[1];
        float m = fmaxf(l0, l1);
        float e0 = expf(l0 - m), e1 = expf(l1 - m);
        float inv = 1.f / (e0 + e1);
        out[g * 2 + 0] = e0 * inv;
        out[g * 2 + 1] = e1 * inv;
    }
}

extern "C" void kernel_launch(void* const* d_in, const int* in_sizes, int n_in,
                              void* d_out, int out_size, void* d_ws, size_t ws_size,
                              hipStream_t stream) {
    const float* x = (const float*)d_in[0];
    const int* ei = (const int*)d_in[1];
    const int* row = ei;
    const int* col = ei + NE;
    const int* batch = (const int*)d_in[2];
    const float* gn0w = (const float*)d_in[3];
    const float* gn0b = (const float*)d_in[4];
    const float* gn0ms = (const float*)d_in[5];
    const float* W1 = (const float*)d_in[6];
    const float* b1 = (const float*)d_in[7];
    const float* gn1w = (const float*)d_in[8];
    const float* gn1b = (const float*)d_in[9];
    const float* gn1ms = (const float*)d_in[10];
    const float* W2 = (const float*)d_in[11];
    const float* b2 = (const float*)d_in[12];
    const float* gn2w = (const float*)d_in[13];
    const float* gn2b = (const float*)d_in[14];
    const float* gn2ms = (const float*)d_in[15];
    const float* W3 = (const float*)d_in[16];
    const float* b3 = (const float*)d_in[17];
    const float* Wd = (const float*)d_in[18];
    const float* bd = (const float*)d_in[19];
    const float* Wo = (const float*)d_in[20];
    const float* bo = (const float*)d_in[21];
    float* outp = (float*)d_out;

    // workspace layout
    int* degc = (int*)d_ws;                    // NN
    float* dinv = (float*)(degc + NN);         // NN
    int* startv = (int*)(dinv + NN);           // NN
    int* fillcur = startv + NN;                // NN
    int* cursor = fillcur + NN;                // 64
    int2* csr = (int2*)(cursor + 64);          // NE int2
    float* bufA = (float*)(csr + NE);          // NN*64
    float* bufB = bufA + (long)NN * HID;       // NN*64
    float* tabA = bufB + (long)NN * HID;       // NG*64
    float* tabB = tabA + NG * HID;             // NG*64
    float* gpool = tabB + NG * HID;            // NG*64
    float* X16n = bufA;                        // alias (dead before bufA written)
    float* agg16 = bufB;                       // alias (dead before bufB written)

    // CSR build
    k_init<<<(NN + 255) / 256, 256, 0, stream>>>(degc, cursor);
    k_count<<<(NE / 4 + 255) / 256, 256, 0, stream>>>(row, degc);
    k_alloc<<<(NN + 255) / 256, 256, 0, stream>>>(degc, dinv, cursor, startv, fillcur);
    k_fill<<<(NE + 255) / 256, 256, 0, stream>>>(row, col, fillcur, dinv, csr);

    // layer 1: norm(16) -> aggregate(16) -> gemm 16->64 (+bias+relu)
    k_graphnorm<FIN><<<NG, 256, 0, stream>>>(x, batch, gn0w, gn0b, gn0ms, X16n);
    k_gather16<<<(NN * 64 + 255) / 256, 256, 0, stream>>>(X16n, startv, degc, dinv, csr, agg16);
    k_gemm16<<<NN / 32, 256, 0, stream>>>(agg16, W1, b1, bufA);

    // layer 2: stats -> fused-norm gemm -> gather(+bias+relu)
    k_gnstats<<<NG, 256, 0, stream>>>(bufA, batch, gn1w, gn1b, gn1ms, tabA, tabB);
    k_gemm64n<<<NN / 100, 256, 0, stream>>>(bufA, batch, tabA, tabB, W2, bufB);
    k_gather64<<<(NN * 64 + 255) / 256, 256, 0, stream>>>(bufB, startv, degc, dinv, csr, b2, bufA);

    // layer 3
    k_gnstats<<<NG, 256, 0, stream>>>(bufA, batch, gn2w, gn2b, gn2ms, tabA, tabB);
    k_gemm64n<<<NN / 100, 256, 0, stream>>>(bufA, batch, tabA, tabB, W3, bufB);
    k_gather64<<<(NN * 64 + 255) / 256, 256, 0, stream>>>(bufB, startv, degc, dinv, csr, b3, bufA);

    // pool + head
    k_pool<<<NG, 1024, 0, stream>>>(bufA, batch, gpool);
    k_head<<<NG, 64, 0, stream>>>(gpool, Wd, bd, Wo, bo, outp);
}

// Round 3
// 651.185 us; speedup vs baseline: 1.5855x; 1.0456x over previous
//
#include <hip/hip_runtime.h>
#include <hip/hip_bf16.h>

#define NN 100000
#define NE 1600000
#define NG 256
#define FIN 16
#define HID 64

__device__ __forceinline__ int lower_bound_i(const int* __restrict__ b, int n, int v) {
    int lo = 0, hi = n;
    while (lo < hi) { int m = (lo + hi) >> 1; if (b[m] < v) lo = m + 1; else hi = m; }
    return lo;
}

__device__ __forceinline__ unsigned pack_bf16(float a, float b) {
    unsigned ua = __float_as_uint(a), ub = __float_as_uint(b);
    ua = (ua + 0x7fffu + ((ua >> 16) & 1u)) >> 16;
    ub = (ub + 0x7fffu + ((ub >> 16) & 1u)) & 0xffff0000u;
    return ua | ub;
}
#define BF_LO(u) __uint_as_float((u) << 16)
#define BF_HI(u) __uint_as_float((u) & 0xffff0000u)

// ---- degree / CSR build ------------------------------------------------
__global__ __launch_bounds__(256) void k_init(int* __restrict__ degc, int* __restrict__ cursor) {
    int i = blockIdx.x * blockDim.x + threadIdx.x;
    if (i < NN) degc[i] = 0;
    if (i == 0) *cursor = 0;
}

__global__ __launch_bounds__(256) void k_count(const int* __restrict__ row, int* __restrict__ degc) {
    int t = blockIdx.x * blockDim.x + threadIdx.x;
    if (t * 4 >= NE) return;
    int4 r = ((const int4*)row)[t];
    atomicAdd(&degc[r.x], 1);
    atomicAdd(&degc[r.y], 1);
    atomicAdd(&degc[r.z], 1);
    atomicAdd(&degc[r.w], 1);
}

__global__ __launch_bounds__(256) void k_alloc(const int* __restrict__ degc, float* __restrict__ dinv,
                        int* __restrict__ cursor, int* __restrict__ startv,
                        int* __restrict__ fillcur) {
    int i = blockIdx.x * blockDim.x + threadIdx.x;
    if (i >= NN) return;
    int cnt = degc[i];
    dinv[i] = rsqrtf((float)(cnt + 1));
    int s = atomicAdd(cursor, cnt);
    startv[i] = s;
    fillcur[i] = s;
}

__global__ __launch_bounds__(256) void k_fill(const int* __restrict__ row, const int* __restrict__ col,
                       int* __restrict__ fillcur, int* __restrict__ csr_col) {
    int e = blockIdx.x * blockDim.x + threadIdx.x;
    if (e >= NE) return;
    int r = row[e], c = col[e];
    int pos = atomicAdd(&fillcur[r], 1);
    csr_col[pos] = c;
}

// ---- GraphNorm layer 0 (C=16), writes packed bf16 -----------------------
__global__ __launch_bounds__(256) void k_graphnorm16(const float* __restrict__ x, const int* __restrict__ batch,
                              const float* __restrict__ w, const float* __restrict__ b,
                              const float* __restrict__ ms, unsigned* __restrict__ xb) {
    constexpr int C = FIN, NPB = 256 / C;
    __shared__ float red[NPB][C];
    __shared__ float mm_s[C];
    __shared__ float rstd_s[C];
    int g = blockIdx.x;
    int s = lower_bound_i(batch, NN, g);
    int e = lower_bound_i(batch, NN, g + 1);
    float fc = (float)max(e - s, 1);
    int c = threadIdx.x % C, slot = threadIdx.x / C;

    float acc = 0.f;
    for (int i = s + slot; i < e; i += NPB) acc += x[i * C + c];
    red[slot][c] = acc;
    __syncthreads();
    if (threadIdx.x < C) {
        float t = 0.f;
        for (int k = 0; k < NPB; k++) t += red[k][threadIdx.x];
        mm_s[threadIdx.x] = ms[threadIdx.x] * (t / fc);
    }
    __syncthreads();
    float mm = mm_s[c];
    float acc2 = 0.f;
    for (int i = s + slot; i < e; i += NPB) { float v = x[i * C + c] - mm; acc2 += v * v; }
    red[slot][c] = acc2;
    __syncthreads();
    if (threadIdx.x < C) {
        float t = 0.f;
        for (int k = 0; k < NPB; k++) t += red[k][threadIdx.x];
        rstd_s[threadIdx.x] = rsqrtf(t / fc + 1e-5f);
    }
    __syncthreads();
    float ww = w[c] * rstd_s[c], bb = b[c];
    for (int i = s + slot; i < e; i += NPB) {
        float v = ww * (x[i * C + c] - mm) + bb;
        float partner = __shfl_xor(v, 1);
        if ((c & 1) == 0) xb[(long)i * 8 + (c >> 1)] = pack_bf16(v, partner);
    }
}

// ---- GraphNorm stats only: affine tables A=w*rstd, B=b-A*ms*mean --------
__global__ __launch_bounds__(256) void k_gnstats(const float* __restrict__ x, const int* __restrict__ batch,
                          const float* __restrict__ w, const float* __restrict__ b,
                          const float* __restrict__ ms,
                          float* __restrict__ tabA, float* __restrict__ tabB) {
    constexpr int C = 64, NPB = 4;
    __shared__ float red[NPB][C];
    __shared__ float mm_s[C];
    int g = blockIdx.x;
    int s = lower_bound_i(batch, NN, g);
    int e = lower_bound_i(batch, NN, g + 1);
    float fc = (float)max(e - s, 1);
    int c = threadIdx.x & 63, slot = threadIdx.x >> 6;

    float acc = 0.f;
    for (int i = s + slot; i < e; i += NPB) acc += x[i * C + c];
    red[slot][c] = acc;
    __syncthreads();
    if (threadIdx.x < C) {
        float t = 0.f;
        for (int k = 0; k < NPB; k++) t += red[k][threadIdx.x];
        mm_s[threadIdx.x] = ms[threadIdx.x] * (t / fc);
    }
    __syncthreads();
    float mm = mm_s[c];
    float acc2 = 0.f;
    for (int i = s + slot; i < e; i += NPB) { float v = x[i * C + c] - mm; acc2 += v * v; }
    red[slot][c] = acc2;
    __syncthreads();
    if (threadIdx.x < C) {
        float t = 0.f;
        for (int k = 0; k < NPB; k++) t += red[k][threadIdx.x];
        float rstd = rsqrtf(t / fc + 1e-5f);
        float A = w[threadIdx.x] * rstd;
        tabA[g * C + threadIdx.x] = A;
        tabB[g * C + threadIdx.x] = b[threadIdx.x] - A * mm_s[threadIdx.x];
    }
}

// ---- 16-dim gather (bf16 input, fp32 out): 8 edge-groups per wave -------
__global__ __launch_bounds__(256) void k_gather16(const unsigned* __restrict__ xb, const int* __restrict__ startv,
                           const int* __restrict__ degc, const float* __restrict__ dinv,
                           const int* __restrict__ csr_col, float* __restrict__ agg) {
    int wave = (blockIdx.x * blockDim.x + threadIdx.x) >> 6;
    if (wave >= NN) return;
    int lane = threadIdx.x & 63;
    int p = lane & 7, g = lane >> 3;
    int s = startv[wave], cnt = degc[wave];
    float di = dinv[wave];
    float ax = 0.f, ay = 0.f;
    int k = g;
    for (; k + 8 < cnt; k += 16) {
        int c0 = csr_col[s + k], c1 = csr_col[s + k + 8];
        float n0 = dinv[c0] * di, n1 = dinv[c1] * di;
        unsigned u0 = xb[(long)c0 * 8 + p], u1 = xb[(long)c1 * 8 + p];
        ax += n0 * BF_LO(u0) + n1 * BF_LO(u1);
        ay += n0 * BF_HI(u0) + n1 * BF_HI(u1);
    }
    for (; k < cnt; k += 8) {
        int c0 = csr_col[s + k];
        float n0 = dinv[c0] * di;
        unsigned u0 = xb[(long)c0 * 8 + p];
        ax += n0 * BF_LO(u0);
        ay += n0 * BF_HI(u0);
    }
    ax += __shfl_xor(ax, 8);  ay += __shfl_xor(ay, 8);
    ax += __shfl_xor(ax, 16); ay += __shfl_xor(ay, 16);
    ax += __shfl_xor(ax, 32); ay += __shfl_xor(ay, 32);
    if (g == 0) {
        unsigned u = xb[(long)wave * 8 + p];
        float sl = di * di;
        float2 r;
        r.x = ax + sl * BF_LO(u);
        r.y = ay + sl * BF_HI(u);
        ((float2*)agg)[(long)wave * 8 + p] = r;
    }
}

// ---- 64-dim gather (bf16 input): 2 edge-groups, 4-deep pipelined --------
__global__ __launch_bounds__(256) void k_gather64(const unsigned* __restrict__ h2, const int* __restrict__ startv,
                           const int* __restrict__ degc, const float* __restrict__ dinv,
                           const int* __restrict__ csr_col, const float* __restrict__ bias,
                           float* __restrict__ out) {
    int wave = (blockIdx.x * blockDim.x + threadIdx.x) >> 6;
    if (wave >= NN) return;
    int lane = threadIdx.x & 63;
    int p = lane & 31, g = lane >> 5;
    int s = startv[wave], cnt = degc[wave];
    float di = dinv[wave];
    float ax = 0.f, ay = 0.f;
    if (g == 0) {
        unsigned u = h2[(long)wave * 32 + p];
        float sl = di * di;
        ax = sl * BF_LO(u);
        ay = sl * BF_HI(u);
    }
    int k = g;
    for (; k + 6 < cnt; k += 8) {
        int c0 = csr_col[s + k], c1 = csr_col[s + k + 2],
            c2 = csr_col[s + k + 4], c3 = csr_col[s + k + 6];
        float n0 = dinv[c0] * di, n1 = dinv[c1] * di,
              n2 = dinv[c2] * di, n3 = dinv[c3] * di;
        unsigned u0 = h2[(long)c0 * 32 + p], u1 = h2[(long)c1 * 32 + p],
                 u2 = h2[(long)c2 * 32 + p], u3 = h2[(long)c3 * 32 + p];
        ax += n0 * BF_LO(u0) + n1 * BF_LO(u1) + n2 * BF_LO(u2) + n3 * BF_LO(u3);
        ay += n0 * BF_HI(u0) + n1 * BF_HI(u1) + n2 * BF_HI(u2) + n3 * BF_HI(u3);
    }
    for (; k < cnt; k += 2) {
        int c0 = csr_col[s + k];
        float n0 = dinv[c0] * di;
        unsigned u0 = h2[(long)c0 * 32 + p];
        ax += n0 * BF_LO(u0);
        ay += n0 * BF_HI(u0);
    }
    ax += __shfl_xor(ax, 32);
    ay += __shfl_xor(ay, 32);
    if (g == 0) {
        float2 r;
        r.x = fmaxf(ax + bias[2 * p], 0.f);
        r.y = fmaxf(ay + bias[2 * p + 1], 0.f);
        ((float2*)out)[(long)wave * 32 + p] = r;
    }
}

// ---- GEMM 16->64 with fused bias+relu -----------------------------------
__global__ __launch_bounds__(256) void k_gemm16(const float* __restrict__ x, const float* __restrict__ W,
                         const float* __restrict__ bias, float* __restrict__ out) {
    constexpr int NPB = 32;
    __shared__ float Ws[FIN * 64];
    __shared__ float xs[NPB * FIN];
    int base = blockIdx.x * NPB;
    for (int i = threadIdx.x; i < FIN * 64; i += 256) Ws[i] = W[i];
    for (int i = threadIdx.x; i < NPB * FIN; i += 256)
        xs[i] = x[(long)(base + i / FIN) * FIN + (i % FIN)];
    __syncthreads();
    int j = threadIdx.x & 63, s0 = threadIdx.x >> 6;
    float bb = bias[j];
    for (int r = 0; r < NPB / 4; r++) {
        int slot = s0 + r * 4;
        float acc = bb;
#pragma unroll
        for (int k = 0; k < FIN; k++) acc += xs[slot * FIN + k] * Ws[k * 64 + j];
        out[(long)(base + slot) * 64 + j] = fmaxf(acc, 0.f);
    }
}

// ---- GEMM 64->64, GraphNorm affine fused, W column in regs, bf16 out ----
__global__ __launch_bounds__(256) void k_gemm64n(const float* __restrict__ x, const int* __restrict__ batch,
                          const float* __restrict__ tabA, const float* __restrict__ tabB,
                          const float* __restrict__ W, unsigned* __restrict__ h2) {
    constexpr int NPB = 100;  // 1000 blocks
    __shared__ float xs[NPB * 64];
    __shared__ int gb[NPB];
    int base = blockIdx.x * NPB;
    int j = threadIdx.x & 63;
    float w[64];
#pragma unroll
    for (int k = 0; k < 64; k++) w[k] = W[k * 64 + j];
    for (int i = threadIdx.x; i < NPB; i += 256) gb[i] = batch[base + i];
    __syncthreads();
    for (int i = threadIdx.x; i < NPB * 64; i += 256) {
        int node = i >> 6, c = i & 63;
        int g2 = gb[node];
        xs[i] = tabA[g2 * 64 + c] * x[(long)(base + node) * 64 + c] + tabB[g2 * 64 + c];
    }
    __syncthreads();
    int s0 = threadIdx.x >> 6;
    for (int r = 0; r < 25; r++) {
        int sl = s0 * 25 + r;
        const float4* xv = (const float4*)&xs[sl * 64];
        float acc = 0.f;
#pragma unroll
        for (int k4 = 0; k4 < 16; k4++) {
            float4 v = xv[k4];
            acc += v.x * w[4 * k4] + v.y * w[4 * k4 + 1] + v.z * w[4 * k4 + 2] + v.w * w[4 * k4 + 3];
        }
        float part = __shfl_xor(acc, 1);
        if ((j & 1) == 0) h2[(long)(base + sl) * 32 + (j >> 1)] = pack_bf16(acc, part);
    }
}

// ---- global mean pool ---------------------------------------------------
__global__ __launch_bounds__(1024) void k_pool(const float* __restrict__ x, const int* __restrict__ batch,
                       float* __restrict__ gpool) {
    __shared__ float red[16][64];
    int g = blockIdx.x;
    int s = lower_bound_i(batch, NN, g);
    int e = lower_bound_i(batch, NN, g + 1);
    int c = threadIdx.x & 63, slot = threadIdx.x >> 6;
    float acc = 0.f;
    for (int i = s + slot; i < e; i += 16) acc += x[i * 64 + c];
    red[slot][c] = acc;
    __syncthreads();
    if (threadIdx.x < 64) {
        float t = 0.f;
        for (int k = 0; k < 16; k++) t += red[k][threadIdx.x];
        gpool[g * 64 + threadIdx.x] = t / (float)max(e - s, 1);
    }
}

// ---- dense head + softmax ----------------------------------------------
__global__ __launch_bounds__(64) void k_head(const float* __restrict__ gpool, const float* __restrict__ Wd,
                       const float* __restrict__ bd, const float* __restrict__ Wo,
                       const float* __restrict__ bo, float* __restrict__ out) {
    int g = blockIdx.x, j = threadIdx.x;  // 64 threads
    __shared__ float gs[64];
    gs[j] = gpool[g * 64 + j];
    __syncthreads();
    float acc = bd[j];
    for (int k = 0; k < 64; k++) acc += gs[k] * Wd[k * 64 + j];
    float hv = fmaxf(acc, 0.f);
    float p0 = hv * Wo[j * 2 + 0], p1 = hv * Wo[j * 2 + 1];
    for (int off = 32; off; off >>= 1) { p0 += __shfl_down(p0, off); p1 += __shfl_down(p1, off); }
    if (j == 0) {
        float l0 = p0 + bo[0], l1 = p1 + bo[1];
        float m = fmaxf(l0, l1);
        float e0 = expf(l0 - m), e1 = expf(l1 - m);
        float inv = 1.f / (e0 + e1);
        out[g * 2 + 0] = e0 * inv;
        out[g * 2 + 1] = e1 * inv;
    }
}

extern "C" void kernel_launch(void* const* d_in, const int* in_sizes, int n_in,
                              void* d_out, int out_size, void* d_ws, size_t ws_size,
                              hipStream_t stream) {
    const float* x = (const float*)d_in[0];
    const int* ei = (const int*)d_in[1];
    const int* row = ei;
    const int* col = ei + NE;
    const int* batch = (const int*)d_in[2];
    const float* gn0w = (const float*)d_in[3];
    const float* gn0b = (const float*)d_in[4];
    const float* gn0ms = (const float*)d_in[5];
    const float* W1 = (const float*)d_in[6];
    const float* b1 = (const float*)d_in[7];
    const float* gn1w = (const float*)d_in[8];
    const float* gn1b = (const float*)d_in[9];
    const float* gn1ms = (const float*)d_in[10];
    const float* W2 = (const float*)d_in[11];
    const float* b2 = (const float*)d_in[12];
    const float* gn2w = (const float*)d_in[13];
    const float* gn2b = (const float*)d_in[14];
    const float* gn2ms = (const float*)d_in[15];
    const float* W3 = (const float*)d_in[16];
    const float* b3 = (const float*)d_in[17];
    const float* Wd = (const float*)d_in[18];
    const float* bd = (const float*)d_in[19];
    const float* Wo = (const float*)d_in[20];
    const float* bo = (const float*)d_in[21];
    float* outp = (float*)d_out;

    // workspace layout (all chunks multiple of 8 bytes)
    int* degc = (int*)d_ws;                        // NN
    float* dinv = (float*)(degc + NN);             // NN
    int* startv = (int*)(dinv + NN);               // NN
    int* fillcur = startv + NN;                    // NN
    int* cursor = fillcur + NN;                    // 64
    int* csr_col = cursor + 64;                    // NE
    float* bufA = (float*)(csr_col + NE);          // NN*64
    float* bufB = bufA + (long)NN * HID;           // NN*64
    unsigned* h2 = (unsigned*)(bufB + (long)NN * HID);  // NN*32
    unsigned* xb = h2 + (long)NN * 32;             // NN*8
    float* agg16 = (float*)(xb + (long)NN * 8);    // NN*16
    float* tabA = agg16 + (long)NN * FIN;          // NG*64
    float* tabB = tabA + NG * HID;                 // NG*64
    float* gpool = tabB + NG * HID;                // NG*64

    // CSR build
    k_init<<<(NN + 255) / 256, 256, 0, stream>>>(degc, cursor);
    k_count<<<(NE / 4 + 255) / 256, 256, 0, stream>>>(row, degc);
    k_alloc<<<(NN + 255) / 256, 256, 0, stream>>>(degc, dinv, cursor, startv, fillcur);
    k_fill<<<(NE + 255) / 256, 256, 0, stream>>>(row, col, fillcur, csr_col);

    // layer 1: norm(16,bf16) -> aggregate(16) -> gemm 16->64 (+bias+relu)
    k_graphnorm16<<<NG, 256, 0, stream>>>(x, batch, gn0w, gn0b, gn0ms, xb);
    k_gather16<<<(NN * 64 + 255) / 256, 256, 0, stream>>>(xb, startv, degc, dinv, csr_col, agg16);
    k_gemm16<<<NN / 32, 256, 0, stream>>>(agg16, W1, b1, bufA);

    // layer 2: stats -> fused-norm gemm (bf16 out) -> gather(+bias+relu)
    k_gnstats<<<NG, 256, 0, stream>>>(bufA, batch, gn1w, gn1b, gn1ms, tabA, tabB);
    k_gemm64n<<<NN / 100, 256, 0, stream>>>(bufA, batch, tabA, tabB, W2, h2);
    k_gather64<<<(NN * 64 + 255) / 256, 256, 0, stream>>>(h2, startv, degc, dinv, csr_col, b2, bufB);

    // layer 3
    k_gnstats<<<NG, 256, 0, stream>>>(bufB, batch, gn2w, gn2b, gn2ms, tabA, tabB);
    k_gemm64n<<<NN / 100, 256, 0, stream>>>(bufB, batch, tabA, tabB, W3, h2);
    k_gather64<<<(NN * 64 + 255) / 256, 256, 0, stream>>>(h2, startv, degc, dinv, csr_col, b3, bufA);

    // pool + head
    k_pool<<<NG, 1024, 0, stream>>>(bufA, batch, gpool);
    k_head<<<NG, 64, 0, stream>>>(gpool, Wd, bd, Wo, bo, outp);
}

// Round 4
// 627.627 us; speedup vs baseline: 1.6450x; 1.0375x over previous
//
#include <hip/hip_runtime.h>
#include <hip/hip_bf16.h>

#define NN 100000
#define NE 1600000
#define NG 256
#define FIN 16
#define HID 64
#define PASSES 8
#define PROWS 12500  // PASSES*PROWS == NN

__device__ __forceinline__ int lower_bound_i(const int* __restrict__ b, int n, int v) {
    int lo = 0, hi = n;
    while (lo < hi) { int m = (lo + hi) >> 1; if (b[m] < v) lo = m + 1; else hi = m; }
    return lo;
}

__device__ __forceinline__ unsigned pack_bf16(float a, float b) {
    unsigned ua = __float_as_uint(a), ub = __float_as_uint(b);
    ua = (ua + 0x7fffu + ((ua >> 16) & 1u)) >> 16;
    ub = (ub + 0x7fffu + ((ub >> 16) & 1u)) & 0xffff0000u;
    return ua | ub;
}
#define BF_LO(u) __uint_as_float((u) << 16)
#define BF_HI(u) __uint_as_float((u) & 0xffff0000u)

// ---- degree count -------------------------------------------------------
__global__ __launch_bounds__(256) void k_init(int* __restrict__ degc) {
    int i = blockIdx.x * blockDim.x + threadIdx.x;
    if (i < NN) degc[i] = 0;
}

__global__ __launch_bounds__(256) void k_count(const int* __restrict__ row, int* __restrict__ degc) {
    int t = blockIdx.x * blockDim.x + threadIdx.x;
    if (t * 4 >= NE) return;
    int4 r = ((const int4*)row)[t];
    atomicAdd(&degc[r.x], 1);
    atomicAdd(&degc[r.y], 1);
    atomicAdd(&degc[r.z], 1);
    atomicAdd(&degc[r.w], 1);
}

// ---- exclusive prefix sum over degc -> startv (monotonic) ---------------
__global__ __launch_bounds__(256) void k_scan1(const int* __restrict__ degc, int* __restrict__ startv,
                                               int* __restrict__ bsum) {
    __shared__ int sh[256];
    int t = threadIdx.x;
    int i = blockIdx.x * 256 + t;
    int v = (i < NN) ? degc[i] : 0;
    sh[t] = v;
    __syncthreads();
    int acc = v;
#pragma unroll
    for (int off = 1; off < 256; off <<= 1) {
        int add = (t >= off) ? sh[t - off] : 0;
        __syncthreads();
        acc += add;
        sh[t] = acc;
        __syncthreads();
    }
    if (i < NN) startv[i] = acc - v;
    if (t == 255) bsum[blockIdx.x] = acc;
}

__global__ __launch_bounds__(512) void k_scan2(const int* __restrict__ bsum, int* __restrict__ bofs) {
    __shared__ int sh[512];
    int t = threadIdx.x;
    const int NB = (NN + 255) / 256;  // 391
    int v = (t < NB) ? bsum[t] : 0;
    sh[t] = v;
    __syncthreads();
    int acc = v;
#pragma unroll
    for (int off = 1; off < 512; off <<= 1) {
        int add = (t >= off) ? sh[t - off] : 0;
        __syncthreads();
        acc += add;
        sh[t] = acc;
        __syncthreads();
    }
    if (t < NB) bofs[t] = acc - v;
}

__global__ __launch_bounds__(256) void k_scan3(const int* __restrict__ degc, int* __restrict__ startv,
                                               const int* __restrict__ bofs, float* __restrict__ dinv,
                                               int* __restrict__ fillcur) {
    int i = blockIdx.x * 256 + threadIdx.x;
    if (i >= NN) return;
    int s = startv[i] + bofs[blockIdx.x];
    startv[i] = s;
    fillcur[i] = s;
    dinv[i] = rsqrtf((float)(degc[i] + 1));
}

// ---- windowed CSR fill: only rows in [lo, lo+PROWS) this pass -----------
__global__ __launch_bounds__(256) void k_fillp(const int4* __restrict__ row4, const int4* __restrict__ col4,
                                               int* __restrict__ fillcur, int* __restrict__ csr_col, int lo) {
    int t = blockIdx.x * blockDim.x + threadIdx.x;
    if (t * 4 >= NE) return;
    int4 r = row4[t], c = col4[t];
    int hi = lo + PROWS;
    if (r.x >= lo && r.x < hi) { int pos = atomicAdd(&fillcur[r.x], 1); csr_col[pos] = c.x; }
    if (r.y >= lo && r.y < hi) { int pos = atomicAdd(&fillcur[r.y], 1); csr_col[pos] = c.y; }
    if (r.z >= lo && r.z < hi) { int pos = atomicAdd(&fillcur[r.z], 1); csr_col[pos] = c.z; }
    if (r.w >= lo && r.w < hi) { int pos = atomicAdd(&fillcur[r.w], 1); csr_col[pos] = c.w; }
}

// ---- GraphNorm layer 0 (C=16), writes packed bf16 -----------------------
__global__ __launch_bounds__(256) void k_graphnorm16(const float* __restrict__ x, const int* __restrict__ batch,
                              const float* __restrict__ w, const float* __restrict__ b,
                              const float* __restrict__ ms, unsigned* __restrict__ xb) {
    constexpr int C = FIN, NPB = 256 / C;
    __shared__ float red[NPB][C];
    __shared__ float mm_s[C];
    __shared__ float rstd_s[C];
    int g = blockIdx.x;
    int s = lower_bound_i(batch, NN, g);
    int e = lower_bound_i(batch, NN, g + 1);
    float fc = (float)max(e - s, 1);
    int c = threadIdx.x % C, slot = threadIdx.x / C;

    float acc = 0.f;
    for (int i = s + slot; i < e; i += NPB) acc += x[i * C + c];
    red[slot][c] = acc;
    __syncthreads();
    if (threadIdx.x < C) {
        float t = 0.f;
        for (int k = 0; k < NPB; k++) t += red[k][threadIdx.x];
        mm_s[threadIdx.x] = ms[threadIdx.x] * (t / fc);
    }
    __syncthreads();
    float mm = mm_s[c];
    float acc2 = 0.f;
    for (int i = s + slot; i < e; i += NPB) { float v = x[i * C + c] - mm; acc2 += v * v; }
    red[slot][c] = acc2;
    __syncthreads();
    if (threadIdx.x < C) {
        float t = 0.f;
        for (int k = 0; k < NPB; k++) t += red[k][threadIdx.x];
        rstd_s[threadIdx.x] = rsqrtf(t / fc + 1e-5f);
    }
    __syncthreads();
    float ww = w[c] * rstd_s[c], bb = b[c];
    for (int i = s + slot; i < e; i += NPB) {
        float v = ww * (x[i * C + c] - mm) + bb;
        float partner = __shfl_xor(v, 1);
        if ((c & 1) == 0) xb[(long)i * 8 + (c >> 1)] = pack_bf16(v, partner);
    }
}

// ---- GraphNorm stats only: affine tables A=w*rstd, B=b-A*ms*mean --------
__global__ __launch_bounds__(256) void k_gnstats(const float* __restrict__ x, const int* __restrict__ batch,
                          const float* __restrict__ w, const float* __restrict__ b,
                          const float* __restrict__ ms,
                          float* __restrict__ tabA, float* __restrict__ tabB) {
    constexpr int C = 64, NPB = 4;
    __shared__ float red[NPB][C];
    __shared__ float mm_s[C];
    int g = blockIdx.x;
    int s = lower_bound_i(batch, NN, g);
    int e = lower_bound_i(batch, NN, g + 1);
    float fc = (float)max(e - s, 1);
    int c = threadIdx.x & 63, slot = threadIdx.x >> 6;

    float acc = 0.f;
    for (int i = s + slot; i < e; i += NPB) acc += x[i * C + c];
    red[slot][c] = acc;
    __syncthreads();
    if (threadIdx.x < C) {
        float t = 0.f;
        for (int k = 0; k < NPB; k++) t += red[k][threadIdx.x];
        mm_s[threadIdx.x] = ms[threadIdx.x] * (t / fc);
    }
    __syncthreads();
    float mm = mm_s[c];
    float acc2 = 0.f;
    for (int i = s + slot; i < e; i += NPB) { float v = x[i * C + c] - mm; acc2 += v * v; }
    red[slot][c] = acc2;
    __syncthreads();
    if (threadIdx.x < C) {
        float t = 0.f;
        for (int k = 0; k < NPB; k++) t += red[k][threadIdx.x];
        float rstd = rsqrtf(t / fc + 1e-5f);
        float A = w[threadIdx.x] * rstd;
        tabA[g * C + threadIdx.x] = A;
        tabB[g * C + threadIdx.x] = b[threadIdx.x] - A * mm_s[threadIdx.x];
    }
}

// ---- fused 16-dim gather + 16->64 GEMM (+bias+relu), one wave per node --
__global__ __launch_bounds__(256) void k_gg16(const unsigned* __restrict__ xb, const int* __restrict__ startv,
                        const int* __restrict__ degc, const float* __restrict__ dinv,
                        const int* __restrict__ csr_col, const float* __restrict__ W,
                        const float* __restrict__ bias, float* __restrict__ out) {
    __shared__ float Ws[FIN * 64];
    for (int i = threadIdx.x; i < FIN * 64; i += 256) Ws[i] = W[i];
    __syncthreads();
    int wave = (blockIdx.x * blockDim.x + threadIdx.x) >> 6;
    if (wave >= NN) return;
    int lane = threadIdx.x & 63;
    int p = lane & 7, g = lane >> 3;
    int s = startv[wave], cnt = degc[wave];
    float di = dinv[wave];
    float ax = 0.f, ay = 0.f;
    int k = g;
    for (; k + 8 < cnt; k += 16) {
        int c0 = csr_col[s + k], c1 = csr_col[s + k + 8];
        float n0 = dinv[c0] * di, n1 = dinv[c1] * di;
        unsigned u0 = xb[(long)c0 * 8 + p], u1 = xb[(long)c1 * 8 + p];
        ax += n0 * BF_LO(u0) + n1 * BF_LO(u1);
        ay += n0 * BF_HI(u0) + n1 * BF_HI(u1);
    }
    for (; k < cnt; k += 8) {
        int c0 = csr_col[s + k];
        float n0 = dinv[c0] * di;
        unsigned u0 = xb[(long)c0 * 8 + p];
        ax += n0 * BF_LO(u0);
        ay += n0 * BF_HI(u0);
    }
    ax += __shfl_xor(ax, 8);  ay += __shfl_xor(ay, 8);
    ax += __shfl_xor(ax, 16); ay += __shfl_xor(ay, 16);
    ax += __shfl_xor(ax, 32); ay += __shfl_xor(ay, 32);
    if (g == 0) {  // lanes 0..7 now hold the full aggregate for channels (2p, 2p+1)
        unsigned u = xb[(long)wave * 8 + p];
        float sl = di * di;
        ax += sl * BF_LO(u);
        ay += sl * BF_HI(u);
    }
    // broadcast the 16 aggregated channels from lanes 0..7, mat-vec into 64 outputs
    int j = lane;
    float acc = bias[j];
#pragma unroll
    for (int kk = 0; kk < 8; kk++) {
        float vx = __shfl(ax, kk);
        float vy = __shfl(ay, kk);
        acc += vx * Ws[(2 * kk) * 64 + j] + vy * Ws[(2 * kk + 1) * 64 + j];
    }
    out[(long)wave * 64 + j] = fmaxf(acc, 0.f);
}

// ---- 64-dim gather (bf16 input): 2 edge-groups, 4-deep pipelined --------
__global__ __launch_bounds__(256) void k_gather64(const unsigned* __restrict__ h2, const int* __restrict__ startv,
                           const int* __restrict__ degc, const float* __restrict__ dinv,
                           const int* __restrict__ csr_col, const float* __restrict__ bias,
                           float* __restrict__ out) {
    int wave = (blockIdx.x * blockDim.x + threadIdx.x) >> 6;
    if (wave >= NN) return;
    int lane = threadIdx.x & 63;
    int p = lane & 31, g = lane >> 5;
    int s = startv[wave], cnt = degc[wave];
    float di = dinv[wave];
    float ax = 0.f, ay = 0.f;
    if (g == 0) {
        unsigned u = h2[(long)wave * 32 + p];
        float sl = di * di;
        ax = sl * BF_LO(u);
        ay = sl * BF_HI(u);
    }
    int k = g;
    for (; k + 6 < cnt; k += 8) {
        int c0 = csr_col[s + k], c1 = csr_col[s + k + 2],
            c2 = csr_col[s + k + 4], c3 = csr_col[s + k + 6];
        float n0 = dinv[c0] * di, n1 = dinv[c1] * di,
              n2 = dinv[c2] * di, n3 = dinv[c3] * di;
        unsigned u0 = h2[(long)c0 * 32 + p], u1 = h2[(long)c1 * 32 + p],
                 u2 = h2[(long)c2 * 32 + p], u3 = h2[(long)c3 * 32 + p];
        ax += n0 * BF_LO(u0) + n1 * BF_LO(u1) + n2 * BF_LO(u2) + n3 * BF_LO(u3);
        ay += n0 * BF_HI(u0) + n1 * BF_HI(u1) + n2 * BF_HI(u2) + n3 * BF_HI(u3);
    }
    for (; k < cnt; k += 2) {
        int c0 = csr_col[s + k];
        float n0 = dinv[c0] * di;
        unsigned u0 = h2[(long)c0 * 32 + p];
        ax += n0 * BF_LO(u0);
        ay += n0 * BF_HI(u0);
    }
    ax += __shfl_xor(ax, 32);
    ay += __shfl_xor(ay, 32);
    if (g == 0) {
        float2 r;
        r.x = fmaxf(ax + bias[2 * p], 0.f);
        r.y = fmaxf(ay + bias[2 * p + 1], 0.f);
        ((float2*)out)[(long)wave * 32 + p] = r;
    }
}

// ---- GEMM 64->64, GraphNorm affine fused, W column in regs, bf16 out ----
__global__ __launch_bounds__(256) void k_gemm64n(const float* __restrict__ x, const int* __restrict__ batch,
                          const float* __restrict__ tabA, const float* __restrict__ tabB,
                          const float* __restrict__ W, unsigned* __restrict__ h2) {
    constexpr int NPB = 100;  // 1000 blocks
    __shared__ float xs[NPB * 64];
    __shared__ int gb[NPB];
    int base = blockIdx.x * NPB;
    int j = threadIdx.x & 63;
    float w[64];
#pragma unroll
    for (int k = 0; k < 64; k++) w[k] = W[k * 64 + j];
    for (int i = threadIdx.x; i < NPB; i += 256) gb[i] = batch[base + i];
    __syncthreads();
    for (int i = threadIdx.x; i < NPB * 64; i += 256) {
        int node = i >> 6, c = i & 63;
        int g2 = gb[node];
        xs[i] = tabA[g2 * 64 + c] * x[(long)(base + node) * 64 + c] + tabB[g2 * 64 + c];
    }
    __syncthreads();
    int s0 = threadIdx.x >> 6;
    for (int r = 0; r < 25; r++) {
        int sl = s0 * 25 + r;
        const float4* xv = (const float4*)&xs[sl * 64];
        float acc = 0.f;
#pragma unroll
        for (int k4 = 0; k4 < 16; k4++) {
            float4 v = xv[k4];
            acc += v.x * w[4 * k4] + v.y * w[4 * k4 + 1] + v.z * w[4 * k4 + 2] + v.w * w[4 * k4 + 3];
        }
        float part = __shfl_xor(acc, 1);
        if ((j & 1) == 0) h2[(long)(base + sl) * 32 + (j >> 1)] = pack_bf16(acc, part);
    }
}

// ---- global mean pool ---------------------------------------------------
__global__ __launch_bounds__(1024) void k_pool(const float* __restrict__ x, const int* __restrict__ batch,
                       float* __restrict__ gpool) {
    __shared__ float red[16][64];
    int g = blockIdx.x;
    int s = lower_bound_i(batch, NN, g);
    int e = lower_bound_i(batch, NN, g + 1);
    int c = threadIdx.x & 63, slot = threadIdx.x >> 6;
    float acc = 0.f;
    for (int i = s + slot; i < e; i += 16) acc += x[i * 64 + c];
    red[slot][c] = acc;
    __syncthreads();
    if (threadIdx.x < 64) {
        float t = 0.f;
        for (int k = 0; k < 16; k++) t += red[k][threadIdx.x];
        gpool[g * 64 + threadIdx.x] = t / (float)max(e - s, 1);
    }
}

// ---- dense head + softmax ----------------------------------------------
__global__ __launch_bounds__(64) void k_head(const float* __restrict__ gpool, const float* __restrict__ Wd,
                       const float* __restrict__ bd, const float* __restrict__ Wo,
                       const float* __restrict__ bo, float* __restrict__ out) {
    int g = blockIdx.x, j = threadIdx.x;  // 64 threads
    __shared__ float gs[64];
    gs[j] = gpool[g * 64 + j];
    __syncthreads();
    float acc = bd[j];
    for (int k = 0; k < 64; k++) acc += gs[k] * Wd[k * 64 + j];
    float hv = fmaxf(acc, 0.f);
    float p0 = hv * Wo[j * 2 + 0], p1 = hv * Wo[j * 2 + 1];
    for (int off = 32; off; off >>= 1) { p0 += __shfl_down(p0, off); p1 += __shfl_down(p1, off); }
    if (j == 0) {
        float l0 = p0 + bo[0], l1 = p1 + bo[1];
        float m = fmaxf(l0, l1);
        float e0 = expf(l0 - m), e1 = expf(l1 - m);
        float inv = 1.f / (e0 + e1);
        out[g * 2 + 0] = e0 * inv;
        out[g * 2 + 1] = e1 * inv;
    }
}

extern "C" void kernel_launch(void* const* d_in, const int* in_sizes, int n_in,
                              void* d_out, int out_size, void* d_ws, size_t ws_size,
                              hipStream_t stream) {
    const float* x = (const float*)d_in[0];
    const int* ei = (const int*)d_in[1];
    const int* row = ei;
    const int* col = ei + NE;
    const int* batch = (const int*)d_in[2];
    const float* gn0w = (const float*)d_in[3];
    const float* gn0b = (const float*)d_in[4];
    const float* gn0ms = (const float*)d_in[5];
    const float* W1 = (const float*)d_in[6];
    const float* b1 = (const float*)d_in[7];
    const float* gn1w = (const float*)d_in[8];
    const float* gn1b = (const float*)d_in[9];
    const float* gn1ms = (const float*)d_in[10];
    const float* W2 = (const float*)d_in[11];
    const float* b2 = (const float*)d_in[12];
    const float* gn2w = (const float*)d_in[13];
    const float* gn2b = (const float*)d_in[14];
    const float* gn2ms = (const float*)d_in[15];
    const float* W3 = (const float*)d_in[16];
    const float* b3 = (const float*)d_in[17];
    const float* Wd = (const float*)d_in[18];
    const float* bd = (const float*)d_in[19];
    const float* Wo = (const float*)d_in[20];
    const float* bo = (const float*)d_in[21];
    float* outp = (float*)d_out;

    // workspace layout
    int* degc = (int*)d_ws;                        // NN
    float* dinv = (float*)(degc + NN);             // NN
    int* startv = (int*)(dinv + NN);               // NN
    int* fillcur = startv + NN;                    // NN
    int* bsum = fillcur + NN;                      // 512
    int* bofs = bsum + 512;                        // 512
    int* csr_col = bofs + 512;                     // NE
    float* bufA = (float*)(csr_col + NE);          // NN*64
    float* bufB = bufA + (long)NN * HID;           // NN*64
    unsigned* h2 = (unsigned*)(bufB + (long)NN * HID);  // NN*32
    unsigned* xb = h2 + (long)NN * 32;             // NN*8
    float* tabA = (float*)(xb + (long)NN * 8);     // NG*64
    float* tabB = tabA + NG * HID;                 // NG*64
    float* gpool = tabB + NG * HID;                // NG*64

    const int NB = (NN + 255) / 256;  // 391

    // degree count + deterministic scan + windowed fill
    k_init<<<NB, 256, 0, stream>>>(degc);
    k_count<<<(NE / 4 + 255) / 256, 256, 0, stream>>>(row, degc);
    k_scan1<<<NB, 256, 0, stream>>>(degc, startv, bsum);
    k_scan2<<<1, 512, 0, stream>>>(bsum, bofs);
    k_scan3<<<NB, 256, 0, stream>>>(degc, startv, bofs, dinv, fillcur);
    for (int pss = 0; pss < PASSES; pss++)
        k_fillp<<<(NE / 4 + 255) / 256, 256, 0, stream>>>((const int4*)row, (const int4*)col,
                                                          fillcur, csr_col, pss * PROWS);

    // layer 1: norm(16,bf16) -> fused aggregate+gemm 16->64 (+bias+relu)
    k_graphnorm16<<<NG, 256, 0, stream>>>(x, batch, gn0w, gn0b, gn0ms, xb);
    k_gg16<<<(NN * 64 + 255) / 256, 256, 0, stream>>>(xb, startv, degc, dinv, csr_col, W1, b1, bufA);

    // layer 2: stats -> fused-norm gemm (bf16 out) -> gather(+bias+relu)
    k_gnstats<<<NG, 256, 0, stream>>>(bufA, batch, gn1w, gn1b, gn1ms, tabA, tabB);
    k_gemm64n<<<NN / 100, 256, 0, stream>>>(bufA, batch, tabA, tabB, W2, h2);
    k_gather64<<<(NN * 64 + 255) / 256, 256, 0, stream>>>(h2, startv, degc, dinv, csr_col, b2, bufB);

    // layer 3
    k_gnstats<<<NG, 256, 0, stream>>>(bufB, batch, gn2w, gn2b, gn2ms, tabA, tabB);
    k_gemm64n<<<NN / 100, 256, 0, stream>>>(bufB, batch, tabA, tabB, W3, h2);
    k_gather64<<<(NN * 64 + 255) / 256, 256, 0, stream>>>(h2, startv, degc, dinv, csr_col, b3, bufA);

    // pool + head
    k_pool<<<NG, 1024, 0, stream>>>(bufA, batch, gpool);
    k_head<<<NG, 64, 0, stream>>>(gpool, Wd, bd, Wo, bo, outp);
}

// Round 5
// 454.910 us; speedup vs baseline: 2.2696x; 1.3797x over previous
//
#include <hip/hip_runtime.h>
#include <hip/hip_bf16.h>

#define NN 100000
#define NE 1600000
#define NG 256
#define FIN 16
#define HID 64
#define NBK 391    // buckets of 256 rows; 391*256 = 100096 >= NN
#define NTILE 391  // ceil(NE/4096)
#define PMAX 4864  // max edges per bucket (mean 4092, sigma ~64)

__device__ __forceinline__ int lower_bound_i(const int* __restrict__ b, int n, int v) {
    int lo = 0, hi = n;
    while (lo < hi) { int m = (lo + hi) >> 1; if (b[m] < v) lo = m + 1; else hi = m; }
    return lo;
}

__device__ __forceinline__ unsigned pack_bf16(float a, float b) {
    unsigned ua = __float_as_uint(a), ub = __float_as_uint(b);
    ua = (ua + 0x7fffu + ((ua >> 16) & 1u)) >> 16;
    ub = (ub + 0x7fffu + ((ub >> 16) & 1u)) & 0xffff0000u;
    return ua | ub;
}
#define BF_LO(u) __uint_as_float((u) << 16)
#define BF_HI(u) __uint_as_float((u) & 0xffff0000u)

// ==================== CSR build: 2-level LDS bucket sort ====================
__global__ __launch_bounds__(512) void k_zb(int* __restrict__ bhist) {
    bhist[threadIdx.x] = 0;
}

__global__ __launch_bounds__(512) void k_bhist(const int4* __restrict__ row4, int* __restrict__ bhist) {
    __shared__ int h[NBK];
    for (int i = threadIdx.x; i < NBK; i += 512) h[i] = 0;
    __syncthreads();
    int t0 = blockIdx.x * 1024 + threadIdx.x;
#pragma unroll
    for (int it = 0; it < 2; ++it) {
        int t = t0 + it * 512;
        if (t < NE / 4) {
            int4 r = row4[t];
            atomicAdd(&h[r.x >> 8], 1); atomicAdd(&h[r.y >> 8], 1);
            atomicAdd(&h[r.z >> 8], 1); atomicAdd(&h[r.w >> 8], 1);
        }
    }
    __syncthreads();
    for (int i = threadIdx.x; i < NBK; i += 512)
        if (h[i]) atomicAdd(&bhist[i], h[i]);
}

__global__ __launch_bounds__(512) void k_bscan(const int* __restrict__ bhist, int* __restrict__ bbase,
                                               int* __restrict__ bcur) {
    __shared__ int sc[512];
    int t = threadIdx.x;
    int v = (t < NBK) ? bhist[t] : 0;
    sc[t] = v;
    __syncthreads();
    int acc = v;
    for (int off = 1; off < 512; off <<= 1) {
        int add = (t >= off) ? sc[t - off] : 0;
        __syncthreads();
        acc += add;
        sc[t] = acc;
        __syncthreads();
    }
    if (t < NBK) { bbase[t] = acc - v; bcur[t] = acc - v; }
    if (t == NBK - 1) bbase[NBK] = acc;  // == NE
}

__global__ __launch_bounds__(512) void k_bscatter(const int4* __restrict__ row4, const int4* __restrict__ col4,
                                                  int* __restrict__ bcur, int2* __restrict__ pairs) {
    __shared__ int lh[NBK], lofs[NBK], lbase[NBK], lc[NBK];
    __shared__ int sc[512];
    __shared__ int2 stg[4096];
    for (int i = threadIdx.x; i < NBK; i += 512) { lh[i] = 0; lc[i] = 0; }
    __syncthreads();
    int t0 = blockIdx.x * 1024 + threadIdx.x;
#pragma unroll
    for (int it = 0; it < 2; ++it) {
        int t = t0 + it * 512;
        if (t < NE / 4) {
            int4 r = row4[t];
            atomicAdd(&lh[r.x >> 8], 1); atomicAdd(&lh[r.y >> 8], 1);
            atomicAdd(&lh[r.z >> 8], 1); atomicAdd(&lh[r.w >> 8], 1);
        }
    }
    __syncthreads();
    {   // local exclusive scan lh -> lofs
        int t = threadIdx.x;
        int v = (t < NBK) ? lh[t] : 0;
        sc[t] = v;
        __syncthreads();
        int acc = v;
        for (int off = 1; off < 512; off <<= 1) {
            int add = (t >= off) ? sc[t - off] : 0;
            __syncthreads();
            acc += add;
            sc[t] = acc;
            __syncthreads();
        }
        if (t < NBK) lofs[t] = acc - v;
    }
    if (threadIdx.x < NBK) {  // reserve global ranges
        int c = lh[threadIdx.x];
        lbase[threadIdx.x] = c ? atomicAdd(&bcur[threadIdx.x], c) : 0;
    }
    __syncthreads();
#pragma unroll
    for (int it = 0; it < 2; ++it) {  // stage to LDS at locally-sorted positions
        int t = t0 + it * 512;
        if (t < NE / 4) {
            int4 r = row4[t];
            int4 c = col4[t];
            int b, rk;
            b = r.x >> 8; rk = atomicAdd(&lc[b], 1); stg[lofs[b] + rk] = make_int2(r.x, c.x);
            b = r.y >> 8; rk = atomicAdd(&lc[b], 1); stg[lofs[b] + rk] = make_int2(r.y, c.y);
            b = r.z >> 8; rk = atomicAdd(&lc[b], 1); stg[lofs[b] + rk] = make_int2(r.z, c.z);
            b = r.w >> 8; rk = atomicAdd(&lc[b], 1); stg[lofs[b] + rk] = make_int2(r.w, c.w);
        }
    }
    __syncthreads();
    int nv = min(4096, NE - blockIdx.x * 4096);
    for (int j = threadIdx.x; j < nv; j += 512) {  // run-coalesced global write
        int2 p = stg[j];
        int b = p.x >> 8;
        pairs[lbase[b] + (j - lofs[b])] = p;
    }
}

__global__ __launch_bounds__(256) void k_bsort(const int2* __restrict__ pairs, const int* __restrict__ bbase,
                                               int* __restrict__ csr_col, int* __restrict__ startv,
                                               int* __restrict__ degc, float* __restrict__ dinv) {
    __shared__ int2 prs[PMAX];
    __shared__ int colo[PMAX];
    __shared__ int cnt[256], ofs[256], c2[256], sc[256];
    int b = blockIdx.x;
    int s = bbase[b];
    int n = min(bbase[b + 1] - s, PMAX);
    cnt[threadIdx.x] = 0;
    c2[threadIdx.x] = 0;
    __syncthreads();
    for (int i = threadIdx.x; i < n; i += 256) {
        int2 p = pairs[s + i];
        prs[i] = p;
        atomicAdd(&cnt[p.x & 255], 1);
    }
    __syncthreads();
    {   // exclusive scan cnt -> ofs
        int t = threadIdx.x, v = cnt[t];
        sc[t] = v;
        __syncthreads();
        int acc = v;
        for (int off = 1; off < 256; off <<= 1) {
            int add = (t >= off) ? sc[t - off] : 0;
            __syncthreads();
            acc += add;
            sc[t] = acc;
            __syncthreads();
        }
        ofs[t] = acc - v;
    }
    __syncthreads();
    for (int i = threadIdx.x; i < n; i += 256) {
        int2 p = prs[i];
        int lr = p.x & 255;
        int rk = atomicAdd(&c2[lr], 1);
        colo[ofs[lr] + rk] = p.y;
    }
    __syncthreads();
    for (int i = threadIdx.x; i < n; i += 256) csr_col[s + i] = colo[i];
    int r = (b << 8) + threadIdx.x;
    if (r < NN) {
        int c = cnt[threadIdx.x];
        startv[r] = s + ofs[threadIdx.x];
        degc[r] = c;
        dinv[r] = rsqrtf((float)(c + 1));
    }
}

// ==================== GraphNorm layer 0 (C=16) -> bf16, pre-scaled by dinv ==
__global__ __launch_bounds__(256) void k_graphnorm16(const float* __restrict__ x, const int* __restrict__ batch,
                              const float* __restrict__ w, const float* __restrict__ b,
                              const float* __restrict__ ms, const float* __restrict__ dinv,
                              unsigned* __restrict__ xb) {
    constexpr int C = FIN, NPB = 256 / C;
    __shared__ float red[NPB][C], red2[NPB][C];
    __shared__ float mm_s[C], rs_s[C];
    int g = blockIdx.x;
    int s = lower_bound_i(batch, NN, g);
    int e = lower_bound_i(batch, NN, g + 1);
    float fc = (float)max(e - s, 1);
    int c = threadIdx.x % C, slot = threadIdx.x / C;

    float a1 = 0.f, a2 = 0.f;
    for (int i = s + slot; i < e; i += NPB) { float v = x[i * C + c]; a1 += v; a2 += v * v; }
    red[slot][c] = a1;
    red2[slot][c] = a2;
    __syncthreads();
    if (threadIdx.x < C) {
        float t1 = 0.f, t2 = 0.f;
        for (int k = 0; k < NPB; k++) { t1 += red[k][threadIdx.x]; t2 += red2[k][threadIdx.x]; }
        float mean = t1 / fc;
        float mm = ms[threadIdx.x] * mean;
        float var = t2 / fc - 2.f * mm * mean + mm * mm;
        mm_s[threadIdx.x] = mm;
        rs_s[threadIdx.x] = rsqrtf(var + 1e-5f);
    }
    __syncthreads();
    float mm = mm_s[c], ww = w[c] * rs_s[c], bb = b[c];
    for (int i = s + slot; i < e; i += NPB) {
        float v = (ww * (x[i * C + c] - mm) + bb) * dinv[i];
        float partner = __shfl_xor(v, 1);
        if ((c & 1) == 0) xb[(long)i * 8 + (c >> 1)] = pack_bf16(v, partner);
    }
}

// ==================== GraphNorm stats (C=64) one-pass -> affine tables ======
__global__ __launch_bounds__(256) void k_gnstats(const float* __restrict__ x, const int* __restrict__ batch,
                          const float* __restrict__ w, const float* __restrict__ b,
                          const float* __restrict__ ms,
                          float* __restrict__ tabA, float* __restrict__ tabB) {
    constexpr int C = 64, NPB = 4;
    __shared__ float red[NPB][C], red2[NPB][C];
    int g = blockIdx.x;
    int s = lower_bound_i(batch, NN, g);
    int e = lower_bound_i(batch, NN, g + 1);
    float fc = (float)max(e - s, 1);
    int c = threadIdx.x & 63, slot = threadIdx.x >> 6;

    float a1 = 0.f, a2 = 0.f;
    for (int i = s + slot; i < e; i += NPB) { float v = x[i * C + c]; a1 += v; a2 += v * v; }
    red[slot][c] = a1;
    red2[slot][c] = a2;
    __syncthreads();
    if (threadIdx.x < C) {
        float t1 = 0.f, t2 = 0.f;
        for (int k = 0; k < NPB; k++) { t1 += red[k][threadIdx.x]; t2 += red2[k][threadIdx.x]; }
        float mean = t1 / fc;
        float mm = ms[threadIdx.x] * mean;
        float var = t2 / fc - 2.f * mm * mean + mm * mm;
        float A = w[threadIdx.x] * rsqrtf(var + 1e-5f);
        tabA[g * C + threadIdx.x] = A;
        tabB[g * C + threadIdx.x] = b[threadIdx.x] - A * mm;
    }
}

// ==== fused 16-dim gather (pre-scaled bf16) + 16->64 GEMM (+bias+relu) =====
__global__ __launch_bounds__(256) void k_gg16(const unsigned* __restrict__ xb, const int* __restrict__ startv,
                        const int* __restrict__ degc, const float* __restrict__ dinv,
                        const int* __restrict__ csr_col, const float* __restrict__ W,
                        const float* __restrict__ bias, float* __restrict__ out) {
    __shared__ float Ws[FIN * 64];
    for (int i = threadIdx.x; i < FIN * 64; i += 256) Ws[i] = W[i];
    __syncthreads();
    int wave = (blockIdx.x * blockDim.x + threadIdx.x) >> 6;
    if (wave >= NN) return;
    int lane = threadIdx.x & 63;
    int p = lane & 7, g = lane >> 3;
    int s = startv[wave], cnt = degc[wave];
    float di = dinv[wave];
    float ax = 0.f, ay = 0.f;
    int k = g;
    for (; k + 8 < cnt; k += 16) {
        int c0 = csr_col[s + k], c1 = csr_col[s + k + 8];
        unsigned u0 = xb[(long)c0 * 8 + p], u1 = xb[(long)c1 * 8 + p];
        ax += BF_LO(u0) + BF_LO(u1);
        ay += BF_HI(u0) + BF_HI(u1);
    }
    for (; k < cnt; k += 8) {
        int c0 = csr_col[s + k];
        unsigned u0 = xb[(long)c0 * 8 + p];
        ax += BF_LO(u0);
        ay += BF_HI(u0);
    }
    ax += __shfl_xor(ax, 8);  ay += __shfl_xor(ay, 8);
    ax += __shfl_xor(ax, 16); ay += __shfl_xor(ay, 16);
    ax += __shfl_xor(ax, 32); ay += __shfl_xor(ay, 32);
    if (g == 0) {  // lanes 0..7: add self (pre-scaled), scale by dinv[i]
        unsigned u = xb[(long)wave * 8 + p];
        ax = (ax + BF_LO(u)) * di;
        ay = (ay + BF_HI(u)) * di;
    }
    int j = lane;
    float acc = bias[j];
#pragma unroll
    for (int kk = 0; kk < 8; kk++) {
        float vx = __shfl(ax, kk);
        float vy = __shfl(ay, kk);
        acc += vx * Ws[(2 * kk) * 64 + j] + vy * Ws[(2 * kk + 1) * 64 + j];
    }
    out[(long)wave * 64 + j] = fmaxf(acc, 0.f);
}

// ==== 64-dim gather (pre-scaled bf16): pure-add inner loop =================
__global__ __launch_bounds__(256) void k_gather64(const unsigned* __restrict__ h2, const int* __restrict__ startv,
                           const int* __restrict__ degc, const float* __restrict__ dinv,
                           const int* __restrict__ csr_col, const float* __restrict__ bias,
                           float* __restrict__ out) {
    int wave = (blockIdx.x * blockDim.x + threadIdx.x) >> 6;
    if (wave >= NN) return;
    int lane = threadIdx.x & 63;
    int p = lane & 31, g = lane >> 5;
    int s = startv[wave], cnt = degc[wave];
    float di = dinv[wave];
    float ax = 0.f, ay = 0.f;
    if (g == 0) {  // self term (pre-scaled by dinv[i] already)
        unsigned u = h2[(long)wave * 32 + p];
        ax = BF_LO(u);
        ay = BF_HI(u);
    }
    int k = g;
    for (; k + 6 < cnt; k += 8) {
        int c0 = csr_col[s + k], c1 = csr_col[s + k + 2],
            c2 = csr_col[s + k + 4], c3 = csr_col[s + k + 6];
        unsigned u0 = h2[(long)c0 * 32 + p], u1 = h2[(long)c1 * 32 + p],
                 u2 = h2[(long)c2 * 32 + p], u3 = h2[(long)c3 * 32 + p];
        ax += BF_LO(u0) + BF_LO(u1) + BF_LO(u2) + BF_LO(u3);
        ay += BF_HI(u0) + BF_HI(u1) + BF_HI(u2) + BF_HI(u3);
    }
    for (; k < cnt; k += 2) {
        int c0 = csr_col[s + k];
        unsigned u0 = h2[(long)c0 * 32 + p];
        ax += BF_LO(u0);
        ay += BF_HI(u0);
    }
    ax += __shfl_xor(ax, 32);
    ay += __shfl_xor(ay, 32);
    if (g == 0) {
        float2 r;
        r.x = fmaxf(ax * di + bias[2 * p], 0.f);
        r.y = fmaxf(ay * di + bias[2 * p + 1], 0.f);
        ((float2*)out)[(long)wave * 32 + p] = r;
    }
}

// ==== GEMM 64->64, GraphNorm affine fused, output bf16 pre-scaled by dinv ==
__global__ __launch_bounds__(256) void k_gemm64n(const float* __restrict__ x, const int* __restrict__ batch,
                          const float* __restrict__ tabA, const float* __restrict__ tabB,
                          const float* __restrict__ W, const float* __restrict__ dinv,
                          unsigned* __restrict__ h2) {
    constexpr int NPB = 100;  // 1000 blocks
    __shared__ float xs[NPB * 64];
    __shared__ int gb[NPB];
    int base = blockIdx.x * NPB;
    int j = threadIdx.x & 63;
    float w[64];
#pragma unroll
    for (int k = 0; k < 64; k++) w[k] = W[k * 64 + j];
    for (int i = threadIdx.x; i < NPB; i += 256) gb[i] = batch[base + i];
    __syncthreads();
    for (int i = threadIdx.x; i < NPB * 64; i += 256) {
        int node = i >> 6, c = i & 63;
        int g2 = gb[node];
        xs[i] = tabA[g2 * 64 + c] * x[(long)(base + node) * 64 + c] + tabB[g2 * 64 + c];
    }
    __syncthreads();
    int s0 = threadIdx.x >> 6;
    for (int r = 0; r < 25; r++) {
        int sl = s0 * 25 + r;
        const float4* xv = (const float4*)&xs[sl * 64];
        float acc = 0.f;
#pragma unroll
        for (int k4 = 0; k4 < 16; k4++) {
            float4 v = xv[k4];
            acc += v.x * w[4 * k4] + v.y * w[4 * k4 + 1] + v.z * w[4 * k4 + 2] + v.w * w[4 * k4 + 3];
        }
        acc *= dinv[base + sl];
        float part = __shfl_xor(acc, 1);
        if ((j & 1) == 0) h2[(long)(base + sl) * 32 + (j >> 1)] = pack_bf16(acc, part);
    }
}

// ==================== global mean pool + head ==============================
__global__ __launch_bounds__(1024) void k_pool(const float* __restrict__ x, const int* __restrict__ batch,
                       float* __restrict__ gpool) {
    __shared__ float red[16][64];
    int g = blockIdx.x;
    int s = lower_bound_i(batch, NN, g);
    int e = lower_bound_i(batch, NN, g + 1);
    int c = threadIdx.x & 63, slot = threadIdx.x >> 6;
    float acc = 0.f;
    for (int i = s + slot; i < e; i += 16) acc += x[i * 64 + c];
    red[slot][c] = acc;
    __syncthreads();
    if (threadIdx.x < 64) {
        float t = 0.f;
        for (int k = 0; k < 16; k++) t += red[k][threadIdx.x];
        gpool[g * 64 + threadIdx.x] = t / (float)max(e - s, 1);
    }
}

__global__ __launch_bounds__(64) void k_head(const float* __restrict__ gpool, const float* __restrict__ Wd,
                       const float* __restrict__ bd, const float* __restrict__ Wo,
                       const float* __restrict__ bo, float* __restrict__ out) {
    int g = blockIdx.x, j = threadIdx.x;  // 64 threads
    __shared__ float gs[64];
    gs[j] = gpool[g * 64 + j];
    __syncthreads();
    float acc = bd[j];
    for (int k = 0; k < 64; k++) acc += gs[k] * Wd[k * 64 + j];
    float hv = fmaxf(acc, 0.f);
    float p0 = hv * Wo[j * 2 + 0], p1 = hv * Wo[j * 2 + 1];
    for (int off = 32; off; off >>= 1) { p0 += __shfl_down(p0, off); p1 += __shfl_down(p1, off); }
    if (j == 0) {
        float l0 = p0 + bo[0], l1 = p1 + bo[1];
        float m = fmaxf(l0, l1);
        float e0 = expf(l0 - m), e1 = expf(l1 - m);
        float inv = 1.f / (e0 + e1);
        out[g * 2 + 0] = e0 * inv;
        out[g * 2 + 1] = e1 * inv;
    }
}

extern "C" void kernel_launch(void* const* d_in, const int* in_sizes, int n_in,
                              void* d_out, int out_size, void* d_ws, size_t ws_size,
                              hipStream_t stream) {
    const float* x = (const float*)d_in[0];
    const int* ei = (const int*)d_in[1];
    const int* row = ei;
    const int* col = ei + NE;
    const int* batch = (const int*)d_in[2];
    const float* gn0w = (const float*)d_in[3];
    const float* gn0b = (const float*)d_in[4];
    const float* gn0ms = (const float*)d_in[5];
    const float* W1 = (const float*)d_in[6];
    const float* b1 = (const float*)d_in[7];
    const float* gn1w = (const float*)d_in[8];
    const float* gn1b = (const float*)d_in[9];
    const float* gn1ms = (const float*)d_in[10];
    const float* W2 = (const float*)d_in[11];
    const float* b2 = (const float*)d_in[12];
    const float* gn2w = (const float*)d_in[13];
    const float* gn2b = (const float*)d_in[14];
    const float* gn2ms = (const float*)d_in[15];
    const float* W3 = (const float*)d_in[16];
    const float* b3 = (const float*)d_in[17];
    const float* Wd = (const float*)d_in[18];
    const float* bd = (const float*)d_in[19];
    const float* Wo = (const float*)d_in[20];
    const float* bo = (const float*)d_in[21];
    float* outp = (float*)d_out;

    // workspace layout
    int* bhist = (int*)d_ws;                       // 512
    int* bbase = bhist + 512;                      // 512 (needs NBK+1)
    int* bcur = bbase + 512;                       // 512
    int* startv = bcur + 512;                      // NN
    int* degc = startv + NN;                       // NN
    float* dinv = (float*)(degc + NN);             // NN
    int* csr_col = (int*)(dinv + NN);              // NE
    float* bufA = (float*)(csr_col + NE);          // NN*64
    float* bufB = bufA + (long)NN * HID;           // NN*64
    unsigned* h2 = (unsigned*)(bufB + (long)NN * HID);  // NN*32
    unsigned* xb = h2 + (long)NN * 32;             // NN*8
    float* tabA = (float*)(xb + (long)NN * 8);     // NG*64
    float* tabB = tabA + NG * HID;                 // NG*64
    float* gpool = tabB + NG * HID;                // NG*64
    int2* pairs = (int2*)bufA;                     // alias: NE int2 = 12.8MB <= 25.6MB, dead before bufA use

    // ---- CSR build (bucket sort, coalesced writes) ----
    k_zb<<<1, 512, 0, stream>>>(bhist);
    k_bhist<<<NTILE, 512, 0, stream>>>((const int4*)row, bhist);
    k_bscan<<<1, 512, 0, stream>>>(bhist, bbase, bcur);
    k_bscatter<<<NTILE, 512, 0, stream>>>((const int4*)row, (const int4*)col, bcur, pairs);
    k_bsort<<<NBK, 256, 0, stream>>>(pairs, bbase, csr_col, startv, degc, dinv);

    // layer 1: norm(16, bf16, dinv-prescaled) -> fused aggregate+gemm
    k_graphnorm16<<<NG, 256, 0, stream>>>(x, batch, gn0w, gn0b, gn0ms, dinv, xb);
    k_gg16<<<(NN * 64 + 255) / 256, 256, 0, stream>>>(xb, startv, degc, dinv, csr_col, W1, b1, bufA);

    // layer 2
    k_gnstats<<<NG, 256, 0, stream>>>(bufA, batch, gn1w, gn1b, gn1ms, tabA, tabB);
    k_gemm64n<<<NN / 100, 256, 0, stream>>>(bufA, batch, tabA, tabB, W2, dinv, h2);
    k_gather64<<<(NN * 64 + 255) / 256, 256, 0, stream>>>(h2, startv, degc, dinv, csr_col, b2, bufB);

    // layer 3
    k_gnstats<<<NG, 256, 0, stream>>>(bufB, batch, gn2w, gn2b, gn2ms, tabA, tabB);
    k_gemm64n<<<NN / 100, 256, 0, stream>>>(bufB, batch, tabA, tabB, W3, dinv, h2);
    k_gather64<<<(NN * 64 + 255) / 256, 256, 0, stream>>>(h2, startv, degc, dinv, csr_col, b3, bufA);

    // pool + head
    k_pool<<<NG, 1024, 0, stream>>>(bufA, batch, gpool);
    k_head<<<NG, 64, 0, stream>>>(gpool, Wd, bd, Wo, bo, outp);
}

// Round 6
// 440.487 us; speedup vs baseline: 2.3439x; 1.0327x over previous
//
#include <hip/hip_runtime.h>
#include <hip/hip_bf16.h>

#define NN 100000
#define NE 1600000
#define NG 256
#define FIN 16
#define HID 64
#define NBK 391    // buckets of 256 rows; 391*256 = 100096 >= NN
#define NTILE 391  // ceil(NE/4096)
#define PMAX 4864  // max edges per bucket (mean 4092)
#define MAXT (NN / 16 + NG)  // max graph-aligned 16-node tiles = 6506

__device__ __forceinline__ int lower_bound_i(const int* __restrict__ b, int n, int v) {
    int lo = 0, hi = n;
    while (lo < hi) { int m = (lo + hi) >> 1; if (b[m] < v) lo = m + 1; else hi = m; }
    return lo;
}

__device__ __forceinline__ unsigned pack_bf16(float a, float b) {
    unsigned ua = __float_as_uint(a), ub = __float_as_uint(b);
    ua = (ua + 0x7fffu + ((ua >> 16) & 1u)) >> 16;
    ub = (ub + 0x7fffu + ((ub >> 16) & 1u)) & 0xffff0000u;
    return ua | ub;
}
#define BF_LO(u) __uint_as_float((u) << 16)
#define BF_HI(u) __uint_as_float((u) & 0xffff0000u)

typedef __attribute__((ext_vector_type(8))) short bf16x8;
typedef __attribute__((ext_vector_type(4))) float f32x4;
union FU { uint4 u; bf16x8 v; };

// ==================== CSR build: 2-level LDS bucket sort ====================
__global__ __launch_bounds__(512) void k_zb(int* __restrict__ bhist) {
    bhist[threadIdx.x] = 0;
}

__global__ __launch_bounds__(512) void k_bhist(const int4* __restrict__ row4, int* __restrict__ bhist) {
    __shared__ int h[NBK];
    for (int i = threadIdx.x; i < NBK; i += 512) h[i] = 0;
    __syncthreads();
    int t0 = blockIdx.x * 1024 + threadIdx.x;
#pragma unroll
    for (int it = 0; it < 2; ++it) {
        int t = t0 + it * 512;
        if (t < NE / 4) {
            int4 r = row4[t];
            atomicAdd(&h[r.x >> 8], 1); atomicAdd(&h[r.y >> 8], 1);
            atomicAdd(&h[r.z >> 8], 1); atomicAdd(&h[r.w >> 8], 1);
        }
    }
    __syncthreads();
    for (int i = threadIdx.x; i < NBK; i += 512)
        if (h[i]) atomicAdd(&bhist[i], h[i]);
}

__global__ __launch_bounds__(512) void k_bscan(const int* __restrict__ bhist, int* __restrict__ bbase,
                                               int* __restrict__ bcur) {
    __shared__ int sc[512];
    int t = threadIdx.x;
    int v = (t < NBK) ? bhist[t] : 0;
    sc[t] = v;
    __syncthreads();
    int acc = v;
    for (int off = 1; off < 512; off <<= 1) {
        int add = (t >= off) ? sc[t - off] : 0;
        __syncthreads();
        acc += add;
        sc[t] = acc;
        __syncthreads();
    }
    if (t < NBK) { bbase[t] = acc - v; bcur[t] = acc - v; }
    if (t == NBK - 1) bbase[NBK] = acc;
}

__global__ __launch_bounds__(512) void k_bscatter(const int4* __restrict__ row4, const int4* __restrict__ col4,
                                                  int* __restrict__ bcur, int2* __restrict__ pairs) {
    __shared__ int lh[NBK], lofs[NBK], lbase[NBK], lc[NBK];
    __shared__ int sc[512];
    __shared__ int2 stg[4096];
    for (int i = threadIdx.x; i < NBK; i += 512) { lh[i] = 0; lc[i] = 0; }
    __syncthreads();
    int t0 = blockIdx.x * 1024 + threadIdx.x;
#pragma unroll
    for (int it = 0; it < 2; ++it) {
        int t = t0 + it * 512;
        if (t < NE / 4) {
            int4 r = row4[t];
            atomicAdd(&lh[r.x >> 8], 1); atomicAdd(&lh[r.y >> 8], 1);
            atomicAdd(&lh[r.z >> 8], 1); atomicAdd(&lh[r.w >> 8], 1);
        }
    }
    __syncthreads();
    {
        int t = threadIdx.x;
        int v = (t < NBK) ? lh[t] : 0;
        sc[t] = v;
        __syncthreads();
        int acc = v;
        for (int off = 1; off < 512; off <<= 1) {
            int add = (t >= off) ? sc[t - off] : 0;
            __syncthreads();
            acc += add;
            sc[t] = acc;
            __syncthreads();
        }
        if (t < NBK) lofs[t] = acc - v;
    }
    if (threadIdx.x < NBK) {
        int c = lh[threadIdx.x];
        lbase[threadIdx.x] = c ? atomicAdd(&bcur[threadIdx.x], c) : 0;
    }
    __syncthreads();
#pragma unroll
    for (int it = 0; it < 2; ++it) {
        int t = t0 + it * 512;
        if (t < NE / 4) {
            int4 r = row4[t];
            int4 c = col4[t];
            int b, rk;
            b = r.x >> 8; rk = atomicAdd(&lc[b], 1); stg[lofs[b] + rk] = make_int2(r.x, c.x);
            b = r.y >> 8; rk = atomicAdd(&lc[b], 1); stg[lofs[b] + rk] = make_int2(r.y, c.y);
            b = r.z >> 8; rk = atomicAdd(&lc[b], 1); stg[lofs[b] + rk] = make_int2(r.z, c.z);
            b = r.w >> 8; rk = atomicAdd(&lc[b], 1); stg[lofs[b] + rk] = make_int2(r.w, c.w);
        }
    }
    __syncthreads();
    int nv = min(4096, NE - blockIdx.x * 4096);
    for (int j = threadIdx.x; j < nv; j += 512) {
        int2 p = stg[j];
        int b = p.x >> 8;
        pairs[lbase[b] + (j - lofs[b])] = p;
    }
}

__global__ __launch_bounds__(256) void k_bsort(const int2* __restrict__ pairs, const int* __restrict__ bbase,
                                               int* __restrict__ csr_col, int* __restrict__ startv,
                                               int* __restrict__ degc, float* __restrict__ dinv) {
    __shared__ int2 prs[PMAX];
    __shared__ int colo[PMAX];
    __shared__ int cnt[256], ofs[256], c2[256], sc[256];
    int b = blockIdx.x;
    int s = bbase[b];
    int n = min(bbase[b + 1] - s, PMAX);
    cnt[threadIdx.x] = 0;
    c2[threadIdx.x] = 0;
    __syncthreads();
    for (int i = threadIdx.x; i < n; i += 256) {
        int2 p = pairs[s + i];
        prs[i] = p;
        atomicAdd(&cnt[p.x & 255], 1);
    }
    __syncthreads();
    {
        int t = threadIdx.x, v = cnt[t];
        sc[t] = v;
        __syncthreads();
        int acc = v;
        for (int off = 1; off < 256; off <<= 1) {
            int add = (t >= off) ? sc[t - off] : 0;
            __syncthreads();
            acc += add;
            sc[t] = acc;
            __syncthreads();
        }
        ofs[t] = acc - v;
    }
    __syncthreads();
    for (int i = threadIdx.x; i < n; i += 256) {
        int2 p = prs[i];
        int lr = p.x & 255;
        int rk = atomicAdd(&c2[lr], 1);
        colo[ofs[lr] + rk] = p.y;
    }
    __syncthreads();
    for (int i = threadIdx.x; i < n; i += 256) csr_col[s + i] = colo[i];
    int r = (b << 8) + threadIdx.x;
    if (r < NN) {
        int c = cnt[threadIdx.x];
        startv[r] = s + ofs[threadIdx.x];
        degc[r] = c;
        dinv[r] = rsqrtf((float)(c + 1));
    }
}

// ==================== graph-aligned 16-node tile table ======================
__global__ __launch_bounds__(256) void k_tiles(const int* __restrict__ batch, int* __restrict__ ntot,
                                               int* __restrict__ tg, int* __restrict__ tbase,
                                               int* __restrict__ tcnt) {
    __shared__ int gst[NG + 1];
    __shared__ int sc[NG];
    int t = threadIdx.x;  // 256 == NG
    gst[t] = lower_bound_i(batch, NN, t);
    if (t == 0) gst[NG] = NN;
    __syncthreads();
    int ng = gst[t + 1] - gst[t];
    int nt = (ng + 15) >> 4;
    sc[t] = nt;
    __syncthreads();
    int acc = nt;
    for (int off = 1; off < NG; off <<= 1) {
        int add = (t >= off) ? sc[t - off] : 0;
        __syncthreads();
        acc += add;
        sc[t] = acc;
        __syncthreads();
    }
    int ofs = acc - nt;
    for (int i = 0; i < nt; i++) {
        tg[ofs + i] = t;
        tbase[ofs + i] = gst[t] + i * 16;
        tcnt[ofs + i] = min(16, ng - i * 16);
    }
    if (t == NG - 1) ntot[0] = acc;
}

// ==================== W1 -> bf16 B-operand layout [j][16 u32], K-padded =====
__global__ __launch_bounds__(256) void k_prepw1(const float* __restrict__ W1, unsigned* __restrict__ Wt1p) {
    int t = threadIdx.x;
    int j = t >> 2, kq = t & 3;
#pragma unroll
    for (int i = 0; i < 4; i++) {
        int idx = kq * 4 + i;
        int k = idx * 2;
        unsigned v = 0;
        if (k < FIN) v = pack_bf16(W1[k * 64 + j], W1[(k + 1) * 64 + j]);
        Wt1p[j * 16 + idx] = v;
    }
}

// ==================== GraphNorm layer 0 (C=16) -> bf16, pre-scaled by dinv ==
__global__ __launch_bounds__(256) void k_graphnorm16(const float* __restrict__ x, const int* __restrict__ batch,
                              const float* __restrict__ w, const float* __restrict__ b,
                              const float* __restrict__ ms, const float* __restrict__ dinv,
                              unsigned* __restrict__ xb) {
    constexpr int C = FIN, NPB = 256 / C;
    __shared__ float red[NPB][C], red2[NPB][C];
    __shared__ float mm_s[C], rs_s[C];
    int g = blockIdx.x;
    int s = lower_bound_i(batch, NN, g);
    int e = lower_bound_i(batch, NN, g + 1);
    float fc = (float)max(e - s, 1);
    int c = threadIdx.x % C, slot = threadIdx.x / C;

    float a1 = 0.f, a2 = 0.f;
    for (int i = s + slot; i < e; i += NPB) { float v = x[i * C + c]; a1 += v; a2 += v * v; }
    red[slot][c] = a1;
    red2[slot][c] = a2;
    __syncthreads();
    if (threadIdx.x < C) {
        float t1 = 0.f, t2 = 0.f;
        for (int k = 0; k < NPB; k++) { t1 += red[k][threadIdx.x]; t2 += red2[k][threadIdx.x]; }
        float mean = t1 / fc;
        float mm = ms[threadIdx.x] * mean;
        float var = t2 / fc - 2.f * mm * mean + mm * mm;
        mm_s[threadIdx.x] = mm;
        rs_s[threadIdx.x] = rsqrtf(var + 1e-5f);
    }
    __syncthreads();
    float mm = mm_s[c], ww = w[c] * rs_s[c], bb = b[c];
    for (int i = s + slot; i < e; i += NPB) {
        float v = (ww * (x[i * C + c] - mm) + bb) * dinv[i];
        float partner = __shfl_xor(v, 1);
        if ((c & 1) == 0) xb[(long)i * 8 + (c >> 1)] = pack_bf16(v, partner);
    }
}

// ==== GraphNorm stats (C=64, bf16 in) + fold into per-graph W', bias2 ======
__global__ __launch_bounds__(256) void k_gnstats2(const unsigned* __restrict__ xw, const int* __restrict__ batch,
                          const float* __restrict__ w, const float* __restrict__ b,
                          const float* __restrict__ ms, const float* __restrict__ W,
                          unsigned* __restrict__ Wtp, float* __restrict__ bias2) {
    constexpr int C = 64, NPB = 4;
    __shared__ float red[NPB][C], red2[NPB][C];
    __shared__ float sA[C], sB[C];
    int g = blockIdx.x;
    int s = lower_bound_i(batch, NN, g);
    int e = lower_bound_i(batch, NN, g + 1);
    float fc = (float)max(e - s, 1);
    int c = threadIdx.x & 63, slot = threadIdx.x >> 6;

    float a1 = 0.f, a2 = 0.f;
    for (int i = s + slot; i < e; i += NPB) {
        unsigned u = xw[(long)i * 32 + (c >> 1)];
        float v = (c & 1) ? BF_HI(u) : BF_LO(u);
        a1 += v; a2 += v * v;
    }
    red[slot][c] = a1;
    red2[slot][c] = a2;
    __syncthreads();
    if (threadIdx.x < C) {
        float t1 = 0.f, t2 = 0.f;
        for (int k = 0; k < NPB; k++) { t1 += red[k][threadIdx.x]; t2 += red2[k][threadIdx.x]; }
        float mean = t1 / fc;
        float mm = ms[threadIdx.x] * mean;
        float var = t2 / fc - 2.f * mm * mean + mm * mm;
        float A = w[threadIdx.x] * rsqrtf(var + 1e-5f);
        sA[threadIdx.x] = A;
        sB[threadIdx.x] = b[threadIdx.x] - A * mm;
    }
    __syncthreads();
    // fold: Wt'[g][j][k] = bf16(sA[k]*W[k][j]) (k-pair packed), bias2[g][j] = sum_k sB[k]*W[k][j]
    int j = threadIdx.x >> 2, kq = threadIdx.x & 3;
    unsigned* wrow = Wtp + ((long)g * 64 + j) * 32 + kq * 8;
    float part = 0.f;
#pragma unroll
    for (int i = 0; i < 8; i++) {
        int k = kq * 16 + 2 * i;
        float w0 = W[k * 64 + j], w1 = W[(k + 1) * 64 + j];
        wrow[i] = pack_bf16(sA[k] * w0, sA[k + 1] * w1);
        part += sB[k] * w0 + sB[k + 1] * w1;
    }
    part += __shfl_xor(part, 1);
    part += __shfl_xor(part, 2);
    if (kq == 0) bias2[g * 64 + j] = part;
}

// ==== 16-dim gather (pre-scaled bf16) -> packed bf16 agg [node][16u32] =====
__global__ __launch_bounds__(256) void k_gather16(const unsigned* __restrict__ xb, const int* __restrict__ startv,
                           const int* __restrict__ degc, const float* __restrict__ dinv,
                           const int* __restrict__ csr_col, unsigned* __restrict__ agg) {
    int wave = (blockIdx.x * blockDim.x + threadIdx.x) >> 6;
    if (wave >= NN) return;
    int lane = threadIdx.x & 63;
    int p = lane & 7, g = lane >> 3;
    int s = startv[wave], cnt = degc[wave];
    float di = dinv[wave];
    float ax = 0.f, ay = 0.f;
    int k = g;
    for (; k + 8 < cnt; k += 16) {
        int c0 = csr_col[s + k], c1 = csr_col[s + k + 8];
        unsigned u0 = xb[(long)c0 * 8 + p], u1 = xb[(long)c1 * 8 + p];
        ax += BF_LO(u0) + BF_LO(u1);
        ay += BF_HI(u0) + BF_HI(u1);
    }
    for (; k < cnt; k += 8) {
        int c0 = csr_col[s + k];
        unsigned u0 = xb[(long)c0 * 8 + p];
        ax += BF_LO(u0);
        ay += BF_HI(u0);
    }
    ax += __shfl_xor(ax, 8);  ay += __shfl_xor(ay, 8);
    ax += __shfl_xor(ax, 16); ay += __shfl_xor(ay, 16);
    ax += __shfl_xor(ax, 32); ay += __shfl_xor(ay, 32);
    if (g == 0) {
        unsigned u = xb[(long)wave * 8 + p];
        ax = (ax + BF_LO(u)) * di;
        ay = (ay + BF_HI(u)) * di;
        agg[(long)wave * 16 + p] = pack_bf16(ax, ay);
    } else if (g == 1) {
        agg[(long)wave * 16 + 8 + p] = 0u;  // K-pad for the MFMA GEMM
    }
}

// ==== MFMA GEMM: per-tile 16 nodes x 64 out, K = KU*32 ======================
// A: bf16-pair u32 [node][KU*16]; Wt: [ (g) ][64 j][KU*16] bf16-pair (B^T layout)
template <int KU, bool PERG, bool RELU, bool DINV>
__global__ __launch_bounds__(256) void k_gemmT(const unsigned* __restrict__ Ain, const unsigned* __restrict__ Wt,
                        const float* __restrict__ biasv, const float* __restrict__ dinv,
                        const int* __restrict__ ntot, const int* __restrict__ tg,
                        const int* __restrict__ tbase, const int* __restrict__ tcnt,
                        unsigned* __restrict__ Aout) {
    const int RW = KU * 16;
    int tix = blockIdx.x * 4 + (threadIdx.x >> 6);
    if (tix >= ntot[0]) return;
    int g = tg[tix], base = tbase[tix], n = tcnt[tix];
    int l = threadIdx.x & 63, r = l & 15, q = l >> 4;
    FU a[KU];
#pragma unroll
    for (int s = 0; s < KU; s++) {
        if (r < n) a[s].u = *(const uint4*)(Ain + (long)(base + r) * RW + s * 16 + q * 4);
        else a[s].u = make_uint4(0, 0, 0, 0);
    }
    const unsigned* wb = PERG ? (Wt + (long)g * 64 * RW) : Wt;
    f32x4 acc[4];
#pragma unroll
    for (int t = 0; t < 4; t++) {
        acc[t] = (f32x4){0.f, 0.f, 0.f, 0.f};
#pragma unroll
        for (int s = 0; s < KU; s++) {
            FU bfrag;
            bfrag.u = *(const uint4*)(wb + (long)(t * 16 + r) * RW + s * 16 + q * 4);
            acc[t] = __builtin_amdgcn_mfma_f32_16x16x32_bf16(a[s].v, bfrag.v, acc[t], 0, 0, 0);
        }
    }
    const float* bb = PERG ? (biasv + g * 64) : biasv;
    float dv[4];
#pragma unroll
    for (int e = 0; e < 4; e++) {
        int node = base + q * 4 + e;
        dv[e] = DINV ? ((node < NN) ? dinv[node] : 0.f) : 1.f;
    }
#pragma unroll
    for (int t = 0; t < 4; t++) {
        float bv = bb[t * 16 + r];
#pragma unroll
        for (int e = 0; e < 4; e++) {
            float v = acc[t][e] + bv;
            if (RELU) v = fmaxf(v, 0.f);
            if (DINV) v *= dv[e];
            float part = __shfl_xor(v, 1);
            if ((q * 4 + e) < n && (r & 1) == 0)
                Aout[(long)(base + q * 4 + e) * 32 + t * 8 + (r >> 1)] = pack_bf16(v, part);
        }
    }
}

// ==== 64-dim gather (pre-scaled bf16 in) -> packed bf16 out ================
__global__ __launch_bounds__(256) void k_gather64(const unsigned* __restrict__ h2, const int* __restrict__ startv,
                           const int* __restrict__ degc, const float* __restrict__ dinv,
                           const int* __restrict__ csr_col, const float* __restrict__ bias,
                           unsigned* __restrict__ outp) {
    int wave = (blockIdx.x * blockDim.x + threadIdx.x) >> 6;
    if (wave >= NN) return;
    int lane = threadIdx.x & 63;
    int p = lane & 31, g = lane >> 5;
    int s = startv[wave], cnt = degc[wave];
    float di = dinv[wave];
    float ax = 0.f, ay = 0.f;
    if (g == 0) {
        unsigned u = h2[(long)wave * 32 + p];
        ax = BF_LO(u);
        ay = BF_HI(u);
    }
    int k = g;
    for (; k + 6 < cnt; k += 8) {
        int c0 = csr_col[s + k], c1 = csr_col[s + k + 2],
            c2 = csr_col[s + k + 4], c3 = csr_col[s + k + 6];
        unsigned u0 = h2[(long)c0 * 32 + p], u1 = h2[(long)c1 * 32 + p],
                 u2 = h2[(long)c2 * 32 + p], u3 = h2[(long)c3 * 32 + p];
        ax += BF_LO(u0) + BF_LO(u1) + BF_LO(u2) + BF_LO(u3);
        ay += BF_HI(u0) + BF_HI(u1) + BF_HI(u2) + BF_HI(u3);
    }
    for (; k < cnt; k += 2) {
        int c0 = csr_col[s + k];
        unsigned u0 = h2[(long)c0 * 32 + p];
        ax += BF_LO(u0);
        ay += BF_HI(u0);
    }
    ax += __shfl_xor(ax, 32);
    ay += __shfl_xor(ay, 32);
    if (g == 0) {
        float vx = fmaxf(ax * di + bias[2 * p], 0.f);
        float vy = fmaxf(ay * di + bias[2 * p + 1], 0.f);
        outp[(long)wave * 32 + p] = pack_bf16(vx, vy);
    }
}

// ==================== global mean pool (bf16 in) + head =====================
__global__ __launch_bounds__(1024) void k_pool(const unsigned* __restrict__ xw, const int* __restrict__ batch,
                       float* __restrict__ gpool) {
    __shared__ float red[16][64];
    int g = blockIdx.x;
    int s = lower_bound_i(batch, NN, g);
    int e = lower_bound_i(batch, NN, g + 1);
    int c = threadIdx.x & 63, slot = threadIdx.x >> 6;
    float acc = 0.f;
    for (int i = s + slot; i < e; i += 16) {
        unsigned u = xw[(long)i * 32 + (c >> 1)];
        acc += (c & 1) ? BF_HI(u) : BF_LO(u);
    }
    red[slot][c] = acc;
    __syncthreads();
    if (threadIdx.x < 64) {
        float t = 0.f;
        for (int k = 0; k < 16; k++) t += red[k][threadIdx.x];
        gpool[g * 64 + threadIdx.x] = t / (float)max(e - s, 1);
    }
}

__global__ __launch_bounds__(64) void k_head(const float* __restrict__ gpool, const float* __restrict__ Wd,
                       const float* __restrict__ bd, const float* __restrict__ Wo,
                       const float* __restrict__ bo, float* __restrict__ out) {
    int g = blockIdx.x, j = threadIdx.x;
    __shared__ float gs[64];
    gs[j] = gpool[g * 64 + j];
    __syncthreads();
    float acc = bd[j];
    for (int k = 0; k < 64; k++) acc += gs[k] * Wd[k * 64 + j];
    float hv = fmaxf(acc, 0.f);
    float p0 = hv * Wo[j * 2 + 0], p1 = hv * Wo[j * 2 + 1];
    for (int off = 32; off; off >>= 1) { p0 += __shfl_down(p0, off); p1 += __shfl_down(p1, off); }
    if (j == 0) {
        float l0 = p0 + bo[0], l1 = p1 + bo[1];
        float m = fmaxf(l0, l1);
        float e0 = expf(l0 - m), e1 = expf(l1 - m);
        float inv = 1.f / (e0 + e1);
        out[g * 2 + 0] = e0 * inv;
        out[g * 2 + 1] = e1 * inv;
    }
}

extern "C" void kernel_launch(void* const* d_in, const int* in_sizes, int n_in,
                              void* d_out, int out_size, void* d_ws, size_t ws_size,
                              hipStream_t stream) {
    const float* x = (const float*)d_in[0];
    const int* ei = (const int*)d_in[1];
    const int* row = ei;
    const int* col = ei + NE;
    const int* batch = (const int*)d_in[2];
    const float* gn0w = (const float*)d_in[3];
    const float* gn0b = (const float*)d_in[4];
    const float* gn0ms = (const float*)d_in[5];
    const float* W1 = (const float*)d_in[6];
    const float* b1 = (const float*)d_in[7];
    const float* gn1w = (const float*)d_in[8];
    const float* gn1b = (const float*)d_in[9];
    const float* gn1ms = (const float*)d_in[10];
    const float* W2 = (const float*)d_in[11];
    const float* b2 = (const float*)d_in[12];
    const float* gn2w = (const float*)d_in[13];
    const float* gn2b = (const float*)d_in[14];
    const float* gn2ms = (const float*)d_in[15];
    const float* W3 = (const float*)d_in[16];
    const float* b3 = (const float*)d_in[17];
    const float* Wd = (const float*)d_in[18];
    const float* bd = (const float*)d_in[19];
    const float* Wo = (const float*)d_in[20];
    const float* bo = (const float*)d_in[21];
    float* outp = (float*)d_out;

    // workspace layout (all chunks multiple of 16B)
    int* bhist = (int*)d_ws;                        // 512
    int* bbase = bhist + 512;                       // 512
    int* bcur = bbase + 512;                        // 512
    int* startv = bcur + 512;                       // NN
    int* degc = startv + NN;                        // NN
    float* dinv = (float*)(degc + NN);              // NN
    int* csr_col = (int*)(dinv + NN);               // NE
    int* ntot = csr_col + NE;                       // 16
    int* tg = ntot + 16;                            // 6608
    int* tbase = tg + 6608;                         // 6608
    int* tcnt = tbase + 6608;                       // 6608
    unsigned* Wt1p = (unsigned*)(tcnt + 6608);      // 64*16
    unsigned* Wtp = Wt1p + 1024;                    // NG*64*32 = 524288 (2MB)
    float* bias2 = (float*)(Wtp + (long)NG * 64 * 32);  // NG*64
    unsigned* xb = (unsigned*)(bias2 + NG * 64);    // NN*8
    unsigned* agg16 = xb + (long)NN * 8;            // NN*16
    unsigned* bufA = agg16 + (long)NN * 16;         // NN*32 (12.8MB)
    unsigned* bufB = bufA + (long)NN * 32;          // NN*32
    unsigned* h2 = bufB + (long)NN * 32;            // NN*32
    float* gpool = (float*)(h2 + (long)NN * 32);    // NG*64
    int2* pairs = (int2*)bufA;  // alias: NE int2 = 12.8MB == bufA; dead before bufA written

    const int NBG = (MAXT + 3) / 4;  // gemm blocks (4 tiles each)

    // ---- CSR build (bucket sort, coalesced writes) ----
    k_zb<<<1, 512, 0, stream>>>(bhist);
    k_bhist<<<NTILE, 512, 0, stream>>>((const int4*)row, bhist);
    k_bscan<<<1, 512, 0, stream>>>(bhist, bbase, bcur);
    k_bscatter<<<NTILE, 512, 0, stream>>>((const int4*)row, (const int4*)col, bcur, pairs);
    k_bsort<<<NBK, 256, 0, stream>>>(pairs, bbase, csr_col, startv, degc, dinv);

    // ---- tile table + W1 prep ----
    k_tiles<<<1, 256, 0, stream>>>(batch, ntot, tg, tbase, tcnt);
    k_prepw1<<<1, 256, 0, stream>>>(W1, Wt1p);

    // layer 1: norm(16, bf16, dinv-prescaled) -> gather -> MFMA gemm 16->64
    k_graphnorm16<<<NG, 256, 0, stream>>>(x, batch, gn0w, gn0b, gn0ms, dinv, xb);
    k_gather16<<<(NN * 64 + 255) / 256, 256, 0, stream>>>(xb, startv, degc, dinv, csr_col, agg16);
    k_gemmT<1, false, true, false><<<NBG, 256, 0, stream>>>(agg16, Wt1p, b1, dinv, ntot, tg, tbase, tcnt, bufA);

    // layer 2: stats+fold -> MFMA gemm (affine-folded, xdinv) -> gather
    k_gnstats2<<<NG, 256, 0, stream>>>(bufA, batch, gn1w, gn1b, gn1ms, W2, Wtp, bias2);
    k_gemmT<2, true, false, true><<<NBG, 256, 0, stream>>>(bufA, Wtp, bias2, dinv, ntot, tg, tbase, tcnt, h2);
    k_gather64<<<(NN * 64 + 255) / 256, 256, 0, stream>>>(h2, startv, degc, dinv, csr_col, b2, bufB);

    // layer 3
    k_gnstats2<<<NG, 256, 0, stream>>>(bufB, batch, gn2w, gn2b, gn2ms, W3, Wtp, bias2);
    k_gemmT<2, true, false, true><<<NBG, 256, 0, stream>>>(bufB, Wtp, bias2, dinv, ntot, tg, tbase, tcnt, h2);
    k_gather64<<<(NN * 64 + 255) / 256, 256, 0, stream>>>(h2, startv, degc, dinv, csr_col, b3, bufA);

    // pool + head
    k_pool<<<NG, 1024, 0, stream>>>(bufA, batch, gpool);
    k_head<<<NG, 64, 0, stream>>>(gpool, Wd, bd, Wo, bo, outp);
}

// Round 7
// 414.029 us; speedup vs baseline: 2.4937x; 1.0639x over previous
//
#include <hip/hip_runtime.h>
#include <hip/hip_bf16.h>

#define NN 100000
#define NE 1600000
#define NG 256
#define FIN 16
#define HID 64
#define NBK 391    // buckets of 256 rows; 391*256 = 100096 >= NN
#define NTILE 391  // ceil(NE/4096)
#define PMAX 4864  // max edges per bucket (mean 4092)
#define MAXT (NN / 16 + NG)  // max graph-aligned 16-node tiles = 6506

__device__ __forceinline__ int lower_bound_i(const int* __restrict__ b, int n, int v) {
    int lo = 0, hi = n;
    while (lo < hi) { int m = (lo + hi) >> 1; if (b[m] < v) lo = m + 1; else hi = m; }
    return lo;
}

__device__ __forceinline__ unsigned pack_bf16(float a, float b) {
    unsigned ua = __float_as_uint(a), ub = __float_as_uint(b);
    ua = (ua + 0x7fffu + ((ua >> 16) & 1u)) >> 16;
    ub = (ub + 0x7fffu + ((ub >> 16) & 1u)) & 0xffff0000u;
    return ua | ub;
}
#define BF_LO(u) __uint_as_float((u) << 16)
#define BF_HI(u) __uint_as_float((u) & 0xffff0000u)

typedef __attribute__((ext_vector_type(8))) short bf16x8;
typedef __attribute__((ext_vector_type(4))) float f32x4;
union FU { uint4 u; bf16x8 v; };

// ==================== CSR build: 2-level LDS bucket sort ====================
__global__ __launch_bounds__(512) void k_zb(int* __restrict__ bhist) {
    bhist[threadIdx.x] = 0;
}

__global__ __launch_bounds__(512) void k_bhist(const int4* __restrict__ row4, int* __restrict__ bhist) {
    __shared__ int h[NBK];
    for (int i = threadIdx.x; i < NBK; i += 512) h[i] = 0;
    __syncthreads();
    int t0 = blockIdx.x * 1024 + threadIdx.x;
#pragma unroll
    for (int it = 0; it < 2; ++it) {
        int t = t0 + it * 512;
        if (t < NE / 4) {
            int4 r = row4[t];
            atomicAdd(&h[r.x >> 8], 1); atomicAdd(&h[r.y >> 8], 1);
            atomicAdd(&h[r.z >> 8], 1); atomicAdd(&h[r.w >> 8], 1);
        }
    }
    __syncthreads();
    for (int i = threadIdx.x; i < NBK; i += 512)
        if (h[i]) atomicAdd(&bhist[i], h[i]);
}

__global__ __launch_bounds__(512) void k_bscan(const int* __restrict__ bhist, int* __restrict__ bbase,
                                               int* __restrict__ bcur) {
    __shared__ int sc[512];
    int t = threadIdx.x;
    int v = (t < NBK) ? bhist[t] : 0;
    sc[t] = v;
    __syncthreads();
    int acc = v;
    for (int off = 1; off < 512; off <<= 1) {
        int add = (t >= off) ? sc[t - off] : 0;
        __syncthreads();
        acc += add;
        sc[t] = acc;
        __syncthreads();
    }
    if (t < NBK) { bbase[t] = acc - v; bcur[t] = acc - v; }
    if (t == NBK - 1) bbase[NBK] = acc;
}

__global__ __launch_bounds__(512) void k_bscatter(const int4* __restrict__ row4, const int4* __restrict__ col4,
                                                  int* __restrict__ bcur, int2* __restrict__ pairs) {
    __shared__ int lh[NBK], lofs[NBK], lbase[NBK], lc[NBK];
    __shared__ int sc[512];
    __shared__ int2 stg[4096];
    for (int i = threadIdx.x; i < NBK; i += 512) { lh[i] = 0; lc[i] = 0; }
    __syncthreads();
    int t0 = blockIdx.x * 1024 + threadIdx.x;
#pragma unroll
    for (int it = 0; it < 2; ++it) {
        int t = t0 + it * 512;
        if (t < NE / 4) {
            int4 r = row4[t];
            atomicAdd(&lh[r.x >> 8], 1); atomicAdd(&lh[r.y >> 8], 1);
            atomicAdd(&lh[r.z >> 8], 1); atomicAdd(&lh[r.w >> 8], 1);
        }
    }
    __syncthreads();
    {
        int t = threadIdx.x;
        int v = (t < NBK) ? lh[t] : 0;
        sc[t] = v;
        __syncthreads();
        int acc = v;
        for (int off = 1; off < 512; off <<= 1) {
            int add = (t >= off) ? sc[t - off] : 0;
            __syncthreads();
            acc += add;
            sc[t] = acc;
            __syncthreads();
        }
        if (t < NBK) lofs[t] = acc - v;
    }
    if (threadIdx.x < NBK) {
        int c = lh[threadIdx.x];
        lbase[threadIdx.x] = c ? atomicAdd(&bcur[threadIdx.x], c) : 0;
    }
    __syncthreads();
#pragma unroll
    for (int it = 0; it < 2; ++it) {
        int t = t0 + it * 512;
        if (t < NE / 4) {
            int4 r = row4[t];
            int4 c = col4[t];
            int b, rk;
            b = r.x >> 8; rk = atomicAdd(&lc[b], 1); stg[lofs[b] + rk] = make_int2(r.x, c.x);
            b = r.y >> 8; rk = atomicAdd(&lc[b], 1); stg[lofs[b] + rk] = make_int2(r.y, c.y);
            b = r.z >> 8; rk = atomicAdd(&lc[b], 1); stg[lofs[b] + rk] = make_int2(r.z, c.z);
            b = r.w >> 8; rk = atomicAdd(&lc[b], 1); stg[lofs[b] + rk] = make_int2(r.w, c.w);
        }
    }
    __syncthreads();
    int nv = min(4096, NE - blockIdx.x * 4096);
    for (int j = threadIdx.x; j < nv; j += 512) {
        int2 p = stg[j];
        int b = p.x >> 8;
        pairs[lbase[b] + (j - lofs[b])] = p;
    }
}

__global__ __launch_bounds__(256) void k_bsort(const int2* __restrict__ pairs, const int* __restrict__ bbase,
                                               int* __restrict__ csr_col, int* __restrict__ startv,
                                               int* __restrict__ degc, float* __restrict__ dinv) {
    __shared__ int2 prs[PMAX];
    __shared__ int colo[PMAX];
    __shared__ int cnt[256], ofs[256], c2[256], sc[256];
    int b = blockIdx.x;
    int s = bbase[b];
    int n = min(bbase[b + 1] - s, PMAX);
    cnt[threadIdx.x] = 0;
    c2[threadIdx.x] = 0;
    __syncthreads();
    for (int i = threadIdx.x; i < n; i += 256) {
        int2 p = pairs[s + i];
        prs[i] = p;
        atomicAdd(&cnt[p.x & 255], 1);
    }
    __syncthreads();
    {
        int t = threadIdx.x, v = cnt[t];
        sc[t] = v;
        __syncthreads();
        int acc = v;
        for (int off = 1; off < 256; off <<= 1) {
            int add = (t >= off) ? sc[t - off] : 0;
            __syncthreads();
            acc += add;
            sc[t] = acc;
            __syncthreads();
        }
        ofs[t] = acc - v;
    }
    __syncthreads();
    for (int i = threadIdx.x; i < n; i += 256) {
        int2 p = prs[i];
        int lr = p.x & 255;
        int rk = atomicAdd(&c2[lr], 1);
        colo[ofs[lr] + rk] = p.y;
    }
    __syncthreads();
    for (int i = threadIdx.x; i < n; i += 256) csr_col[s + i] = colo[i];
    int r = (b << 8) + threadIdx.x;
    if (r < NN) {
        int c = cnt[threadIdx.x];
        startv[r] = s + ofs[threadIdx.x];
        degc[r] = c;
        dinv[r] = rsqrtf((float)(c + 1));
    }
}

// ========== setup: block 0 = tile table, block 1 = W1 bf16 prep ============
__global__ __launch_bounds__(256) void k_setup(const int* __restrict__ batch, int* __restrict__ ntot,
                                               int* __restrict__ tg, int* __restrict__ tbase,
                                               int* __restrict__ tcnt, const float* __restrict__ W1,
                                               unsigned* __restrict__ Wt1p) {
    if (blockIdx.x == 1) {
        int t = threadIdx.x;
        int j = t >> 2, kq = t & 3;
#pragma unroll
        for (int i = 0; i < 4; i++) {
            int idx = kq * 4 + i;
            int k = idx * 2;
            unsigned v = 0;
            if (k < FIN) v = pack_bf16(W1[k * 64 + j], W1[(k + 1) * 64 + j]);
            Wt1p[j * 16 + idx] = v;
        }
        return;
    }
    __shared__ int gst[NG + 1];
    __shared__ int sc[NG];
    int t = threadIdx.x;  // 256 == NG
    gst[t] = lower_bound_i(batch, NN, t);
    if (t == 0) gst[NG] = NN;
    __syncthreads();
    int ng = gst[t + 1] - gst[t];
    int nt = (ng + 15) >> 4;
    sc[t] = nt;
    __syncthreads();
    int acc = nt;
    for (int off = 1; off < NG; off <<= 1) {
        int add = (t >= off) ? sc[t - off] : 0;
        __syncthreads();
        acc += add;
        sc[t] = acc;
        __syncthreads();
    }
    int ofs = acc - nt;
    for (int i = 0; i < nt; i++) {
        tg[ofs + i] = t;
        tbase[ofs + i] = gst[t] + i * 16;
        tcnt[ofs + i] = min(16, ng - i * 16);
    }
    if (t == NG - 1) ntot[0] = acc;
}

// ==================== GraphNorm layer 0 (C=16) -> bf16, pre-scaled by dinv ==
__global__ __launch_bounds__(256) void k_graphnorm16(const float* __restrict__ x, const int* __restrict__ batch,
                              const float* __restrict__ w, const float* __restrict__ b,
                              const float* __restrict__ ms, const float* __restrict__ dinv,
                              unsigned* __restrict__ xb) {
    constexpr int C = FIN, NPB = 256 / C;
    __shared__ float red[NPB][C], red2[NPB][C];
    __shared__ float mm_s[C], rs_s[C];
    int g = blockIdx.x;
    int s = lower_bound_i(batch, NN, g);
    int e = lower_bound_i(batch, NN, g + 1);
    float fc = (float)max(e - s, 1);
    int c = threadIdx.x % C, slot = threadIdx.x / C;

    float a1 = 0.f, a2 = 0.f;
    for (int i = s + slot; i < e; i += NPB) { float v = x[i * C + c]; a1 += v; a2 += v * v; }
    red[slot][c] = a1;
    red2[slot][c] = a2;
    __syncthreads();
    if (threadIdx.x < C) {
        float t1 = 0.f, t2 = 0.f;
        for (int k = 0; k < NPB; k++) { t1 += red[k][threadIdx.x]; t2 += red2[k][threadIdx.x]; }
        float mean = t1 / fc;
        float mm = ms[threadIdx.x] * mean;
        float var = t2 / fc - 2.f * mm * mean + mm * mm;
        mm_s[threadIdx.x] = mm;
        rs_s[threadIdx.x] = rsqrtf(var + 1e-5f);
    }
    __syncthreads();
    float mm = mm_s[c], ww = w[c] * rs_s[c], bb = b[c];
    for (int i = s + slot; i < e; i += NPB) {
        float v = (ww * (x[i * C + c] - mm) + bb) * dinv[i];
        float partner = __shfl_xor(v, 1);
        if ((c & 1) == 0) xb[(long)i * 8 + (c >> 1)] = pack_bf16(v, partner);
    }
}

// ==== GraphNorm stats (C=64, bf16 in) + fold into per-graph W', bias2 ======
__global__ __launch_bounds__(256) void k_gnstats2(const unsigned* __restrict__ xw, const int* __restrict__ batch,
                          const float* __restrict__ w, const float* __restrict__ b,
                          const float* __restrict__ ms, const float* __restrict__ W,
                          unsigned* __restrict__ Wtp, float* __restrict__ bias2) {
    constexpr int C = 64, NPB = 4;
    __shared__ float red[NPB][C], red2[NPB][C];
    __shared__ float sA[C], sB[C];
    int g = blockIdx.x;
    int s = lower_bound_i(batch, NN, g);
    int e = lower_bound_i(batch, NN, g + 1);
    float fc = (float)max(e - s, 1);
    int c = threadIdx.x & 63, slot = threadIdx.x >> 6;

    float a1 = 0.f, a2 = 0.f;
    for (int i = s + slot; i < e; i += NPB) {
        unsigned u = xw[(long)i * 32 + (c >> 1)];
        float v = (c & 1) ? BF_HI(u) : BF_LO(u);
        a1 += v; a2 += v * v;
    }
    red[slot][c] = a1;
    red2[slot][c] = a2;
    __syncthreads();
    if (threadIdx.x < C) {
        float t1 = 0.f, t2 = 0.f;
        for (int k = 0; k < NPB; k++) { t1 += red[k][threadIdx.x]; t2 += red2[k][threadIdx.x]; }
        float mean = t1 / fc;
        float mm = ms[threadIdx.x] * mean;
        float var = t2 / fc - 2.f * mm * mean + mm * mm;
        float A = w[threadIdx.x] * rsqrtf(var + 1e-5f);
        sA[threadIdx.x] = A;
        sB[threadIdx.x] = b[threadIdx.x] - A * mm;
    }
    __syncthreads();
    int j = threadIdx.x >> 2, kq = threadIdx.x & 3;
    unsigned* wrow = Wtp + ((long)g * 64 + j) * 32 + kq * 8;
    float part = 0.f;
#pragma unroll
    for (int i = 0; i < 8; i++) {
        int k = kq * 16 + 2 * i;
        float w0 = W[k * 64 + j], w1 = W[(k + 1) * 64 + j];
        wrow[i] = pack_bf16(sA[k] * w0, sA[k + 1] * w1);
        part += sB[k] * w0 + sB[k + 1] * w1;
    }
    part += __shfl_xor(part, 1);
    part += __shfl_xor(part, 2);
    if (kq == 0) bias2[g * 64 + j] = part;
}

// ==== 16-dim gather (pre-scaled bf16) -> packed bf16 agg [node][16u32] =====
__global__ __launch_bounds__(256) void k_gather16(const unsigned* __restrict__ xb, const int* __restrict__ startv,
                           const int* __restrict__ degc, const float* __restrict__ dinv,
                           const int* __restrict__ csr_col, unsigned* __restrict__ agg) {
    int wave = (blockIdx.x * blockDim.x + threadIdx.x) >> 6;
    if (wave >= NN) return;
    int lane = threadIdx.x & 63;
    int p = lane & 7, g = lane >> 3;
    int s = startv[wave], cnt = degc[wave];
    float di = dinv[wave];
    float ax = 0.f, ay = 0.f;
    int k = g;
    for (; k + 8 < cnt; k += 16) {
        int c0 = csr_col[s + k], c1 = csr_col[s + k + 8];
        unsigned u0 = xb[(long)c0 * 8 + p], u1 = xb[(long)c1 * 8 + p];
        ax += BF_LO(u0) + BF_LO(u1);
        ay += BF_HI(u0) + BF_HI(u1);
    }
    for (; k < cnt; k += 8) {
        int c0 = csr_col[s + k];
        unsigned u0 = xb[(long)c0 * 8 + p];
        ax += BF_LO(u0);
        ay += BF_HI(u0);
    }
    ax += __shfl_xor(ax, 8);  ay += __shfl_xor(ay, 8);
    ax += __shfl_xor(ax, 16); ay += __shfl_xor(ay, 16);
    ax += __shfl_xor(ax, 32); ay += __shfl_xor(ay, 32);
    if (g == 0) {
        unsigned u = xb[(long)wave * 8 + p];
        ax = (ax + BF_LO(u)) * di;
        ay = (ay + BF_HI(u)) * di;
        agg[(long)wave * 16 + p] = pack_bf16(ax, ay);
    } else if (g == 1) {
        agg[(long)wave * 16 + 8 + p] = 0u;  // K-pad for the MFMA GEMM
    }
}

// ==== MFMA GEMM: per-tile 16 nodes x 64 out, K = KU*32 ======================
template <int KU, bool PERG, bool RELU, bool DINV>
__global__ __launch_bounds__(256) void k_gemmT(const unsigned* __restrict__ Ain, const unsigned* __restrict__ Wt,
                        const float* __restrict__ biasv, const float* __restrict__ dinv,
                        const int* __restrict__ ntot, const int* __restrict__ tg,
                        const int* __restrict__ tbase, const int* __restrict__ tcnt,
                        unsigned* __restrict__ Aout) {
    const int RW = KU * 16;
    int tix = blockIdx.x * 4 + (threadIdx.x >> 6);
    if (tix >= ntot[0]) return;
    int g = tg[tix], base = tbase[tix], n = tcnt[tix];
    int l = threadIdx.x & 63, r = l & 15, q = l >> 4;
    FU a[KU];
#pragma unroll
    for (int s = 0; s < KU; s++) {
        if (r < n) a[s].u = *(const uint4*)(Ain + (long)(base + r) * RW + s * 16 + q * 4);
        else a[s].u = make_uint4(0, 0, 0, 0);
    }
    const unsigned* wb = PERG ? (Wt + (long)g * 64 * RW) : Wt;
    f32x4 acc[4];
#pragma unroll
    for (int t = 0; t < 4; t++) {
        acc[t] = (f32x4){0.f, 0.f, 0.f, 0.f};
#pragma unroll
        for (int s = 0; s < KU; s++) {
            FU bfrag;
            bfrag.u = *(const uint4*)(wb + (long)(t * 16 + r) * RW + s * 16 + q * 4);
            acc[t] = __builtin_amdgcn_mfma_f32_16x16x32_bf16(a[s].v, bfrag.v, acc[t], 0, 0, 0);
        }
    }
    const float* bb = PERG ? (biasv + g * 64) : biasv;
    float dv[4];
#pragma unroll
    for (int e = 0; e < 4; e++) {
        int node = base + q * 4 + e;
        dv[e] = DINV ? ((node < NN) ? dinv[node] : 0.f) : 1.f;
    }
#pragma unroll
    for (int t = 0; t < 4; t++) {
        float bv = bb[t * 16 + r];
#pragma unroll
        for (int e = 0; e < 4; e++) {
            float v = acc[t][e] + bv;
            if (RELU) v = fmaxf(v, 0.f);
            if (DINV) v *= dv[e];
            float part = __shfl_xor(v, 1);
            if ((q * 4 + e) < n && (r & 1) == 0)
                Aout[(long)(base + q * 4 + e) * 32 + t * 8 + (r >> 1)] = pack_bf16(v, part);
        }
    }
}

// ==== 64-dim gather: 8-deep per half-wave (16 edges in flight) =============
__global__ __launch_bounds__(256) void k_gather64(const unsigned* __restrict__ h2, const int* __restrict__ startv,
                           const int* __restrict__ degc, const float* __restrict__ dinv,
                           const int* __restrict__ csr_col, const float* __restrict__ bias,
                           unsigned* __restrict__ outp) {
    int wave = (blockIdx.x * blockDim.x + threadIdx.x) >> 6;
    if (wave >= NN) return;
    int lane = threadIdx.x & 63;
    int p = lane & 31, g = lane >> 5;
    int s = startv[wave], cnt = degc[wave];
    float di = dinv[wave];
    float ax = 0.f, ay = 0.f;
    if (g == 0) {  // self term (pre-scaled by dinv already)
        unsigned u = h2[(long)wave * 32 + p];
        ax = BF_LO(u);
        ay = BF_HI(u);
    }
    // group g owns edge blocks [k, k+8) for k = g*8, g*8+16, ...
    for (int k = g * 8; k < cnt; k += 16) {
        int cc[8];
#pragma unroll
        for (int i = 0; i < 8; i++) {
            int idx = k + i;
            cc[i] = (idx < cnt) ? csr_col[s + idx] : -1;
        }
        unsigned u[8];
#pragma unroll
        for (int i = 0; i < 8; i++)
            u[i] = (cc[i] >= 0) ? h2[(long)cc[i] * 32 + p] : 0u;
#pragma unroll
        for (int i = 0; i < 8; i++) { ax += BF_LO(u[i]); ay += BF_HI(u[i]); }
    }
    ax += __shfl_xor(ax, 32);
    ay += __shfl_xor(ay, 32);
    if (g == 0) {
        float vx = fmaxf(ax * di + bias[2 * p], 0.f);
        float vy = fmaxf(ay * di + bias[2 * p + 1], 0.f);
        outp[(long)wave * 32 + p] = pack_bf16(vx, vy);
    }
}

// ============ fused global mean pool (bf16 in) + dense head ================
__global__ __launch_bounds__(1024) void k_poolhead(const unsigned* __restrict__ xw, const int* __restrict__ batch,
                       const float* __restrict__ Wd, const float* __restrict__ bd,
                       const float* __restrict__ Wo, const float* __restrict__ bo,
                       float* __restrict__ out) {
    __shared__ float red[16][64];
    __shared__ float wds[64 * 64];
    __shared__ float gs[64];
    int g = blockIdx.x;
    int s = lower_bound_i(batch, NN, g);
    int e = lower_bound_i(batch, NN, g + 1);
    int c = threadIdx.x & 63, slot = threadIdx.x >> 6;
    for (int i = threadIdx.x; i < 64 * 64; i += 1024) wds[i] = Wd[i];
    float acc = 0.f;
    for (int i = s + slot; i < e; i += 16) {
        unsigned u = xw[(long)i * 32 + (c >> 1)];
        acc += (c & 1) ? BF_HI(u) : BF_LO(u);
    }
    red[slot][c] = acc;
    __syncthreads();
    if (threadIdx.x < 64) {
        float t = 0.f;
        for (int k = 0; k < 16; k++) t += red[k][threadIdx.x];
        gs[threadIdx.x] = t / (float)max(e - s, 1);
    }
    __syncthreads();
    if (threadIdx.x < 64) {
        int j = threadIdx.x;
        float a2 = bd[j];
        for (int k = 0; k < 64; k++) a2 += gs[k] * wds[k * 64 + j];
        float hv = fmaxf(a2, 0.f);
        float p0 = hv * Wo[j * 2 + 0], p1 = hv * Wo[j * 2 + 1];
        for (int off = 32; off; off >>= 1) { p0 += __shfl_down(p0, off); p1 += __shfl_down(p1, off); }
        if (j == 0) {
            float l0 = p0 + bo[0], l1 = p1 + bo[1];
            float m = fmaxf(l0, l1);
            float e0 = expf(l0 - m), e1 = expf(l1 - m);
            float inv = 1.f / (e0 + e1);
            out[g * 2 + 0] = e0 * inv;
            out[g * 2 + 1] = e1 * inv;
        }
    }
}

extern "C" void kernel_launch(void* const* d_in, const int* in_sizes, int n_in,
                              void* d_out, int out_size, void* d_ws, size_t ws_size,
                              hipStream_t stream) {
    const float* x = (const float*)d_in[0];
    const int* ei = (const int*)d_in[1];
    const int* row = ei;
    const int* col = ei + NE;
    const int* batch = (const int*)d_in[2];
    const float* gn0w = (const float*)d_in[3];
    const float* gn0b = (const float*)d_in[4];
    const float* gn0ms = (const float*)d_in[5];
    const float* W1 = (const float*)d_in[6];
    const float* b1 = (const float*)d_in[7];
    const float* gn1w = (const float*)d_in[8];
    const float* gn1b = (const float*)d_in[9];
    const float* gn1ms = (const float*)d_in[10];
    const float* W2 = (const float*)d_in[11];
    const float* b2 = (const float*)d_in[12];
    const float* gn2w = (const float*)d_in[13];
    const float* gn2b = (const float*)d_in[14];
    const float* gn2ms = (const float*)d_in[15];
    const float* W3 = (const float*)d_in[16];
    const float* b3 = (const float*)d_in[17];
    const float* Wd = (const float*)d_in[18];
    const float* bd = (const float*)d_in[19];
    const float* Wo = (const float*)d_in[20];
    const float* bo = (const float*)d_in[21];
    float* outp = (float*)d_out;

    // workspace layout (all chunks multiple of 16B)
    int* bhist = (int*)d_ws;                        // 512
    int* bbase = bhist + 512;                       // 512
    int* bcur = bbase + 512;                        // 512
    int* startv = bcur + 512;                       // NN
    int* degc = startv + NN;                        // NN
    float* dinv = (float*)(degc + NN);              // NN
    int* csr_col = (int*)(dinv + NN);               // NE
    int* ntot = csr_col + NE;                       // 16
    int* tg = ntot + 16;                            // 6608
    int* tbase = tg + 6608;                         // 6608
    int* tcnt = tbase + 6608;                       // 6608
    unsigned* Wt1p = (unsigned*)(tcnt + 6608);      // 64*16
    unsigned* Wtp = Wt1p + 1024;                    // NG*64*32 = 524288 (2MB)
    float* bias2 = (float*)(Wtp + (long)NG * 64 * 32);  // NG*64
    unsigned* xb = (unsigned*)(bias2 + NG * 64);    // NN*8
    unsigned* agg16 = xb + (long)NN * 8;            // NN*16
    unsigned* bufA = agg16 + (long)NN * 16;         // NN*32 (12.8MB)
    unsigned* bufB = bufA + (long)NN * 32;          // NN*32
    unsigned* h2 = bufB + (long)NN * 32;            // NN*32
    int2* pairs = (int2*)bufA;  // alias: NE int2 = 12.8MB == bufA; dead before bufA written

    const int NBG = (MAXT + 3) / 4;  // gemm blocks (4 tiles each)

    // ---- CSR build (bucket sort, coalesced writes) ----
    k_zb<<<1, 512, 0, stream>>>(bhist);
    k_bhist<<<NTILE, 512, 0, stream>>>((const int4*)row, bhist);
    k_bscan<<<1, 512, 0, stream>>>(bhist, bbase, bcur);
    k_bscatter<<<NTILE, 512, 0, stream>>>((const int4*)row, (const int4*)col, bcur, pairs);
    k_bsort<<<NBK, 256, 0, stream>>>(pairs, bbase, csr_col, startv, degc, dinv);

    // ---- tile table + W1 prep (fused) ----
    k_setup<<<2, 256, 0, stream>>>(batch, ntot, tg, tbase, tcnt, W1, Wt1p);

    // layer 1: norm(16, bf16, dinv-prescaled) -> gather -> MFMA gemm 16->64
    k_graphnorm16<<<NG, 256, 0, stream>>>(x, batch, gn0w, gn0b, gn0ms, dinv, xb);
    k_gather16<<<(NN * 64 + 255) / 256, 256, 0, stream>>>(xb, startv, degc, dinv, csr_col, agg16);
    k_gemmT<1, false, true, false><<<NBG, 256, 0, stream>>>(agg16, Wt1p, b1, dinv, ntot, tg, tbase, tcnt, bufA);

    // layer 2: stats+fold -> MFMA gemm (affine-folded, xdinv) -> gather
    k_gnstats2<<<NG, 256, 0, stream>>>(bufA, batch, gn1w, gn1b, gn1ms, W2, Wtp, bias2);
    k_gemmT<2, true, false, true><<<NBG, 256, 0, stream>>>(bufA, Wtp, bias2, dinv, ntot, tg, tbase, tcnt, h2);
    k_gather64<<<(NN * 64 + 255) / 256, 256, 0, stream>>>(h2, startv, degc, dinv, csr_col, b2, bufB);

    // layer 3
    k_gnstats2<<<NG, 256, 0, stream>>>(bufB, batch, gn2w, gn2b, gn2ms, W3, Wtp, bias2);
    k_gemmT<2, true, false, true><<<NBG, 256, 0, stream>>>(bufB, Wtp, bias2, dinv, ntot, tg, tbase, tcnt, h2);
    k_gather64<<<(NN * 64 + 255) / 256, 256, 0, stream>>>(h2, startv, degc, dinv, csr_col, b3, bufA);

    // fused pool + head
    k_poolhead<<<NG, 1024, 0, stream>>>(bufA, batch, Wd, bd, Wo, bo, outp);
}

// Round 8
// 382.343 us; speedup vs baseline: 2.7004x; 1.0829x over previous
//
#include <hip/hip_runtime.h>
#include <hip/hip_bf16.h>

#define NN 100000
#define NE 1600000
#define NG 256
#define FIN 16
#define HID 64
#define NBK 391     // buckets of 256 rows; 391*256 = 100096 >= NN
#define NTILE 391   // ceil(NE/4096)
#define PMAX 4864   // max actual edges per bucket (mean 4092)
#define BMAXP 5632  // fixed padded csr region per bucket (PMAX + 256*3)
#define MAXT (NN / 16 + NG)

__device__ __forceinline__ int lower_bound_i(const int* __restrict__ b, int n, int v) {
    int lo = 0, hi = n;
    while (lo < hi) { int m = (lo + hi) >> 1; if (b[m] < v) lo = m + 1; else hi = m; }
    return lo;
}

__device__ __forceinline__ unsigned pack_bf16(float a, float b) {
    unsigned ua = __float_as_uint(a), ub = __float_as_uint(b);
    ua = (ua + 0x7fffu + ((ua >> 16) & 1u)) >> 16;
    ub = (ub + 0x7fffu + ((ub >> 16) & 1u)) & 0xffff0000u;
    return ua | ub;
}
#define BF_LO(u) __uint_as_float((u) << 16)
#define BF_HI(u) __uint_as_float((u) & 0xffff0000u)

typedef __attribute__((ext_vector_type(8))) short bf16x8;
typedef __attribute__((ext_vector_type(4))) float f32x4;
union FU { uint4 u; bf16x8 v; };

// ==================== CSR build: 2-level LDS bucket sort ====================
__global__ __launch_bounds__(512) void k_bhist(const int4* __restrict__ row4, int* __restrict__ bhist) {
    __shared__ int h[NBK];
    for (int i = threadIdx.x; i < NBK; i += 512) h[i] = 0;
    __syncthreads();
    int t0 = blockIdx.x * 1024 + threadIdx.x;
#pragma unroll
    for (int it = 0; it < 2; ++it) {
        int t = t0 + it * 512;
        if (t < NE / 4) {
            int4 r = row4[t];
            atomicAdd(&h[r.x >> 8], 1); atomicAdd(&h[r.y >> 8], 1);
            atomicAdd(&h[r.z >> 8], 1); atomicAdd(&h[r.w >> 8], 1);
        }
    }
    __syncthreads();
    for (int i = threadIdx.x; i < NBK; i += 512)
        if (h[i]) atomicAdd(&bhist[i], h[i]);
}

__global__ __launch_bounds__(512) void k_bscan(const int* __restrict__ bhist, int* __restrict__ bbase,
                                               int* __restrict__ bcur) {
    __shared__ int sc[512];
    int t = threadIdx.x;
    int v = (t < NBK) ? bhist[t] : 0;
    sc[t] = v;
    __syncthreads();
    int acc = v;
    for (int off = 1; off < 512; off <<= 1) {
        int add = (t >= off) ? sc[t - off] : 0;
        __syncthreads();
        acc += add;
        sc[t] = acc;
        __syncthreads();
    }
    if (t < NBK) { bbase[t] = acc - v; bcur[t] = acc - v; }
    if (t == NBK - 1) bbase[NBK] = acc;
}

__global__ __launch_bounds__(512) void k_bscatter(const int4* __restrict__ row4, const int4* __restrict__ col4,
                                                  int* __restrict__ bcur, int2* __restrict__ pairs) {
    __shared__ int lh[NBK], lofs[NBK], lbase[NBK], lc[NBK];
    __shared__ int sc[512];
    __shared__ int2 stg[4096];
    for (int i = threadIdx.x; i < NBK; i += 512) { lh[i] = 0; lc[i] = 0; }
    __syncthreads();
    int t0 = blockIdx.x * 1024 + threadIdx.x;
#pragma unroll
    for (int it = 0; it < 2; ++it) {
        int t = t0 + it * 512;
        if (t < NE / 4) {
            int4 r = row4[t];
            atomicAdd(&lh[r.x >> 8], 1); atomicAdd(&lh[r.y >> 8], 1);
            atomicAdd(&lh[r.z >> 8], 1); atomicAdd(&lh[r.w >> 8], 1);
        }
    }
    __syncthreads();
    {
        int t = threadIdx.x;
        int v = (t < NBK) ? lh[t] : 0;
        sc[t] = v;
        __syncthreads();
        int acc = v;
        for (int off = 1; off < 512; off <<= 1) {
            int add = (t >= off) ? sc[t - off] : 0;
            __syncthreads();
            acc += add;
            sc[t] = acc;
            __syncthreads();
        }
        if (t < NBK) lofs[t] = acc - v;
    }
    if (threadIdx.x < NBK) {
        int c = lh[threadIdx.x];
        lbase[threadIdx.x] = c ? atomicAdd(&bcur[threadIdx.x], c) : 0;
    }
    __syncthreads();
#pragma unroll
    for (int it = 0; it < 2; ++it) {
        int t = t0 + it * 512;
        if (t < NE / 4) {
            int4 r = row4[t];
            int4 c = col4[t];
            int b, rk;
            b = r.x >> 8; rk = atomicAdd(&lc[b], 1); stg[lofs[b] + rk] = make_int2(r.x, c.x);
            b = r.y >> 8; rk = atomicAdd(&lc[b], 1); stg[lofs[b] + rk] = make_int2(r.y, c.y);
            b = r.z >> 8; rk = atomicAdd(&lc[b], 1); stg[lofs[b] + rk] = make_int2(r.z, c.z);
            b = r.w >> 8; rk = atomicAdd(&lc[b], 1); stg[lofs[b] + rk] = make_int2(r.w, c.w);
        }
    }
    __syncthreads();
    int nv = min(4096, NE - blockIdx.x * 4096);
    for (int j = threadIdx.x; j < nv; j += 512) {
        int2 p = stg[j];
        int b = p.x >> 8;
        pairs[lbase[b] + (j - lofs[b])] = p;
    }
}

// per-row counting sort into fixed padded bucket region; pads = sentinel NN
__global__ __launch_bounds__(256) void k_bsort(const int2* __restrict__ pairs, const int* __restrict__ bbase,
                                               int* __restrict__ csr_col, int* __restrict__ startv,
                                               int* __restrict__ degc, float* __restrict__ dinv) {
    __shared__ int colo[BMAXP];
    __shared__ int cnt[256], pofs[256], c2[256], sc[256];
    int b = blockIdx.x;
    int s = bbase[b];
    int n = min(bbase[b + 1] - s, PMAX);
    cnt[threadIdx.x] = 0;
    c2[threadIdx.x] = 0;
    __syncthreads();
    for (int i = threadIdx.x; i < n; i += 256)
        atomicAdd(&cnt[pairs[s + i].x & 255], 1);
    __syncthreads();
    int c = cnt[threadIdx.x];
    int pc = (c + 3) & ~3;  // pad row to multiple of 4
    {
        int t = threadIdx.x, v = pc;
        sc[t] = v;
        __syncthreads();
        int acc = v;
        for (int off = 1; off < 256; off <<= 1) {
            int add = (t >= off) ? sc[t - off] : 0;
            __syncthreads();
            acc += add;
            sc[t] = acc;
            __syncthreads();
        }
        pofs[t] = acc - v;
    }
    __syncthreads();
    int ptot = sc[255];
    for (int i = threadIdx.x; i < ptot; i += 256) colo[i] = NN;  // sentinel
    __syncthreads();
    for (int i = threadIdx.x; i < n; i += 256) {
        int2 p = pairs[s + i];
        int lr = p.x & 255;
        int rk = atomicAdd(&c2[lr], 1);
        colo[pofs[lr] + rk] = p.y;
    }
    __syncthreads();
    int gb = b * BMAXP;
    for (int i = threadIdx.x; i < ptot; i += 256) csr_col[gb + i] = colo[i];
    int r = (b << 8) + threadIdx.x;
    if (r < NN) {
        startv[r] = gb + pofs[threadIdx.x];
        degc[r] = pc;                         // PADDED count (used by gathers)
        dinv[r] = rsqrtf((float)(c + 1));     // actual degree
    }
}

// ========== setup: block 0 = tile table, block 1 = W1 prep + sentinels =====
__global__ __launch_bounds__(256) void k_setup(const int* __restrict__ batch, int* __restrict__ ntot,
                                               int* __restrict__ tg, int* __restrict__ tbase,
                                               int* __restrict__ tcnt, const float* __restrict__ W1,
                                               unsigned* __restrict__ Wt1p, unsigned* __restrict__ xb,
                                               unsigned* __restrict__ h2) {
    if (blockIdx.x == 1) {
        int t = threadIdx.x;
        int j = t >> 2, kq = t & 3;
#pragma unroll
        for (int i = 0; i < 4; i++) {
            int idx = kq * 4 + i;
            int k = idx * 2;
            unsigned v = 0;
            if (k < FIN) v = pack_bf16(W1[k * 64 + j], W1[(k + 1) * 64 + j]);
            Wt1p[j * 16 + idx] = v;
        }
        if (t < 32) h2[(long)NN * 32 + t] = 0u;   // zero sentinel row
        if (t < 8) xb[(long)NN * 8 + t] = 0u;
        return;
    }
    __shared__ int gst[NG + 1];
    __shared__ int sc[NG];
    int t = threadIdx.x;  // 256 == NG
    gst[t] = lower_bound_i(batch, NN, t);
    if (t == 0) gst[NG] = NN;
    __syncthreads();
    int ng = gst[t + 1] - gst[t];
    int nt = (ng + 15) >> 4;
    sc[t] = nt;
    __syncthreads();
    int acc = nt;
    for (int off = 1; off < NG; off <<= 1) {
        int add = (t >= off) ? sc[t - off] : 0;
        __syncthreads();
        acc += add;
        sc[t] = acc;
        __syncthreads();
    }
    int ofs = acc - nt;
    for (int i = 0; i < nt; i++) {
        tg[ofs + i] = t;
        tbase[ofs + i] = gst[t] + i * 16;
        tcnt[ofs + i] = min(16, ng - i * 16);
    }
    if (t == NG - 1) ntot[0] = acc;
}

// ==================== GraphNorm layer 0 (C=16) -> bf16, pre-scaled by dinv ==
__global__ __launch_bounds__(512) void k_graphnorm16(const float* __restrict__ x, const int* __restrict__ batch,
                              const float* __restrict__ w, const float* __restrict__ b,
                              const float* __restrict__ ms, const float* __restrict__ dinv,
                              unsigned* __restrict__ xb) {
    constexpr int C = FIN, NPB = 512 / C;
    __shared__ float red[NPB][C], red2[NPB][C];
    __shared__ float mm_s[C], rs_s[C];
    int g = blockIdx.x;
    int s = lower_bound_i(batch, NN, g);
    int e = lower_bound_i(batch, NN, g + 1);
    float fc = (float)max(e - s, 1);
    int c = threadIdx.x % C, slot = threadIdx.x / C;

    float a1 = 0.f, a2 = 0.f;
    for (int i = s + slot; i < e; i += NPB) { float v = x[i * C + c]; a1 += v; a2 += v * v; }
    red[slot][c] = a1;
    red2[slot][c] = a2;
    __syncthreads();
    if (threadIdx.x < C) {
        float t1 = 0.f, t2 = 0.f;
        for (int k = 0; k < NPB; k++) { t1 += red[k][threadIdx.x]; t2 += red2[k][threadIdx.x]; }
        float mean = t1 / fc;
        float mm = ms[threadIdx.x] * mean;
        float var = t2 / fc - 2.f * mm * mean + mm * mm;
        mm_s[threadIdx.x] = mm;
        rs_s[threadIdx.x] = rsqrtf(var + 1e-5f);
    }
    __syncthreads();
    float mm = mm_s[c], ww = w[c] * rs_s[c], bb = b[c];
    for (int i = s + slot; i < e; i += NPB) {
        float v = (ww * (x[i * C + c] - mm) + bb) * dinv[i];
        float partner = __shfl_xor(v, 1);
        if ((c & 1) == 0) xb[(long)i * 8 + (c >> 1)] = pack_bf16(v, partner);
    }
}

// ==== GraphNorm stats (C=64, bf16 in, 512 thr) + fold per-graph W', bias2 ==
__global__ __launch_bounds__(512) void k_gnstats2(const unsigned* __restrict__ xw, const int* __restrict__ batch,
                          const float* __restrict__ w, const float* __restrict__ b,
                          const float* __restrict__ ms, const float* __restrict__ W,
                          unsigned* __restrict__ Wtp, float* __restrict__ bias2) {
    __shared__ float4 red[16][32];
    __shared__ float sA[64], sB[64];
    int g = blockIdx.x;
    int s = lower_bound_i(batch, NN, g);
    int e = lower_bound_i(batch, NN, g + 1);
    float fc = (float)max(e - s, 1);
    int cu = threadIdx.x & 31, slot = threadIdx.x >> 5;  // 16 slots x 32 u32

    float s1l = 0.f, s1h = 0.f, s2l = 0.f, s2h = 0.f;
    for (int i = s + slot; i < e; i += 16) {
        unsigned u = xw[(long)i * 32 + cu];
        float lo = BF_LO(u), hi = BF_HI(u);
        s1l += lo; s1h += hi; s2l += lo * lo; s2h += hi * hi;
    }
    red[slot][cu] = make_float4(s1l, s1h, s2l, s2h);
    __syncthreads();
    if (threadIdx.x < 64) {
        int cc = threadIdx.x, iu = cc >> 1, hi = cc & 1;
        float t1 = 0.f, t2 = 0.f;
        for (int k = 0; k < 16; k++) {
            float4 v = red[k][iu];
            t1 += hi ? v.y : v.x;
            t2 += hi ? v.w : v.z;
        }
        float mean = t1 / fc;
        float mm = ms[cc] * mean;
        float var = t2 / fc - 2.f * mm * mean + mm * mm;
        float A = w[cc] * rsqrtf(var + 1e-5f);
        sA[cc] = A;
        sB[cc] = b[cc] - A * mm;
    }
    __syncthreads();
    if (threadIdx.x < 256) {
        int j = threadIdx.x >> 2, kq = threadIdx.x & 3;
        unsigned* wrow = Wtp + ((long)g * 64 + j) * 32 + kq * 8;
        float part = 0.f;
#pragma unroll
        for (int i = 0; i < 8; i++) {
            int k = kq * 16 + 2 * i;
            float w0 = W[k * 64 + j], w1 = W[(k + 1) * 64 + j];
            wrow[i] = pack_bf16(sA[k] * w0, sA[k + 1] * w1);
            part += sB[k] * w0 + sB[k + 1] * w1;
        }
        part += __shfl_xor(part, 1);
        part += __shfl_xor(part, 2);
        if (kq == 0) bias2[g * 64 + j] = part;
    }
}

// ==== 16-dim gather (sentinel-padded, guard-free) -> packed bf16 agg =======
__global__ __launch_bounds__(256) void k_gather16(const unsigned* __restrict__ xb, const int* __restrict__ startv,
                           const int* __restrict__ degc, const float* __restrict__ dinv,
                           const int* __restrict__ csr_col, unsigned* __restrict__ agg) {
    int wave = (blockIdx.x * blockDim.x + threadIdx.x) >> 6;
    if (wave >= NN) return;
    int lane = threadIdx.x & 63;
    unsigned p = lane & 7;
    int g = lane >> 3;
    int s = startv[wave], pcnt = degc[wave];
    float di = dinv[wave];
    float ax = 0.f, ay = 0.f;
    int k = g;
    for (; k + 8 < pcnt; k += 16) {
        unsigned c0 = (unsigned)csr_col[s + k], c1 = (unsigned)csr_col[s + k + 8];
        unsigned u0 = xb[c0 * 8u + p], u1 = xb[c1 * 8u + p];
        ax += BF_LO(u0) + BF_LO(u1);
        ay += BF_HI(u0) + BF_HI(u1);
    }
    if (k < pcnt) {
        unsigned c0 = (unsigned)csr_col[s + k];
        unsigned u0 = xb[c0 * 8u + p];
        ax += BF_LO(u0);
        ay += BF_HI(u0);
    }
    ax += __shfl_xor(ax, 8);  ay += __shfl_xor(ay, 8);
    ax += __shfl_xor(ax, 16); ay += __shfl_xor(ay, 16);
    ax += __shfl_xor(ax, 32); ay += __shfl_xor(ay, 32);
    if (g == 0) {
        unsigned u = xb[(unsigned)wave * 8u + p];
        ax = (ax + BF_LO(u)) * di;
        ay = (ay + BF_HI(u)) * di;
        agg[(long)wave * 16 + p] = pack_bf16(ax, ay);
    } else if (g == 1) {
        agg[(long)wave * 16 + 8 + p] = 0u;  // K-pad for the MFMA GEMM
    }
}

// ==== MFMA GEMM: per-tile 16 nodes x 64 out, K = KU*32 ======================
template <int KU, bool PERG, bool RELU, bool DINV>
__global__ __launch_bounds__(256) void k_gemmT(const unsigned* __restrict__ Ain, const unsigned* __restrict__ Wt,
                        const float* __restrict__ biasv, const float* __restrict__ dinv,
                        const int* __restrict__ ntot, const int* __restrict__ tg,
                        const int* __restrict__ tbase, const int* __restrict__ tcnt,
                        unsigned* __restrict__ Aout) {
    const int RW = KU * 16;
    int tix = blockIdx.x * 4 + (threadIdx.x >> 6);
    if (tix >= ntot[0]) return;
    int g = tg[tix], base = tbase[tix], n = tcnt[tix];
    int l = threadIdx.x & 63, r = l & 15, q = l >> 4;
    FU a[KU];
#pragma unroll
    for (int s = 0; s < KU; s++) {
        if (r < n) a[s].u = *(const uint4*)(Ain + (long)(base + r) * RW + s * 16 + q * 4);
        else a[s].u = make_uint4(0, 0, 0, 0);
    }
    const unsigned* wb = PERG ? (Wt + (long)g * 64 * RW) : Wt;
    f32x4 acc[4];
#pragma unroll
    for (int t = 0; t < 4; t++) {
        acc[t] = (f32x4){0.f, 0.f, 0.f, 0.f};
#pragma unroll
        for (int s = 0; s < KU; s++) {
            FU bfrag;
            bfrag.u = *(const uint4*)(wb + (long)(t * 16 + r) * RW + s * 16 + q * 4);
            acc[t] = __builtin_amdgcn_mfma_f32_16x16x32_bf16(a[s].v, bfrag.v, acc[t], 0, 0, 0);
        }
    }
    const float* bb = PERG ? (biasv + g * 64) : biasv;
    float dv[4];
#pragma unroll
    for (int e = 0; e < 4; e++) {
        int node = base + q * 4 + e;
        dv[e] = DINV ? ((node < NN) ? dinv[node] : 0.f) : 1.f;
    }
#pragma unroll
    for (int t = 0; t < 4; t++) {
        float bv = bb[t * 16 + r];
#pragma unroll
        for (int e = 0; e < 4; e++) {
            float v = acc[t][e] + bv;
            if (RELU) v = fmaxf(v, 0.f);
            if (DINV) v *= dv[e];
            float part = __shfl_xor(v, 1);
            if ((q * 4 + e) < n && (r & 1) == 0)
                Aout[(long)(base + q * 4 + e) * 32 + t * 8 + (r >> 1)] = pack_bf16(v, part);
        }
    }
}

// ==== 64-dim gather: guard-free, uint4 col loads, 8-deep per half-wave =====
__global__ __launch_bounds__(256) void k_gather64(const unsigned* __restrict__ h2, const int* __restrict__ startv,
                           const int* __restrict__ degc, const float* __restrict__ dinv,
                           const int* __restrict__ csr_col, const float* __restrict__ bias,
                           unsigned* __restrict__ outp) {
    int wave = (blockIdx.x * blockDim.x + threadIdx.x) >> 6;
    if (wave >= NN) return;
    int lane = threadIdx.x & 63;
    unsigned p = lane & 31;
    int g = lane >> 5;
    int s = startv[wave], pcnt = degc[wave];
    float di = dinv[wave];
    float ax = 0.f, ay = 0.f;
    if (g == 0) {  // self term (pre-scaled by dinv already)
        unsigned u = h2[(unsigned)wave * 32u + p];
        ax = BF_LO(u);
        ay = BF_HI(u);
    }
    int k = g * 8;
    for (; k + 8 <= pcnt; k += 16) {
        uint4 c0 = *(const uint4*)(csr_col + s + k);
        uint4 c1 = *(const uint4*)(csr_col + s + k + 4);
        unsigned u0 = h2[c0.x * 32u + p], u1 = h2[c0.y * 32u + p],
                 u2 = h2[c0.z * 32u + p], u3 = h2[c0.w * 32u + p],
                 u4 = h2[c1.x * 32u + p], u5 = h2[c1.y * 32u + p],
                 u6 = h2[c1.z * 32u + p], u7 = h2[c1.w * 32u + p];
        ax += BF_LO(u0) + BF_LO(u1) + BF_LO(u2) + BF_LO(u3)
            + BF_LO(u4) + BF_LO(u5) + BF_LO(u6) + BF_LO(u7);
        ay += BF_HI(u0) + BF_HI(u1) + BF_HI(u2) + BF_HI(u3)
            + BF_HI(u4) + BF_HI(u5) + BF_HI(u6) + BF_HI(u7);
    }
    if (k < pcnt) {  // exactly 4 remaining (rows padded to multiple of 4)
        uint4 c0 = *(const uint4*)(csr_col + s + k);
        unsigned u0 = h2[c0.x * 32u + p], u1 = h2[c0.y * 32u + p],
                 u2 = h2[c0.z * 32u + p], u3 = h2[c0.w * 32u + p];
        ax += BF_LO(u0) + BF_LO(u1) + BF_LO(u2) + BF_LO(u3);
        ay += BF_HI(u0) + BF_HI(u1) + BF_HI(u2) + BF_HI(u3);
    }
    ax += __shfl_xor(ax, 32);
    ay += __shfl_xor(ay, 32);
    if (g == 0) {
        float2 bv = ((const float2*)bias)[p];
        float vx = fmaxf(ax * di + bv.x, 0.f);
        float vy = fmaxf(ay * di + bv.y, 0.f);
        outp[(unsigned)wave * 32u + p] = pack_bf16(vx, vy);
    }
}

// ============ fused global mean pool (bf16 in) + dense head ================
__global__ __launch_bounds__(1024) void k_poolhead(const unsigned* __restrict__ xw, const int* __restrict__ batch,
                       const float* __restrict__ Wd, const float* __restrict__ bd,
                       const float* __restrict__ Wo, const float* __restrict__ bo,
                       float* __restrict__ out) {
    __shared__ float red[16][64];
    __shared__ float wds[64 * 64];
    __shared__ float gs[64];
    int g = blockIdx.x;
    int s = lower_bound_i(batch, NN, g);
    int e = lower_bound_i(batch, NN, g + 1);
    int c = threadIdx.x & 63, slot = threadIdx.x >> 6;
    for (int i = threadIdx.x; i < 64 * 64; i += 1024) wds[i] = Wd[i];
    float acc = 0.f;
    for (int i = s + slot; i < e; i += 16) {
        unsigned u = xw[(long)i * 32 + (c >> 1)];
        acc += (c & 1) ? BF_HI(u) : BF_LO(u);
    }
    red[slot][c] = acc;
    __syncthreads();
    if (threadIdx.x < 64) {
        float t = 0.f;
        for (int k = 0; k < 16; k++) t += red[k][threadIdx.x];
        gs[threadIdx.x] = t / (float)max(e - s, 1);
    }
    __syncthreads();
    if (threadIdx.x < 64) {
        int j = threadIdx.x;
        float a2 = bd[j];
        for (int k = 0; k < 64; k++) a2 += gs[k] * wds[k * 64 + j];
        float hv = fmaxf(a2, 0.f);
        float p0 = hv * Wo[j * 2 + 0], p1 = hv * Wo[j * 2 + 1];
        for (int off = 32; off; off >>= 1) { p0 += __shfl_down(p0, off); p1 += __shfl_down(p1, off); }
        if (j == 0) {
            float l0 = p0 + bo[0], l1 = p1 + bo[1];
            float m = fmaxf(l0, l1);
            float e0 = expf(l0 - m), e1 = expf(l1 - m);
            float inv = 1.f / (e0 + e1);
            out[g * 2 + 0] = e0 * inv;
            out[g * 2 + 1] = e1 * inv;
        }
    }
}

extern "C" void kernel_launch(void* const* d_in, const int* in_sizes, int n_in,
                              void* d_out, int out_size, void* d_ws, size_t ws_size,
                              hipStream_t stream) {
    const float* x = (const float*)d_in[0];
    const int* ei = (const int*)d_in[1];
    const int* row = ei;
    const int* col = ei + NE;
    const int* batch = (const int*)d_in[2];
    const float* gn0w = (const float*)d_in[3];
    const float* gn0b = (const float*)d_in[4];
    const float* gn0ms = (const float*)d_in[5];
    const float* W1 = (const float*)d_in[6];
    const float* b1 = (const float*)d_in[7];
    const float* gn1w = (const float*)d_in[8];
    const float* gn1b = (const float*)d_in[9];
    const float* gn1ms = (const float*)d_in[10];
    const float* W2 = (const float*)d_in[11];
    const float* b2 = (const float*)d_in[12];
    const float* gn2w = (const float*)d_in[13];
    const float* gn2b = (const float*)d_in[14];
    const float* gn2ms = (const float*)d_in[15];
    const float* W3 = (const float*)d_in[16];
    const float* b3 = (const float*)d_in[17];
    const float* Wd = (const float*)d_in[18];
    const float* bd = (const float*)d_in[19];
    const float* Wo = (const float*)d_in[20];
    const float* bo = (const float*)d_in[21];
    float* outp = (float*)d_out;

    // workspace layout (16B-aligned chunks)
    int* bhist = (int*)d_ws;                        // 512
    int* bbase = bhist + 512;                       // 512
    int* bcur = bbase + 512;                        // 512
    int* startv = bcur + 512;                       // NN
    int* degc = startv + NN;                        // NN
    float* dinv = (float*)(degc + NN);              // NN
    int* csr_col = (int*)(dinv + NN);               // NBK*BMAXP = 2,202,112
    int* ntot = csr_col + (long)NBK * BMAXP;        // 16
    int* tg = ntot + 16;                            // 6608
    int* tbase = tg + 6608;                         // 6608
    int* tcnt = tbase + 6608;                       // 6608
    unsigned* Wt1p = (unsigned*)(tcnt + 6608);      // 1024
    unsigned* Wtp = Wt1p + 1024;                    // NG*64*32 (2MB)
    float* bias2 = (float*)(Wtp + (long)NG * 64 * 32);  // NG*64
    unsigned* xb = (unsigned*)(bias2 + NG * 64);    // NN*8 + 16 (sentinel row)
    unsigned* agg16 = xb + (long)NN * 8 + 16;       // NN*16
    unsigned* bufA = agg16 + (long)NN * 16;         // NN*32 (12.8MB)
    unsigned* bufB = bufA + (long)NN * 32;          // NN*32
    unsigned* h2 = bufB + (long)NN * 32;            // NN*32 + 32 (sentinel row)
    int2* pairs = (int2*)bufA;  // alias: NE int2 == bufA size; dead before bufA written

    const int NBG = (MAXT + 3) / 4;

    // ---- CSR build (bucket sort, coalesced writes, sentinel-padded rows) ----
    hipMemsetAsync(bhist, 0, 512 * sizeof(int), stream);
    k_bhist<<<NTILE, 512, 0, stream>>>((const int4*)row, bhist);
    k_bscan<<<1, 512, 0, stream>>>(bhist, bbase, bcur);
    k_bscatter<<<NTILE, 512, 0, stream>>>((const int4*)row, (const int4*)col, bcur, pairs);
    k_bsort<<<NBK, 256, 0, stream>>>(pairs, bbase, csr_col, startv, degc, dinv);

    // ---- tile table + W1 prep + sentinel zeroing ----
    k_setup<<<2, 256, 0, stream>>>(batch, ntot, tg, tbase, tcnt, W1, Wt1p, xb, h2);

    // layer 1: norm(16, bf16, dinv-prescaled) -> gather -> MFMA gemm 16->64
    k_graphnorm16<<<NG, 512, 0, stream>>>(x, batch, gn0w, gn0b, gn0ms, dinv, xb);
    k_gather16<<<(NN * 64 + 255) / 256, 256, 0, stream>>>(xb, startv, degc, dinv, csr_col, agg16);
    k_gemmT<1, false, true, false><<<NBG, 256, 0, stream>>>(agg16, Wt1p, b1, dinv, ntot, tg, tbase, tcnt, bufA);

    // layer 2: stats+fold -> MFMA gemm (affine-folded, xdinv) -> gather
    k_gnstats2<<<NG, 512, 0, stream>>>(bufA, batch, gn1w, gn1b, gn1ms, W2, Wtp, bias2);
    k_gemmT<2, true, false, true><<<NBG, 256, 0, stream>>>(bufA, Wtp, bias2, dinv, ntot, tg, tbase, tcnt, h2);
    k_gather64<<<(NN * 64 + 255) / 256, 256, 0, stream>>>(h2, startv, degc, dinv, csr_col, b2, bufB);

    // layer 3
    k_gnstats2<<<NG, 512, 0, stream>>>(bufB, batch, gn2w, gn2b, gn2ms, W3, Wtp, bias2);
    k_gemmT<2, true, false, true><<<NBG, 256, 0, stream>>>(bufB, Wtp, bias2, dinv, ntot, tg, tbase, tcnt, h2);
    k_gather64<<<(NN * 64 + 255) / 256, 256, 0, stream>>>(h2, startv, degc, dinv, csr_col, b3, bufA);

    // fused pool + head
    k_poolhead<<<NG, 1024, 0, stream>>>(bufA, batch, Wd, bd, Wo, bo, outp);
}

// Round 9
// 375.852 us; speedup vs baseline: 2.7470x; 1.0173x over previous
//
#include <hip/hip_runtime.h>
#include <hip/hip_bf16.h>

#define NN 100000
#define NE 1600000
#define NG 256
#define FIN 16
#define HID 64
#define NBK 391     // buckets of 256 rows; 391*256 = 100096 >= NN
#define NTILE 391   // ceil(NE/4096)
#define PMAX 4864   // max actual edges per bucket (mean 4092)
#define BMAXP 5632  // fixed region per bucket (pairs and padded csr)
#define MAXT (NN / 16 + NG)

__device__ __forceinline__ int lower_bound_i(const int* __restrict__ b, int n, int v) {
    int lo = 0, hi = n;
    while (lo < hi) { int m = (lo + hi) >> 1; if (b[m] < v) lo = m + 1; else hi = m; }
    return lo;
}

__device__ __forceinline__ unsigned pack_bf16(float a, float b) {
    unsigned ua = __float_as_uint(a), ub = __float_as_uint(b);
    ua = (ua + 0x7fffu + ((ua >> 16) & 1u)) >> 16;
    ub = (ub + 0x7fffu + ((ub >> 16) & 1u)) & 0xffff0000u;
    return ua | ub;
}
#define BF_LO(u) __uint_as_float((u) << 16)
#define BF_HI(u) __uint_as_float((u) & 0xffff0000u)

typedef __attribute__((ext_vector_type(8))) short bf16x8;
typedef __attribute__((ext_vector_type(4))) float f32x4;
union FU { uint4 u; bf16x8 v; };

// ============ CSR build: direct bucket scatter (fixed regions) =============
__global__ __launch_bounds__(512) void k_bscatter(const int4* __restrict__ row4, const int4* __restrict__ col4,
                                                  int* __restrict__ bcur, int2* __restrict__ pairs) {
    __shared__ int lh[NBK], lofs[NBK], lbase[NBK], lc[NBK];
    __shared__ int sc[512];
    __shared__ int2 stg[4096];
    for (int i = threadIdx.x; i < NBK; i += 512) { lh[i] = 0; lc[i] = 0; }
    __syncthreads();
    int t0 = blockIdx.x * 1024 + threadIdx.x;
#pragma unroll
    for (int it = 0; it < 2; ++it) {
        int t = t0 + it * 512;
        if (t < NE / 4) {
            int4 r = row4[t];
            atomicAdd(&lh[r.x >> 8], 1); atomicAdd(&lh[r.y >> 8], 1);
            atomicAdd(&lh[r.z >> 8], 1); atomicAdd(&lh[r.w >> 8], 1);
        }
    }
    __syncthreads();
    {
        int t = threadIdx.x;
        int v = (t < NBK) ? lh[t] : 0;
        sc[t] = v;
        __syncthreads();
        int acc = v;
        for (int off = 1; off < 512; off <<= 1) {
            int add = (t >= off) ? sc[t - off] : 0;
            __syncthreads();
            acc += add;
            sc[t] = acc;
            __syncthreads();
        }
        if (t < NBK) lofs[t] = acc - v;
    }
    if (threadIdx.x < NBK) {  // reserve range inside fixed bucket region
        int c = lh[threadIdx.x];
        lbase[threadIdx.x] = c ? atomicAdd(&bcur[threadIdx.x], c) : 0;
    }
    __syncthreads();
#pragma unroll
    for (int it = 0; it < 2; ++it) {
        int t = t0 + it * 512;
        if (t < NE / 4) {
            int4 r = row4[t];
            int4 c = col4[t];
            int b, rk;
            b = r.x >> 8; rk = atomicAdd(&lc[b], 1); stg[lofs[b] + rk] = make_int2(r.x, c.x);
            b = r.y >> 8; rk = atomicAdd(&lc[b], 1); stg[lofs[b] + rk] = make_int2(r.y, c.y);
            b = r.z >> 8; rk = atomicAdd(&lc[b], 1); stg[lofs[b] + rk] = make_int2(r.z, c.z);
            b = r.w >> 8; rk = atomicAdd(&lc[b], 1); stg[lofs[b] + rk] = make_int2(r.w, c.w);
        }
    }
    __syncthreads();
    int nv = min(4096, NE - blockIdx.x * 4096);
    for (int j = threadIdx.x; j < nv; j += 512) {
        int2 p = stg[j];
        int b = p.x >> 8;
        pairs[(long)b * BMAXP + lbase[b] + (j - lofs[b])] = p;
    }
}

// per-row counting sort into fixed padded bucket region; pads = sentinel NN
__global__ __launch_bounds__(256) void k_bsort(const int2* __restrict__ pairs, const int* __restrict__ bcur,
                                               int* __restrict__ csr_col, int* __restrict__ startv,
                                               int* __restrict__ degc, float* __restrict__ dinv) {
    __shared__ int colo[BMAXP];
    __shared__ int cnt[256], pofs[256], c2[256], sc[256];
    int b = blockIdx.x;
    long sp = (long)b * BMAXP;
    int n = min(bcur[b], PMAX);
    cnt[threadIdx.x] = 0;
    c2[threadIdx.x] = 0;
    __syncthreads();
    for (int i = threadIdx.x; i < n; i += 256)
        atomicAdd(&cnt[pairs[sp + i].x & 255], 1);
    __syncthreads();
    int c = cnt[threadIdx.x];
    int pc = (c + 3) & ~3;  // row padded to multiple of 4 (alignment)
    {
        int t = threadIdx.x, v = pc;
        sc[t] = v;
        __syncthreads();
        int acc = v;
        for (int off = 1; off < 256; off <<= 1) {
            int add = (t >= off) ? sc[t - off] : 0;
            __syncthreads();
            acc += add;
            sc[t] = acc;
            __syncthreads();
        }
        pofs[t] = acc - v;
    }
    __syncthreads();
    int ptot = sc[255];
    for (int i = threadIdx.x; i < ptot; i += 256) colo[i] = NN;  // sentinel
    __syncthreads();
    for (int i = threadIdx.x; i < n; i += 256) {
        int2 p = pairs[sp + i];
        int lr = p.x & 255;
        int rk = atomicAdd(&c2[lr], 1);
        colo[pofs[lr] + rk] = p.y;
    }
    __syncthreads();
    int gb = b * BMAXP;
    for (int i = threadIdx.x; i < ptot; i += 256) csr_col[gb + i] = colo[i];
    int r = (b << 8) + threadIdx.x;
    if (r < NN) {
        startv[r] = gb + pofs[threadIdx.x];
        degc[r] = c;                          // ACTUAL degree (guarded gathers)
        dinv[r] = rsqrtf((float)(c + 1));
    }
}

// ========== setup: block 0 = tile table, block 1 = W1 prep + sentinels =====
__global__ __launch_bounds__(256) void k_setup(const int* __restrict__ batch, int* __restrict__ ntot,
                                               int* __restrict__ tg, int* __restrict__ tbase,
                                               int* __restrict__ tcnt, const float* __restrict__ W1,
                                               unsigned* __restrict__ Wt1p, unsigned* __restrict__ xb,
                                               unsigned* __restrict__ h2) {
    if (blockIdx.x == 1) {
        int t = threadIdx.x;
        int j = t >> 2, kq = t & 3;
#pragma unroll
        for (int i = 0; i < 4; i++) {
            int idx = kq * 4 + i;
            int k = idx * 2;
            unsigned v = 0;
            if (k < FIN) v = pack_bf16(W1[k * 64 + j], W1[(k + 1) * 64 + j]);
            Wt1p[j * 16 + idx] = v;
        }
        if (t < 32) h2[(long)NN * 32 + t] = 0u;   // zero sentinel row
        if (t < 8) xb[(long)NN * 8 + t] = 0u;
        return;
    }
    __shared__ int gst[NG + 1];
    __shared__ int sc[NG];
    int t = threadIdx.x;  // 256 == NG
    gst[t] = lower_bound_i(batch, NN, t);
    if (t == 0) gst[NG] = NN;
    __syncthreads();
    int ng = gst[t + 1] - gst[t];
    int nt = (ng + 15) >> 4;
    sc[t] = nt;
    __syncthreads();
    int acc = nt;
    for (int off = 1; off < NG; off <<= 1) {
        int add = (t >= off) ? sc[t - off] : 0;
        __syncthreads();
        acc += add;
        sc[t] = acc;
        __syncthreads();
    }
    int ofs = acc - nt;
    for (int i = 0; i < nt; i++) {
        tg[ofs + i] = t;
        tbase[ofs + i] = gst[t] + i * 16;
        tcnt[ofs + i] = min(16, ng - i * 16);
    }
    if (t == NG - 1) ntot[0] = acc;
}

// ==================== GraphNorm layer 0 (C=16) -> bf16, pre-scaled by dinv ==
__global__ __launch_bounds__(512) void k_graphnorm16(const float* __restrict__ x, const int* __restrict__ batch,
                              const float* __restrict__ w, const float* __restrict__ b,
                              const float* __restrict__ ms, const float* __restrict__ dinv,
                              unsigned* __restrict__ xb) {
    constexpr int C = FIN, NPB = 512 / C;
    __shared__ float red[NPB][C], red2[NPB][C];
    __shared__ float mm_s[C], rs_s[C];
    int g = blockIdx.x;
    int s = lower_bound_i(batch, NN, g);
    int e = lower_bound_i(batch, NN, g + 1);
    float fc = (float)max(e - s, 1);
    int c = threadIdx.x % C, slot = threadIdx.x / C;

    float a1 = 0.f, a2 = 0.f;
    for (int i = s + slot; i < e; i += NPB) { float v = x[i * C + c]; a1 += v; a2 += v * v; }
    red[slot][c] = a1;
    red2[slot][c] = a2;
    __syncthreads();
    if (threadIdx.x < C) {
        float t1 = 0.f, t2 = 0.f;
        for (int k = 0; k < NPB; k++) { t1 += red[k][threadIdx.x]; t2 += red2[k][threadIdx.x]; }
        float mean = t1 / fc;
        float mm = ms[threadIdx.x] * mean;
        float var = t2 / fc - 2.f * mm * mean + mm * mm;
        mm_s[threadIdx.x] = mm;
        rs_s[threadIdx.x] = rsqrtf(var + 1e-5f);
    }
    __syncthreads();
    float mm = mm_s[c], ww = w[c] * rs_s[c], bb = b[c];
    for (int i = s + slot; i < e; i += NPB) {
        float v = (ww * (x[i * C + c] - mm) + bb) * dinv[i];
        float partner = __shfl_xor(v, 1);
        if ((c & 1) == 0) xb[(long)i * 8 + (c >> 1)] = pack_bf16(v, partner);
    }
}

// ==== GraphNorm stats (C=64, bf16 in, 512 thr) + fold per-graph W', bias2 ==
__global__ __launch_bounds__(512) void k_gnstats2(const unsigned* __restrict__ xw, const int* __restrict__ batch,
                          const float* __restrict__ w, const float* __restrict__ b,
                          const float* __restrict__ ms, const float* __restrict__ W,
                          unsigned* __restrict__ Wtp, float* __restrict__ bias2) {
    __shared__ float4 red[16][32];
    __shared__ float sA[64], sB[64];
    int g = blockIdx.x;
    int s = lower_bound_i(batch, NN, g);
    int e = lower_bound_i(batch, NN, g + 1);
    float fc = (float)max(e - s, 1);
    int cu = threadIdx.x & 31, slot = threadIdx.x >> 5;  // 16 slots x 32 u32

    float s1l = 0.f, s1h = 0.f, s2l = 0.f, s2h = 0.f;
    for (int i = s + slot; i < e; i += 16) {
        unsigned u = xw[(long)i * 32 + cu];
        float lo = BF_LO(u), hi = BF_HI(u);
        s1l += lo; s1h += hi; s2l += lo * lo; s2h += hi * hi;
    }
    red[slot][cu] = make_float4(s1l, s1h, s2l, s2h);
    __syncthreads();
    if (threadIdx.x < 64) {
        int cc = threadIdx.x, iu = cc >> 1, hi = cc & 1;
        float t1 = 0.f, t2 = 0.f;
        for (int k = 0; k < 16; k++) {
            float4 v = red[k][iu];
            t1 += hi ? v.y : v.x;
            t2 += hi ? v.w : v.z;
        }
        float mean = t1 / fc;
        float mm = ms[cc] * mean;
        float var = t2 / fc - 2.f * mm * mean + mm * mm;
        float A = w[cc] * rsqrtf(var + 1e-5f);
        sA[cc] = A;
        sB[cc] = b[cc] - A * mm;
    }
    __syncthreads();
    if (threadIdx.x < 256) {
        int j = threadIdx.x >> 2, kq = threadIdx.x & 3;
        unsigned* wrow = Wtp + ((long)g * 64 + j) * 32 + kq * 8;
        float part = 0.f;
#pragma unroll
        for (int i = 0; i < 8; i++) {
            int k = kq * 16 + 2 * i;
            float w0 = W[k * 64 + j], w1 = W[(k + 1) * 64 + j];
            wrow[i] = pack_bf16(sA[k] * w0, sA[k + 1] * w1);
            part += sB[k] * w0 + sB[k + 1] * w1;
        }
        part += __shfl_xor(part, 1);
        part += __shfl_xor(part, 2);
        if (kq == 0) bias2[g * 64 + j] = part;
    }
}

// ==== 16-dim gather (actual-count, guarded) -> packed bf16 agg =============
__global__ __launch_bounds__(256) void k_gather16(const unsigned* __restrict__ xb, const int* __restrict__ startv,
                           const int* __restrict__ degc, const float* __restrict__ dinv,
                           const int* __restrict__ csr_col, unsigned* __restrict__ agg) {
    int wave = (blockIdx.x * blockDim.x + threadIdx.x) >> 6;
    if (wave >= NN) return;
    int lane = threadIdx.x & 63;
    unsigned p = lane & 7;
    int g = lane >> 3;
    int s = startv[wave], cnt = degc[wave];
    float di = dinv[wave];
    float ax = 0.f, ay = 0.f;
    int k = g;
    for (; k + 8 < cnt; k += 16) {
        unsigned c0 = (unsigned)csr_col[s + k], c1 = (unsigned)csr_col[s + k + 8];
        unsigned u0 = xb[c0 * 8u + p], u1 = xb[c1 * 8u + p];
        ax += BF_LO(u0) + BF_LO(u1);
        ay += BF_HI(u0) + BF_HI(u1);
    }
    if (k < cnt) {
        unsigned c0 = (unsigned)csr_col[s + k];
        unsigned u0 = xb[c0 * 8u + p];
        ax += BF_LO(u0);
        ay += BF_HI(u0);
    }
    ax += __shfl_xor(ax, 8);  ay += __shfl_xor(ay, 8);
    ax += __shfl_xor(ax, 16); ay += __shfl_xor(ay, 16);
    ax += __shfl_xor(ax, 32); ay += __shfl_xor(ay, 32);
    if (g == 0) {
        unsigned u = xb[(unsigned)wave * 8u + p];
        ax = (ax + BF_LO(u)) * di;
        ay = (ay + BF_HI(u)) * di;
        agg[(long)wave * 16 + p] = pack_bf16(ax, ay);
    } else if (g == 1) {
        agg[(long)wave * 16 + 8 + p] = 0u;  // K-pad for the MFMA GEMM
    }
}

// ==== MFMA GEMM: per-tile 16 nodes x 64 out, K = KU*32 ======================
template <int KU, bool PERG, bool RELU, bool DINV>
__global__ __launch_bounds__(256) void k_gemmT(const unsigned* __restrict__ Ain, const unsigned* __restrict__ Wt,
                        const float* __restrict__ biasv, const float* __restrict__ dinv,
                        const int* __restrict__ ntot, const int* __restrict__ tg,
                        const int* __restrict__ tbase, const int* __restrict__ tcnt,
                        unsigned* __restrict__ Aout) {
    const int RW = KU * 16;
    int tix = blockIdx.x * 4 + (threadIdx.x >> 6);
    if (tix >= ntot[0]) return;
    int g = tg[tix], base = tbase[tix], n = tcnt[tix];
    int l = threadIdx.x & 63, r = l & 15, q = l >> 4;
    FU a[KU];
#pragma unroll
    for (int s = 0; s < KU; s++) {
        if (r < n) a[s].u = *(const uint4*)(Ain + (long)(base + r) * RW + s * 16 + q * 4);
        else a[s].u = make_uint4(0, 0, 0, 0);
    }
    const unsigned* wb = PERG ? (Wt + (long)g * 64 * RW) : Wt;
    f32x4 acc[4];
#pragma unroll
    for (int t = 0; t < 4; t++) {
        acc[t] = (f32x4){0.f, 0.f, 0.f, 0.f};
#pragma unroll
        for (int s = 0; s < KU; s++) {
            FU bfrag;
            bfrag.u = *(const uint4*)(wb + (long)(t * 16 + r) * RW + s * 16 + q * 4);
            acc[t] = __builtin_amdgcn_mfma_f32_16x16x32_bf16(a[s].v, bfrag.v, acc[t], 0, 0, 0);
        }
    }
    const float* bb = PERG ? (biasv + g * 64) : biasv;
    float dv[4];
#pragma unroll
    for (int e = 0; e < 4; e++) {
        int node = base + q * 4 + e;
        dv[e] = DINV ? ((node < NN) ? dinv[node] : 0.f) : 1.f;
    }
#pragma unroll
    for (int t = 0; t < 4; t++) {
        float bv = bb[t * 16 + r];
#pragma unroll
        for (int e = 0; e < 4; e++) {
            float v = acc[t][e] + bv;
            if (RELU) v = fmaxf(v, 0.f);
            if (DINV) v *= dv[e];
            float part = __shfl_xor(v, 1);
            if ((q * 4 + e) < n && (r & 1) == 0)
                Aout[(long)(base + q * 4 + e) * 32 + t * 8 + (r >> 1)] = pack_bf16(v, part);
        }
    }
}

// ==== 64-dim gather: R7 pattern (guarded scalar cols), u32 addressing ======
__global__ __launch_bounds__(256) void k_gather64(const unsigned* __restrict__ h2, const int* __restrict__ startv,
                           const int* __restrict__ degc, const float* __restrict__ dinv,
                           const int* __restrict__ csr_col, const float* __restrict__ bias,
                           unsigned* __restrict__ outp) {
    int wave = (blockIdx.x * blockDim.x + threadIdx.x) >> 6;
    if (wave >= NN) return;
    int lane = threadIdx.x & 63;
    unsigned p = lane & 31;
    int g = lane >> 5;
    int s = startv[wave], cnt = degc[wave];
    float di = dinv[wave];
    float ax = 0.f, ay = 0.f;
    if (g == 0) {  // self term (pre-scaled by dinv already)
        unsigned u = h2[(unsigned)wave * 32u + p];
        ax = BF_LO(u);
        ay = BF_HI(u);
    }
    // group g owns edge blocks [k, k+8) for k = g*8, g*8+16, ...
    for (int k = g * 8; k < cnt; k += 16) {
        int cc[8];
#pragma unroll
        for (int i = 0; i < 8; i++) {
            int idx = k + i;
            cc[i] = (idx < cnt) ? csr_col[s + idx] : -1;
        }
        unsigned u[8];
#pragma unroll
        for (int i = 0; i < 8; i++)
            u[i] = (cc[i] >= 0) ? h2[(unsigned)cc[i] * 32u + p] : 0u;
#pragma unroll
        for (int i = 0; i < 8; i++) { ax += BF_LO(u[i]); ay += BF_HI(u[i]); }
    }
    ax += __shfl_xor(ax, 32);
    ay += __shfl_xor(ay, 32);
    if (g == 0) {
        float2 bv = ((const float2*)bias)[p];
        float vx = fmaxf(ax * di + bv.x, 0.f);
        float vy = fmaxf(ay * di + bv.y, 0.f);
        outp[(unsigned)wave * 32u + p] = pack_bf16(vx, vy);
    }
}

// ============ fused global mean pool (bf16 in) + dense head ================
__global__ __launch_bounds__(1024) void k_poolhead(const unsigned* __restrict__ xw, const int* __restrict__ batch,
                       const float* __restrict__ Wd, const float* __restrict__ bd,
                       const float* __restrict__ Wo, const float* __restrict__ bo,
                       float* __restrict__ out) {
    __shared__ float red[16][64];
    __shared__ float wds[64 * 64];
    __shared__ float gs[64];
    int g = blockIdx.x;
    int s = lower_bound_i(batch, NN, g);
    int e = lower_bound_i(batch, NN, g + 1);
    int c = threadIdx.x & 63, slot = threadIdx.x >> 6;
    for (int i = threadIdx.x; i < 64 * 64; i += 1024) wds[i] = Wd[i];
    float acc = 0.f;
    for (int i = s + slot; i < e; i += 16) {
        unsigned u = xw[(long)i * 32 + (c >> 1)];
        acc += (c & 1) ? BF_HI(u) : BF_LO(u);
    }
    red[slot][c] = acc;
    __syncthreads();
    if (threadIdx.x < 64) {
        float t = 0.f;
        for (int k = 0; k < 16; k++) t += red[k][threadIdx.x];
        gs[threadIdx.x] = t / (float)max(e - s, 1);
    }
    __syncthreads();
    if (threadIdx.x < 64) {
        int j = threadIdx.x;
        float a2 = bd[j];
        for (int k = 0; k < 64; k++) a2 += gs[k] * wds[k * 64 + j];
        float hv = fmaxf(a2, 0.f);
        float p0 = hv * Wo[j * 2 + 0], p1 = hv * Wo[j * 2 + 1];
        for (int off = 32; off; off >>= 1) { p0 += __shfl_down(p0, off); p1 += __shfl_down(p1, off); }
        if (j == 0) {
            float l0 = p0 + bo[0], l1 = p1 + bo[1];
            float m = fmaxf(l0, l1);
            float e0 = expf(l0 - m), e1 = expf(l1 - m);
            float inv = 1.f / (e0 + e1);
            out[g * 2 + 0] = e0 * inv;
            out[g * 2 + 1] = e1 * inv;
        }
    }
}

extern "C" void kernel_launch(void* const* d_in, const int* in_sizes, int n_in,
                              void* d_out, int out_size, void* d_ws, size_t ws_size,
                              hipStream_t stream) {
    const float* x = (const float*)d_in[0];
    const int* ei = (const int*)d_in[1];
    const int* row = ei;
    const int* col = ei + NE;
    const int* batch = (const int*)d_in[2];
    const float* gn0w = (const float*)d_in[3];
    const float* gn0b = (const float*)d_in[4];
    const float* gn0ms = (const float*)d_in[5];
    const float* W1 = (const float*)d_in[6];
    const float* b1 = (const float*)d_in[7];
    const float* gn1w = (const float*)d_in[8];
    const float* gn1b = (const float*)d_in[9];
    const float* gn1ms = (const float*)d_in[10];
    const float* W2 = (const float*)d_in[11];
    const float* b2 = (const float*)d_in[12];
    const float* gn2w = (const float*)d_in[13];
    const float* gn2b = (const float*)d_in[14];
    const float* gn2ms = (const float*)d_in[15];
    const float* W3 = (const float*)d_in[16];
    const float* b3 = (const float*)d_in[17];
    const float* Wd = (const float*)d_in[18];
    const float* bd = (const float*)d_in[19];
    const float* Wo = (const float*)d_in[20];
    const float* bo = (const float*)d_in[21];
    float* outp = (float*)d_out;

    // workspace layout (16B-aligned chunks)
    int* bcur = (int*)d_ws;                         // 512
    int* startv = bcur + 512;                       // NN
    int* degc = startv + NN;                        // NN
    float* dinv = (float*)(degc + NN);              // NN
    int* csr_col = (int*)(dinv + NN);               // NBK*BMAXP = 2,202,112
    int* ntot = csr_col + (long)NBK * BMAXP;        // 16
    int* tg = ntot + 16;                            // 6608
    int* tbase = tg + 6608;                         // 6608
    int* tcnt = tbase + 6608;                       // 6608
    unsigned* Wt1p = (unsigned*)(tcnt + 6608);      // 1024
    unsigned* Wtp = Wt1p + 1024;                    // NG*64*32 (2MB)
    float* bias2 = (float*)(Wtp + (long)NG * 64 * 32);  // NG*64
    unsigned* xb = (unsigned*)(bias2 + NG * 64);    // NN*8 + 16 (sentinel row)
    unsigned* agg16 = xb + (long)NN * 8 + 16;       // NN*16
    unsigned* bufA = agg16 + (long)NN * 16;         // NN*32 (12.8MB)
    unsigned* bufB = bufA + (long)NN * 32;          // NN*32
    unsigned* h2 = bufB + (long)NN * 32;            // NN*32 + 32 (sentinel row)
    // pairs: NBK*BMAXP int2 = 17.6MB, aliases bufA+bufB (25.6MB, dead during build)
    int2* pairs = (int2*)bufA;

    const int NBG = (MAXT + 3) / 4;

    // ---- CSR build: zero cursors -> direct bucket scatter -> per-bucket sort
    hipMemsetAsync(bcur, 0, 512 * sizeof(int), stream);
    k_bscatter<<<NTILE, 512, 0, stream>>>((const int4*)row, (const int4*)col, bcur, pairs);
    k_bsort<<<NBK, 256, 0, stream>>>(pairs, bcur, csr_col, startv, degc, dinv);

    // ---- tile table + W1 prep + sentinel zeroing ----
    k_setup<<<2, 256, 0, stream>>>(batch, ntot, tg, tbase, tcnt, W1, Wt1p, xb, h2);

    // layer 1: norm(16, bf16, dinv-prescaled) -> gather -> MFMA gemm 16->64
    k_graphnorm16<<<NG, 512, 0, stream>>>(x, batch, gn0w, gn0b, gn0ms, dinv, xb);
    k_gather16<<<(NN * 64 + 255) / 256, 256, 0, stream>>>(xb, startv, degc, dinv, csr_col, agg16);
    k_gemmT<1, false, true, false><<<NBG, 256, 0, stream>>>(agg16, Wt1p, b1, dinv, ntot, tg, tbase, tcnt, bufA);

    // layer 2: stats+fold -> MFMA gemm (affine-folded, xdinv) -> gather
    k_gnstats2<<<NG, 512, 0, stream>>>(bufA, batch, gn1w, gn1b, gn1ms, W2, Wtp, bias2);
    k_gemmT<2, true, false, true><<<NBG, 256, 0, stream>>>(bufA, Wtp, bias2, dinv, ntot, tg, tbase, tcnt, h2);
    k_gather64<<<(NN * 64 + 255) / 256, 256, 0, stream>>>(h2, startv, degc, dinv, csr_col, b2, bufB);

    // layer 3
    k_gnstats2<<<NG, 512, 0, stream>>>(bufB, batch, gn2w, gn2b, gn2ms, W3, Wtp, bias2);
    k_gemmT<2, true, false, true><<<NBG, 256, 0, stream>>>(bufB, Wtp, bias2, dinv, ntot, tg, tbase, tcnt, h2);
    k_gather64<<<(NN * 64 + 255) / 256, 256, 0, stream>>>(h2, startv, degc, dinv, csr_col, b3, bufA);

    // fused pool + head
    k_poolhead<<<NG, 1024, 0, stream>>>(bufA, batch, Wd, bd, Wo, bo, outp);
}